// Round 7
// baseline (744.746 us; speedup 1.0000x reference)
//
#include <hip/hip_runtime.h>
#include <math.h>

namespace {

typedef unsigned short ushort_t;
typedef __attribute__((ext_vector_type(8))) short short8;
typedef __attribute__((ext_vector_type(4))) float float4v;

__device__ __forceinline__ unsigned short f2bf(float x) {
  unsigned u = __float_as_uint(x);
  u += 0x7fffu + ((u >> 16) & 1u);        // RNE
  return (unsigned short)(u >> 16);
}
__device__ __forceinline__ float bf2f(unsigned short u) {
  return __uint_as_float((unsigned)u << 16);
}
__device__ __forceinline__ void bf8_to_f(const ushort_t* p, float* o) {
  const short8 v = *(const short8*)p;
#pragma unroll
  for (int k = 0; k < 8; ++k) o[k] = bf2f((unsigned short)v[k]);
}
__device__ __forceinline__ ushort4 f4bf(float4 v) {
  ushort4 r;
  r.x = f2bf(v.x); r.y = f2bf(v.y); r.z = f2bf(v.z); r.w = f2bf(v.w);
  return r;
}

__device__ __forceinline__ float wave_sum(float v) {
#pragma unroll
  for (int off = 32; off; off >>= 1) v += __shfl_down(v, off, 64);
  return v;
}
__device__ __forceinline__ float wave_max(float v) {
#pragma unroll
  for (int off = 32; off; off >>= 1) v = fmaxf(v, __shfl_down(v, off, 64));
  return v;
}
__device__ __forceinline__ float2 blocksum2(float a, float b, float2* red, int t, int nw) {
#pragma unroll
  for (int off = 32; off; off >>= 1) {
    a += __shfl_down(a, off, 64);
    b += __shfl_down(b, off, 64);
  }
  __syncthreads();
  if ((t & 63) == 0) red[t >> 6] = make_float2(a, b);
  __syncthreads();
  float sa = 0.f, sb = 0.f;
  for (int i = 0; i < nw; ++i) { sa += red[i].x; sb += red[i].y; }
  return make_float2(sa, sb);
}

// =================== bf16 MFMA NT-GEMM, 128x128 tile ===================
// C[M,N] = A[M,K] * Bt[N,K]^T.  M,N multiples of 128, K mult of 64.
// 3-slot ring, prefetch depth 2, ONE barrier per K-step (r5-verified schedule):
//   vmcnt(4) -> barrier -> STAGE(ks+2) -> setprio(1) MFMA setprio(0).
// This version strength-reduces per-step VALU: persistent per-thread global
// pointers (koff += 32/step) and COMPILE-TIME ring-slot indices via 3-unrolled
// loop, so LDS src/dst addresses fold to base+immediate.
// MODE 0: bf16 out, v += u[(c0+z)*512+row]*aw[(c0+z)*512+col]
// MODE 1: bf16 out, relu(v + bias[row])
// MODE 2: bf16 out, plain
// MODE 3: bf16 out, v + bias[col]
// MODE 4: f32 out, plain
template<int MODE>
__global__ __launch_bounds__(256)
void mgemm(const ushort_t* __restrict__ A, int lda, long sA,
           const ushort_t* __restrict__ Bt, int ldb, long sB,
           void* __restrict__ C, int ldc, long sC, int K,
           const float* __restrict__ bias,
           const float* __restrict__ aw, const float* __restrict__ u, int c0)
{
  __shared__ __attribute__((aligned(16))) ushort_t As[3][4096];
  __shared__ __attribute__((aligned(16))) ushort_t Bs[3][4096];

  // ---- XCD-aware swizzle: group all xy-tiles of one z on one XCD ----
  int bx = blockIdx.x, by = blockIdx.y, bz = blockIdx.z;
  const int nx = gridDim.x, ny = gridDim.y, nz = gridDim.z;
  if ((nz & 7) == 0) {
    const int nxy = nx * ny;
    const int L = bx + nx * (by + ny * bz);
    const int xcd = L & 7;
    const int idx = L >> 3;
    const int lz = idx / nxy;
    const int xy = idx - lz * nxy;
    bz = xcd + 8 * lz;
    bx = xy % nx;
    by = xy / nx;
  }

  const int z = bz;
  const ushort_t* Ab = A  + (long)z * sA;
  const ushort_t* Bb = Bt + (long)z * sB;
  const int tm = by * 128, tn = bx * 128;
  const int t = threadIdx.x, wv = t >> 6, ln = t & 63;
  const int lrow = ln >> 2, lseg = ln & 3;        // staging: 16 rows x 4 segs of 16B
  const int gseg = lseg ^ ((lrow >> 1) & 3);      // bank-conflict-free seg XOR
  const int frow = ln & 15, q = ln >> 4;          // fragment: m=ln&15, k-quad
  const int sw8 = (frow >> 1) & 3;
  const int aoff = (q ^ sw8) << 3;
  const int wm = (wv >> 1) * 64, wn = (wv & 1) * 64;

  float4v acc[4][4];
#pragma unroll
  for (int i = 0; i < 4; ++i)
#pragma unroll
    for (int j = 0; j < 4; ++j) acc[i][j] = (float4v)0.f;

  // persistent staging pointers (advance by koff); LDS dests are wave-uniform
  const ushort_t* pa0 = Ab + (long)(tm + wv * 32 + lrow) * lda + gseg * 8;
  const ushort_t* pa1 = pa0 + (long)16 * lda;
  const ushort_t* pb0 = Bb + (long)(tn + wv * 32 + lrow) * ldb + gseg * 8;
  const ushort_t* pb1 = pb0 + (long)16 * ldb;
  const int ra0 = wv * 1024, ra1 = wv * 1024 + 512;
  int koff = 0;

#define STAGE_TO(SL) do {                                                          \
    __builtin_amdgcn_global_load_lds(                                              \
        (const __attribute__((address_space(1))) void*)(pa0 + koff),               \
        (__attribute__((address_space(3))) void*)&As[(SL)][ra0], 16, 0, 0);        \
    __builtin_amdgcn_global_load_lds(                                              \
        (const __attribute__((address_space(1))) void*)(pa1 + koff),               \
        (__attribute__((address_space(3))) void*)&As[(SL)][ra1], 16, 0, 0);        \
    __builtin_amdgcn_global_load_lds(                                              \
        (const __attribute__((address_space(1))) void*)(pb0 + koff),               \
        (__attribute__((address_space(3))) void*)&Bs[(SL)][ra0], 16, 0, 0);        \
    __builtin_amdgcn_global_load_lds(                                              \
        (const __attribute__((address_space(1))) void*)(pb1 + koff),               \
        (__attribute__((address_space(3))) void*)&Bs[(SL)][ra1], 16, 0, 0);        \
    koff += 32;                                                                    \
  } while (0)

#define COMPUTE_SLOT(SL) do {                                                      \
    short8 af[4], bfr[4];                                                          \
    _Pragma("unroll")                                                              \
    for (int i = 0; i < 4; ++i)                                                    \
      af[i]  = *(const short8*)&As[(SL)][(wm + i * 16 + frow) * 32 + aoff];        \
    _Pragma("unroll")                                                              \
    for (int j = 0; j < 4; ++j)                                                    \
      bfr[j] = *(const short8*)&Bs[(SL)][(wn + j * 16 + frow) * 32 + aoff];        \
    __builtin_amdgcn_s_setprio(1);                                                 \
    _Pragma("unroll")                                                              \
    for (int i = 0; i < 4; ++i)                                                    \
      _Pragma("unroll")                                                            \
      for (int j = 0; j < 4; ++j)                                                  \
        acc[i][j] = __builtin_amdgcn_mfma_f32_16x16x32_bf16(af[i], bfr[j],         \
                                                            acc[i][j], 0, 0, 0);  \
    __builtin_amdgcn_s_setprio(0);                                                 \
  } while (0)

#define GSTEP(SL) do {                                                             \
    if (ks + 1 < NS) asm volatile("s_waitcnt vmcnt(4)" ::: "memory");              \
    else             asm volatile("s_waitcnt vmcnt(0)" ::: "memory");              \
    __builtin_amdgcn_s_barrier();                                                  \
    if (ks + 2 < NS) STAGE_TO(((SL) + 2) % 3);                                     \
    COMPUTE_SLOT(SL);                                                              \
    ++ks;                                                                          \
  } while (0)

  const int NS = K >> 5;   // 32-wide K-steps
  STAGE_TO(0);
  if (NS > 1) STAGE_TO(1);
  int ks = 0;
  while (ks < NS) {
    GSTEP(0);
    if (ks >= NS) break;
    GSTEP(1);
    if (ks >= NS) break;
    GSTEP(2);
  }

#undef GSTEP
#undef COMPUTE_SLOT
#undef STAGE_TO

  // epilogue: C/D layout col=lane&15, row=(lane>>4)*4+reg
#pragma unroll
  for (int i = 0; i < 4; ++i) {
#pragma unroll
    for (int j = 0; j < 4; ++j) {
      const int col = tn + wn + j * 16 + (ln & 15);
#pragma unroll
      for (int reg = 0; reg < 4; ++reg) {
        const int row = tm + wm + i * 16 + (ln >> 4) * 4 + reg;
        float v = acc[i][j][reg];
        if (MODE == 0) v += u[(c0 + z) * 512 + row] * aw[(c0 + z) * 512 + col];
        else if (MODE == 1) v = fmaxf(v + bias[row], 0.f);
        else if (MODE == 3) v += bias[col];
        if (MODE == 4) ((float*)C)[(long)z * sC + (long)row * ldc + col] = v;
        else ((ushort_t*)C)[(long)z * sC + (long)row * ldc + col] = f2bf(v);
      }
    }
  }
}

// =================== transposed-weight conversions (LDS tiled) ===================
// job 0: gc1LT[d][k] = bf(gc1_W[512+k][d])      (512x512 src lower half)
// job 1: gc2WT[e][d] = bf(gc2_W[d][e])          (src 512x1024)
// job 2: cWT[k][o]   = concat_W[o][k]           (src 512x1024, f32 out)
// job 3: nWT[k][j]   = nop_W[j][k], j>=124 -> 0 (src 124x512, dst 512x128)
__global__ __launch_bounds__(256)
void k_tw(const float* __restrict__ gc1_W, const float* __restrict__ gc2_W,
          const float* __restrict__ concat_W, const float* __restrict__ nop_W,
          ushort_t* __restrict__ gc1LT, ushort_t* __restrict__ gc2WT,
          float* __restrict__ cWT, float* __restrict__ nWT)
{
  __shared__ float tile[32][33];
  const int job = blockIdx.y;
  const float* src; int sr, sc;
  if (job == 0)      { src = gc1_W + 262144; sr = 512; sc = 512;  }
  else if (job == 1) { src = gc2_W;          sr = 512; sc = 1024; }
  else if (job == 2) { src = concat_W;       sr = 512; sc = 1024; }
  else               { src = nop_W;          sr = 124; sc = 512;  }
  const int tpr = sc >> 5;
  const int ntile = ((sr + 31) >> 5) * tpr;
  if ((int)blockIdx.x >= ntile) return;
  const int tr = (blockIdx.x / tpr) * 32, tc = (blockIdx.x % tpr) * 32;
  const int t = threadIdx.x, tx = t & 31, ty = t >> 5;   // 8 rows per pass
#pragma unroll
  for (int p = 0; p < 4; ++p) {
    const int r = tr + ty + p * 8;
    tile[ty + p * 8][tx] = (r < sr) ? src[(size_t)r * sc + tc + tx] : 0.f;
  }
  __syncthreads();
#pragma unroll
  for (int p = 0; p < 4; ++p) {
    const int dr = tc + ty + p * 8;   // dst row = src col
    const int dc = tr + tx;           // dst col = src row
    const float v = tile[tx][ty + p * 8];
    if (job == 0)      gc1LT[(size_t)dr * 512 + dc] = f2bf(v);
    else if (job == 1) gc2WT[(size_t)dr * 512 + dc] = f2bf(v);
    else if (job == 2) cWT[(size_t)dr * 512 + dc] = v;
    else               nWT[(size_t)dr * 128 + dc] = v;   // dc < 128 always (sr pad)
  }
}

// =================== bulk front kernel (frozen from r5) ===================
__global__ __launch_bounds__(256)
void k_front2(const int* __restrict__ step, const float* __restrict__ emb,
              const float* __restrict__ last_hidden,
              const float* __restrict__ wo_W, const float* __restrict__ ot_W,
              const float* __restrict__ W_ih, const float* __restrict__ W_hh,
              const float* __restrict__ ww, const int* __restrict__ ex,
              const float* __restrict__ word_op, const int* __restrict__ seq_mask,
              ushort_t* __restrict__ woWb, ushort_t* __restrict__ otWb,
              ushort_t* __restrict__ wihb, ushort_t* __restrict__ xhb,
              ushort_t* __restrict__ adj, float* __restrict__ won, int do_adj)
{
  const int blk = blockIdx.x;
  const int t = threadIdx.x;
  const size_t u0 = (size_t)blk * 256 + t;           // < 524288

  // ---- adjacency: 8 fixed units/thread, fully unrolled ----
  if (do_adj) {
    float4 w[8]; int4 e[8];
#pragma unroll
    for (int k = 0; k < 8; ++k) {
      w[k] = ((const float4*)ww)[u0 + (size_t)k * 524288];
      e[k] = ((const int4*)ex)[u0 + (size_t)k * 524288];
    }
#pragma unroll
    for (int k = 0; k < 8; ++k) {
      ushort4 r;
      r.x = (e[k].x == 1) ? f2bf(w[k].x) : 0;
      r.y = (e[k].y == 1) ? f2bf(w[k].y) : 0;
      r.z = (e[k].z == 1) ? f2bf(w[k].z) : 0;
      r.w = (e[k].w == 1) ? f2bf(w[k].w) : 0;
      ((ushort4*)adj)[u0 + (size_t)k * 524288] = r;
    }
  }

  // ---- copies: unit A (always) + unit B (u0 < 163840) ----
  if (u0 < 131072) {
    ((ushort4*)woWb)[u0] = f4bf(((const float4*)wo_W)[u0]);
    const size_t i2 = u0 + 262144;
    ((ushort4*)wihb)[i2] = f4bf(((const float4*)W_hh)[i2 - 196608]);
  } else if (u0 < 262144) {
    const size_t i = u0 - 131072;
    ((ushort4*)otWb)[i] = f4bf(((const float4*)ot_W)[i]);
    if (u0 < 163840) {
      const size_t e = i * 4;
      const int z = (int)(e >> 16), b = (int)((e >> 9) & 127), k = (int)(e & 511);
      float4 v = make_float4(0.f, 0.f, 0.f, 0.f);
      if (b < 64)
        v = z ? *(const float4*)&last_hidden[b * 512 + k]
              : *(const float4*)&emb[(size_t)step[b] * 512 + k];
      ((ushort4*)xhb)[i] = f4bf(v);
    }
  } else {
    const size_t i = u0 - 262144;    // < 262144: wihb first part
    const float4 v = (i < 196608) ? ((const float4*)W_ih)[i]
                                  : ((const float4*)W_hh)[i - 196608];
    ((ushort4*)wihb)[i] = f4bf(v);
  }

  // ---- wo_n normalization: blocks 0..63, one per batch ----
  if (blk < 64) {
    const int b = blk;
    __shared__ float red[4][4];               // [wave][o]
    float4 a0 = ((const float4*)word_op)[b * 512 + t];
    float4 a1 = ((const float4*)word_op)[b * 512 + t + 256];
    if (seq_mask[b * 512 + t])       a0 = make_float4(0.f, 0.f, 0.f, 0.f);
    if (seq_mask[b * 512 + t + 256]) a1 = make_float4(0.f, 0.f, 0.f, 0.f);
    float l0 = a0.x + a1.x, l1 = a0.y + a1.y, l2 = a0.z + a1.z, l3 = a0.w + a1.w;
#pragma unroll
    for (int off = 32; off; off >>= 1) {
      l0 += __shfl_down(l0, off, 64);
      l1 += __shfl_down(l1, off, 64);
      l2 += __shfl_down(l2, off, 64);
      l3 += __shfl_down(l3, off, 64);
    }
    if ((t & 63) == 0) {
      red[t >> 6][0] = l0; red[t >> 6][1] = l1;
      red[t >> 6][2] = l2; red[t >> 6][3] = l3;
    }
    __syncthreads();
    const float tot0 = red[0][0] + red[1][0] + red[2][0] + red[3][0] + 1e-30f;
    const float tot1 = red[0][1] + red[1][1] + red[2][1] + red[3][1] + 1e-30f;
    const float tot2 = red[0][2] + red[1][2] + red[2][2] + red[3][2] + 1e-30f;
    const float tot3 = red[0][3] + red[1][3] + red[2][3] + red[3][3] + 1e-30f;
    float* w0 = won + ((size_t)b * 4 + 0) * 512;
    float* w1 = won + ((size_t)b * 4 + 1) * 512;
    float* w2 = won + ((size_t)b * 4 + 2) * 512;
    float* w3 = won + ((size_t)b * 4 + 3) * 512;
    w0[t] = a0.x / tot0; w0[t + 256] = a1.x / tot0;
    w1[t] = a0.y / tot1; w1[t + 256] = a1.y / tot1;
    w2[t] = a0.z / tot2; w2[t + 256] = a1.z / tot2;
    w3[t] = a0.w / tot3; w3[t + 256] = a1.w / tot3;
  }
}

// =================== small fused kernels ===================

// GRU gate combine; gi2 holds gi (1536x128) then gh (1536x128) f32
__global__ __launch_bounds__(256)
void k_gru(const float* __restrict__ gi2, const float* __restrict__ last_hidden,
           const float* __restrict__ b_ih, const float* __restrict__ b_hh,
           float* __restrict__ hnew, float* __restrict__ hnew_out)
{
  const int idx = blockIdx.x * 256 + threadIdx.x;
  const int b = idx >> 9, tt = idx & 511;
  const float* gh = gi2 + 196608;
  const float ir  = gi2[tt * 128 + b]          + b_ih[tt];
  const float iz  = gi2[(512 + tt) * 128 + b]  + b_ih[512 + tt];
  const float inn = gi2[(1024 + tt) * 128 + b] + b_ih[1024 + tt];
  const float hr  = gh[tt * 128 + b]          + b_hh[tt];
  const float hz  = gh[(512 + tt) * 128 + b]  + b_hh[512 + tt];
  const float hn  = gh[(1024 + tt) * 128 + b] + b_hh[1024 + tt];
  const float h   = last_hidden[idx];
  const float r = 1.f / (1.f + __expf(-(ir + hr)));
  const float z = 1.f / (1.f + __expf(-(iz + hz)));
  const float n = tanhf(inn + r * hn);
  const float o = (1.f - z) * n + z * h;
  hnew[idx] = o;
  hnew_out[idx] = o;
}

// q = h_new @ attn_W ; u = h_new @ gc1_W[:512].  grid (64,4) x 128 threads.
__global__ __launch_bounds__(128)
void k_qu(const float* __restrict__ hnew, const float* __restrict__ attn_W,
          const float* __restrict__ gc1_W, float* __restrict__ q, float* __restrict__ u)
{
  const int b = blockIdx.x, j = blockIdx.y * 128 + threadIdx.x;
  __shared__ float hs[512];
  for (int i = threadIdx.x; i < 512; i += 128) hs[i] = hnew[b * 512 + i];
  __syncthreads();
  float qa = 0.f, ua = 0.f;
  for (int h = 0; h < 512; ++h) {
    const float hv = hs[h];
    qa += hv * attn_W[(size_t)h * 512 + j];
    ua += hv * gc1_W[(size_t)h * 512 + j];
  }
  q[b * 512 + j] = qa;
  u[b * 512 + j] = ua;
}

// scores[b,s] = q[b]·enc[s,b]; also emits encbf[b][s][k] (bf16) when emit!=0.
__global__ __launch_bounds__(256)
void k_score(const float* __restrict__ q, const float* __restrict__ enc,
             float* __restrict__ scores, ushort_t* __restrict__ encb, int emit)
{
  const int b = blockIdx.x, p = blockIdx.y;
  const int t = threadIdx.x, wv = t >> 6, ln = t & 63;
  __shared__ float qs[512];
  for (int i = t; i < 512; i += 256) qs[i] = q[b * 512 + i];
  __syncthreads();
  const int e0 = ln * 8;
  const float4 q0 = *(const float4*)&qs[e0];
  const float4 q1 = *(const float4*)&qs[e0 + 4];
  for (int it = 0; it < 8; ++it) {
    const int s = p * 32 + wv * 8 + it;
    const float* e = enc + ((size_t)s * 64 + b) * 512 + e0;
    const float4 v0 = *(const float4*)e;
    const float4 v1 = *(const float4*)(e + 4);
    float a = q0.x * v0.x + q0.y * v0.y + q0.z * v0.z + q0.w * v0.w
            + q1.x * v1.x + q1.y * v1.y + q1.z * v1.z + q1.w * v1.w;
    if (emit) {
      short8 o;
      o[0] = (short)f2bf(v0.x); o[1] = (short)f2bf(v0.y);
      o[2] = (short)f2bf(v0.z); o[3] = (short)f2bf(v0.w);
      o[4] = (short)f2bf(v1.x); o[5] = (short)f2bf(v1.y);
      o[6] = (short)f2bf(v1.z); o[7] = (short)f2bf(v1.w);
      *(short8*)&encb[(size_t)b * 262144 + (size_t)s * 512 + e0] = o;
    }
    a = wave_sum(a);
    if (ln == 0) scores[b * 512 + s] = a;
  }
}

// Fused softmax + context partials.  grid (64,16) x 512.
__global__ __launch_bounds__(512)
void k_ctx2(const float* __restrict__ scores, const ushort_t* __restrict__ encb,
            const float* __restrict__ enc, float* __restrict__ aw_dout,
            float* __restrict__ aw_ws, float* __restrict__ ctxpart, int use_bf)
{
  const int b = blockIdx.x, p = blockIdx.y, t = threadIdx.x;
  const int w = t >> 6, lane = t & 63;
  __shared__ float sc[512];
  __shared__ float red[8];
  __shared__ float red2[8];
  const float v = scores[b * 512 + t];
  float m = wave_max(v);
  if (lane == 0) red[w] = m;
  __syncthreads();
  float mm = red[0];
#pragma unroll
  for (int i = 1; i < 8; ++i) mm = fmaxf(mm, red[i]);
  const float e = __expf(v - mm);
  float s = wave_sum(e);
  if (lane == 0) red2[w] = s;
  __syncthreads();
  float tot = 0.f;
#pragma unroll
  for (int i = 0; i < 8; ++i) tot += red2[i];
  const float awv = e / tot;
  sc[t] = awv;
  if (p == 0) {
    aw_dout[b * 512 + t] = awv;
    aw_ws[b * 512 + t]   = awv;
  }
  __syncthreads();
  float acc = 0.f;
  if (use_bf) {
#pragma unroll 4
    for (int si = 0; si < 32; ++si)
      acc += sc[p * 32 + si] * bf2f(encb[((size_t)b * 512 + p * 32 + si) * 512 + t]);
  } else {
#pragma unroll 4
    for (int si = 0; si < 32; ++si)
      acc += sc[p * 32 + si] * enc[((size_t)(p * 32 + si) * 64 + b) * 512 + t];
  }
  ctxpart[((size_t)b * 16 + p) * 512 + t] = acc;
}

// concat_output = relu([h_new, sum_p ctxpart] @ cWT + b).  grid (64,4) x 128.
__global__ __launch_bounds__(128)
void k_concat(const float* __restrict__ hnew, const float* __restrict__ ctxpart,
              const float* __restrict__ cWT, const float* __restrict__ bias,
              float* __restrict__ out_cc, float* __restrict__ cc_ws)
{
  const int b = blockIdx.x, o = blockIdx.y * 128 + threadIdx.x;
  __shared__ __align__(16) float cat[1024];
  for (int m = 0; m < 8; ++m) {
    const int i = threadIdx.x + 128 * m;
    if (i < 512) {
      cat[i] = hnew[b * 512 + i];
    } else {
      const int d = i - 512;
      float s = 0.f;
#pragma unroll
      for (int pp = 0; pp < 16; ++pp) s += ctxpart[((size_t)b * 16 + pp) * 512 + d];
      cat[i] = s;
    }
  }
  __syncthreads();
  float acc = bias[o];
  for (int k = 0; k < 1024; k += 4) {
    acc += cat[k]     * cWT[(size_t)k * 512 + o]
         + cat[k + 1] * cWT[(size_t)(k + 1) * 512 + o]
         + cat[k + 2] * cWT[(size_t)(k + 2) * 512 + o]
         + cat[k + 3] * cWT[(size_t)(k + 3) * 512 + o];
  }
  acc = fmaxf(acc, 0.f);
  out_cc[b * 512 + o] = acc;
  cc_ws[b * 512 + o]  = acc;
}

// adj (bf16) for chunk (CB<64 fallback)
__global__ __launch_bounds__(256)
void k_adjc(const float* __restrict__ ww, const int* __restrict__ ex,
            ushort_t* __restrict__ adj, int c0)
{
  const size_t i = (size_t)blockIdx.x * 256 + threadIdx.x;
  const size_t base4 = (size_t)c0 * 512 * 512 / 4;
  const float4 w4 = ((const float4*)ww)[base4 + i];
  const int4   e4 = ((const int4*)ex)[base4 + i];
  ushort4 r;
  r.x = (e4.x == 1) ? f2bf(w4.x) : 0;
  r.y = (e4.y == 1) ? f2bf(w4.y) : 0;
  r.z = (e4.z == 1) ? f2bf(w4.z) : 0;
  r.w = (e4.w == 1) ? f2bf(w4.w) : 0;
  ((ushort4*)adj)[i] = r;
}

// enc (bf16, batch-packed) for chunk (CB<64 fallback)
__global__ __launch_bounds__(256)
void k_encc(const float* __restrict__ enc, ushort_t* __restrict__ encb, int c0)
{
  const size_t i = (size_t)blockIdx.x * 256 + threadIdx.x;
  const size_t el = i * 4;
  const int k = el & 511;
  const int s = (el >> 9) & 511;
  const int z = el >> 18;
  const float4 v = *(const float4*)&enc[((size_t)s * 64 + c0 + z) * 512 + k];
  ushort4 r;
  r.x = f2bf(v.x); r.y = f2bf(v.y); r.z = f2bf(v.z); r.w = f2bf(v.w);
  ((ushort4*)encb)[i] = r;
}

// Barrier-free fused LN + residual + wo_n contraction.
__global__ __launch_bounds__(256)
void k_red2(const ushort_t* __restrict__ w2w, const float* __restrict__ aw,
            const float* __restrict__ hnew, const ushort_t* __restrict__ encb,
            const float* __restrict__ won, const float* __restrict__ ng,
            const float* __restrict__ nb, float* __restrict__ part, int c0)
{
  const int z = blockIdx.x, b = c0 + z, yb = blockIdx.y;
  const int t = threadIdx.x, wv = t >> 6, ln = t & 63;
  __shared__ float sw[32][5];               // won0..3, aw per s-local
  __shared__ float accs[2][4][1024];        // cross-wave combine (32 KB)
  if (t < 160) {
    const int sl = t / 5, c_ = t - sl * 5;
    const int sg = yb * 32 + sl;
    sw[sl][c_] = (c_ < 4) ? won[((size_t)b * 4 + c_) * 512 + sg] : aw[b * 512 + sg];
  }
  const int d0 = ln * 16;
  float gg[16], bb[16], hv[16];
#pragma unroll
  for (int k = 0; k < 16; k += 4) {
    *(float4*)&gg[k] = *(const float4*)&ng[d0 + k];
    *(float4*)&bb[k] = *(const float4*)&nb[d0 + k];
  }
  if (ln < 32) {
#pragma unroll
    for (int k = 0; k < 16; k += 4)
      *(float4*)&hv[k] = *(const float4*)&hnew[b * 512 + d0 + k];
  }
  float acc[4][16];
#pragma unroll
  for (int o = 0; o < 4; ++o)
#pragma unroll
    for (int k = 0; k < 16; ++k) acc[o][k] = 0.f;
  __syncthreads();
  for (int it = 0; it < 8; ++it) {
    const int sl = wv * 8 + it;
    const int s = yb * 32 + sl;
    const ushort_t* row = w2w + ((size_t)z * 512 + s) * 1024 + d0;
    float x[16];
    bf8_to_f(row, x);
    bf8_to_f(row + 8, x + 8);
    float ls = 0.f, lss = 0.f;
#pragma unroll
    for (int k = 0; k < 16; ++k) { ls += x[k]; lss += x[k] * x[k]; }
#pragma unroll
    for (int off = 32; off; off >>= 1) {
      ls  += __shfl_xor(ls,  off, 64);
      lss += __shfl_xor(lss, off, 64);
    }
    const float mean = ls * (1.f / 1024.f);
    const float var  = lss * (1.f / 1024.f) - mean * mean;
    const float inv  = rsqrtf(var + 1e-6f);
    float res[16];
    if (ln < 32) {
      const float a_ = sw[sl][4];
#pragma unroll
      for (int k = 0; k < 16; ++k) res[k] = a_ * hv[k];
    } else {
      const ushort_t* er = encb + ((size_t)z * 512 + s) * 512 + (d0 - 512);
      bf8_to_f(er, res);
      bf8_to_f(er + 8, res + 8);
    }
    const float w0 = sw[sl][0], w1 = sw[sl][1], w2 = sw[sl][2], w3 = sw[sl][3];
#pragma unroll
    for (int k = 0; k < 16; ++k) {
      const float val = (x[k] - mean) * inv * gg[k] + bb[k] + res[k];
      acc[0][k] += w0 * val; acc[1][k] += w1 * val;
      acc[2][k] += w2 * val; acc[3][k] += w3 * val;
    }
  }
  if (wv < 2) {
#pragma unroll
    for (int o = 0; o < 4; ++o)
#pragma unroll
      for (int k = 0; k < 16; k += 4)
        *(float4*)&accs[wv][o][d0 + k] = *(float4*)&acc[o][k];
  }
  __syncthreads();
  if (wv >= 2) {
#pragma unroll
    for (int o = 0; o < 4; ++o)
#pragma unroll
      for (int k = 0; k < 16; ++k)
        accs[wv - 2][o][d0 + k] += acc[o][k];
  }
  __syncthreads();
  for (int i = t; i < 4096; i += 256) {
    const int o = i >> 10, d = i & 1023;
    part[(((size_t)(b * 16 + yb) * 4 + o) << 10) + d] = accs[0][o][d] + accs[1][o][d];
  }
}

// sum 16 partials -> ctx_op bf16 (256 x 1024)
__global__ __launch_bounds__(256)
void k_psum(const float* __restrict__ part, ushort_t* __restrict__ ctxop)
{
  const int idx = blockIdx.x * 256 + threadIdx.x;   // 262144
  const int r = idx >> 10, d = idx & 1023;
  const int b = r >> 2, o = r & 3;
  float s = 0.f;
#pragma unroll
  for (int p = 0; p < 16; ++p)
    s += part[(((size_t)(b * 16 + p) * 4 + o) << 10) + d];
  ctxop[idx] = f2bf(s);
}

// relu+bias, LN1, build op_all bf16 = [s1, ops[o]]
__global__ __launch_bounds__(512)
void k_ln1(const float* __restrict__ oppre, const float* __restrict__ wo_b,
           const float* __restrict__ n1g, const float* __restrict__ n1b,
           const float* __restrict__ ops, ushort_t* __restrict__ opall)
{
  const int r = blockIdx.x, t = threadIdx.x;
  const int o = r & 3;
  __shared__ float2 red[8];
  const float val = fmaxf(oppre[(size_t)r * 512 + t] + wo_b[t], 0.f);
  const float2 ss = blocksum2(val, val * val, red, t, 8);
  const float m = ss.x * (1.f / 512.f);
  const float v = ss.y * (1.f / 512.f) - m * m;
  const float s1 = (val - m) * rsqrtf(v + 1e-6f) * n1g[t] + n1b[t];
  opall[(size_t)r * 1024 + t] = f2bf(s1);
  opall[(size_t)r * 1024 + 512 + t] = f2bf(ops[o * 512 + t]);
}

// relu+bias, LN2 + ops, dot with concat_output -> oo
__global__ __launch_bounds__(512)
void k_ln2dot(const float* __restrict__ ohpre, const float* __restrict__ ot_b,
              const float* __restrict__ n2g, const float* __restrict__ n2b,
              const float* __restrict__ ops, const float* __restrict__ cc,
              const float* __restrict__ ops_bias, float* __restrict__ oo)
{
  const int r = blockIdx.x, t = threadIdx.x;
  const int b = r >> 2, o = r & 3;
  __shared__ float2 red[8];
  const float oh = fmaxf(ohpre[(size_t)r * 512 + t] + ot_b[t], 0.f);
  const float2 ss = blocksum2(oh, oh * oh, red, t, 8);
  const float m = ss.x * (1.f / 512.f);
  const float v = ss.y * (1.f / 512.f) - m * m;
  const float opo = (oh - m) * rsqrtf(v + 1e-6f) * n2g[t] + n2b[t] + ops[o * 512 + t];
  const float p = cc[b * 512 + t] * opo;
  const float2 s3 = blocksum2(p, 0.f, red, t, 8);
  if (t == 0) oo[r] = s3.x + ops_bias[o];
}

// nop head (coalesced via nWT) + log_softmax over 128
__global__ __launch_bounds__(128)
void k_final(const float* __restrict__ oo, const float* __restrict__ cc,
             const float* __restrict__ nWT, const float* __restrict__ nop_b,
             float* __restrict__ outp)
{
  const int b = blockIdx.x, t = threadIdx.x;
  __shared__ __align__(16) float ccs[512];
  __shared__ float red[2];
  __shared__ float red2[2];
  for (int i = t; i < 512; i += 128) ccs[i] = cc[b * 512 + i];
  __syncthreads();
  float v;
  if (t < 4) {
    v = oo[b * 4 + t];
  } else {
    const int j = t - 4;
    float a = nop_b[j];
    for (int k = 0; k < 512; ++k) a += ccs[k] * nWT[k * 128 + j];
    v = a;
  }
  float m = wave_max(v);
  if ((t & 63) == 0) red[t >> 6] = m;
  __syncthreads();
  m = fmaxf(red[0], red[1]);
  const float e = __expf(v - m);
  float s = wave_sum(e);
  if ((t & 63) == 0) red2[t >> 6] = s;
  __syncthreads();
  s = red2[0] + red2[1];
  outp[b * 128 + t] = v - m - logf(s);
}

} // namespace

extern "C" void kernel_launch(void* const* d_in, const int* in_sizes, int n_in,
                              void* d_out, int out_size, void* d_ws, size_t ws_size,
                              hipStream_t stream)
{
  const int*   input_step  = (const int*)  d_in[0];
  const float* last_hidden = (const float*)d_in[1];
  const float* enc         = (const float*)d_in[2];
  const float* word_word   = (const float*)d_in[3];
  const float* word_op     = (const float*)d_in[4];
  const int*   word_exist  = (const int*)  d_in[5];
  const int*   seq_mask    = (const int*)  d_in[6];
  const float* emb         = (const float*)d_in[7];
  const float* W_ih        = (const float*)d_in[8];
  const float* W_hh        = (const float*)d_in[9];
  const float* b_ih        = (const float*)d_in[10];
  const float* b_hh        = (const float*)d_in[11];
  const float* attn_W      = (const float*)d_in[12];
  const float* concat_W    = (const float*)d_in[14];
  const float* concat_b    = (const float*)d_in[15];
  const float* ops         = (const float*)d_in[16];
  const float* ops_bias    = (const float*)d_in[17];
  const float* nop_W       = (const float*)d_in[18];
  const float* nop_b       = (const float*)d_in[19];
  const float* gc1_W       = (const float*)d_in[20];
  const float* gc1_b       = (const float*)d_in[21];
  const float* gc2_W       = (const float*)d_in[22];
  const float* gc2_b       = (const float*)d_in[23];
  const float* norm_g      = (const float*)d_in[24];
  const float* norm_b      = (const float*)d_in[25];
  const float* norm1_g     = (const float*)d_in[26];
  const float* norm1_b     = (const float*)d_in[27];
  const float* norm2_g     = (const float*)d_in[28];
  const float* norm2_b     = (const float*)d_in[29];
  const float* wo_W        = (const float*)d_in[30];
  const float* wo_b        = (const float*)d_in[31];
  const float* ot_W        = (const float*)d_in[32];
  const float* ot_b        = (const float*)d_in[33];

  float* ws  = (float*)d_ws;
  float* out = (float*)d_out;

  // ---- workspace layout (floats) ----
  size_t off = 0;
  auto take = [&](size_t n) { size_t o = off; off += n; return o; };
  const size_t o_hnew = take(32768);
  const size_t o_q    = take(32768);
  const size_t o_u    = take(32768);
  const size_t o_aw   = take(32768);
  const size_t o_scores = take(32768);
  const size_t o_ctxpart = take(524288);   // 64*16*512
  const size_t o_cc   = take(32768);
  const size_t o_won  = take(131072);
  const size_t o_oo   = take(256);
  const size_t o_gi2  = take(393216);      // 2 x 1536 x 128 f32
  const size_t o_part = take(4194304);     // 64*16*4*1024
  const size_t o_oppre = take(131072);
  const size_t o_ohpre = take(131072);
  const size_t o_gc1LT = take(131072);
  const size_t o_gc2WT = take(262144);
  const size_t o_woW   = take(262144);
  const size_t o_otW   = take(262144);
  const size_t o_cWT   = take(524288);
  const size_t o_nWT   = take(65536);
  const size_t o_wihb  = take(786432);     // 2 x 1536 x 512 bf16
  const size_t o_xhb   = take(65536);      // 2 x 128 x 512 bf16
  const size_t o_ctxop = take(131072);
  const size_t o_opall = take(131072);
  const size_t base = off;

  // pick chunk size by available workspace (constant across calls -> graph-safe)
  int CB = 16;
  if (ws_size >= (base + 64ull * 524288) * 4) CB = 64;
  else if (ws_size >= (base + 32ull * 524288) * 4) CB = 32;
  const int nch = 64 / CB;

  const size_t o_adjbf = take((size_t)CB * 131072);
  const size_t o_h1t   = take((size_t)CB * 131072);
  const size_t o_encbf = take((size_t)CB * 131072);
  const size_t o_xw1t  = take((size_t)CB * 131072);
  const size_t o_tmat  = o_xw1t;           // overlays xw1t (dead after mgemm<1>)
  const size_t o_w2w   = o_adjbf;          // overlays adjbf+h1t (dead after mgemm<2>)

  float* hnew = ws + o_hnew;
  float* q    = ws + o_q;
  float* u    = ws + o_u;
  float* aw   = ws + o_aw;
  float* scores = ws + o_scores;
  float* ctxpart = ws + o_ctxpart;
  float* cc   = ws + o_cc;
  float* won  = ws + o_won;
  float* oo   = ws + o_oo;
  float* gi2  = ws + o_gi2;
  float* part = ws + o_part;
  float* oppre = ws + o_oppre;
  float* ohpre = ws + o_ohpre;
  float* cWT  = ws + o_cWT;
  float* nWT  = ws + o_nWT;
  ushort_t* gc1LT = (ushort_t*)(ws + o_gc1LT);
  ushort_t* gc2WT = (ushort_t*)(ws + o_gc2WT);
  ushort_t* woWb  = (ushort_t*)(ws + o_woW);
  ushort_t* otWb  = (ushort_t*)(ws + o_otW);
  ushort_t* wihb  = (ushort_t*)(ws + o_wihb);
  ushort_t* xhb   = (ushort_t*)(ws + o_xhb);
  ushort_t* ctxop = (ushort_t*)(ws + o_ctxop);
  ushort_t* opall = (ushort_t*)(ws + o_opall);
  ushort_t* adjbf = (ushort_t*)(ws + o_adjbf);
  ushort_t* h1t   = (ushort_t*)(ws + o_h1t);
  ushort_t* encbf = (ushort_t*)(ws + o_encbf);
  ushort_t* xw1t  = (ushort_t*)(ws + o_xw1t);
  ushort_t* tmat  = (ushort_t*)(ws + o_tmat);
  ushort_t* w2wbf = (ushort_t*)(ws + o_w2w);

  float* out_logits = out;
  float* out_hnew   = out + 8192;
  float* out_aw     = out + 8192 + 32768;
  float* out_cc     = out + 8192 + 65536;

  const int full = (CB == 64) ? 1 : 0;

  // ---- front: transposed weights (LDS tiled) + bulk streams ----
  k_tw<<<dim3(512, 4), 256, 0, stream>>>(gc1_W, gc2_W, concat_W, nop_W,
      gc1LT, gc2WT, cWT, nWT);
  k_front2<<<2048, 256, 0, stream>>>(input_step, emb, last_hidden,
      wo_W, ot_W, W_ih, W_hh, word_word, word_exist, word_op, seq_mask,
      woWb, otWb, wihb, xhb, adjbf, won, full);

  // ---- GRU via MFMA: gi/gh = [W_ih;W_hh] @ [x;h]^T, N padded to 128 ----
  mgemm<4><<<dim3(1, 12, 2), 256, 0, stream>>>(wihb, 512, 786432, xhb, 512, 65536,
      gi2, 128, 196608, 512, nullptr, nullptr, nullptr, 0);
  k_gru<<<128, 256, 0, stream>>>(gi2, last_hidden, b_ih, b_hh, hnew, out_hnew);

  // ---- attention + concat ----
  k_qu<<<dim3(64, 4), 128, 0, stream>>>(hnew, attn_W, gc1_W, q, u);
  k_score<<<dim3(64, 16), 256, 0, stream>>>(q, enc, scores, encbf, full);
  k_ctx2<<<dim3(64, 16), 512, 0, stream>>>(scores, encbf, enc, out_aw, aw, ctxpart, full);
  k_concat<<<dim3(64, 4), 128, 0, stream>>>(hnew, ctxpart, cWT, concat_b, out_cc, cc);

  // ---- GCN chain (bf16 MFMA, 128x128 tiles), chunked ----
  for (int c = 0; c < nch; ++c) {
    const int c0 = c * CB;
    if (!full) {
      k_adjc<<<CB * 256, 256, 0, stream>>>(word_word, word_exist, adjbf, c0);
      k_encc<<<CB * 256, 256, 0, stream>>>(enc, encbf, c0);
    }
    // XW1T[d][s] = gc1LT[d][:] . enc_b[s][:] + u[b][d]*aw[b][s]
    mgemm<0><<<dim3(4, 4, CB), 256, 0, stream>>>(gc1LT, 512, 0, encbf, 512, 262144,
        xw1t, 512, 262144, 512, nullptr, aw, u, c0);
    // h1T[d][s] = relu(XW1T[d][:] . adj[s][:] + gc1_b[d])
    mgemm<1><<<dim3(4, 4, CB), 256, 0, stream>>>(xw1t, 512, 262144, adjbf, 512, 262144,
        h1t, 512, 262144, 512, gc1_b, nullptr, nullptr, 0);
    // t[s][d] = adj[s][:] . h1T[d][:]   (overlays xw1t, dead)
    mgemm<2><<<dim3(4, 4, CB), 256, 0, stream>>>(adjbf, 512, 262144, h1t, 512, 262144,
        tmat, 512, 262144, 512, nullptr, nullptr, nullptr, 0);
    // w2w[s][e] = t[s][:] . gc2WT[e][:] + gc2_b[e]   (overlays adjbf+h1t, dead)
    mgemm<3><<<dim3(8, 4, CB), 256, 0, stream>>>(tmat, 512, 262144, gc2WT, 512, 0,
        w2wbf, 1024, 524288, 512, gc2_b, nullptr, nullptr, 0);
    k_red2<<<dim3(CB, 16), 256, 0, stream>>>(w2wbf, aw, hnew, encbf, won, norm_g, norm_b, part, c0);
  }

  // ---- op head (MFMA GEMMs) + nop head + log_softmax ----
  k_psum<<<1024, 256, 0, stream>>>(part, ctxop);
  mgemm<4><<<dim3(4, 2, 1), 256, 0, stream>>>(ctxop, 1024, 0, woWb, 1024, 0,
      oppre, 512, 0, 1024, nullptr, nullptr, nullptr, 0);
  k_ln1<<<256, 512, 0, stream>>>(oppre, wo_b, norm1_g, norm1_b, ops, opall);
  mgemm<4><<<dim3(4, 2, 1), 256, 0, stream>>>(opall, 1024, 0, otWb, 1024, 0,
      ohpre, 512, 0, 1024, nullptr, nullptr, nullptr, 0);
  k_ln2dot<<<256, 512, 0, stream>>>(ohpre, ot_b, norm2_g, norm2_b, ops, cc, ops_bias, oo);
  k_final<<<64, 128, 0, stream>>>(oo, cc, nWT, nop_b, out_logits);

  (void)in_sizes; (void)n_in; (void)out_size;
}

// Round 9
// 654.651 us; speedup vs baseline: 1.1376x; 1.1376x over previous
//
#include <hip/hip_runtime.h>
#include <math.h>

namespace {

typedef unsigned short ushort_t;
typedef __attribute__((ext_vector_type(8))) short short8;
typedef __attribute__((ext_vector_type(4))) float float4v;

__device__ __forceinline__ unsigned short f2bf(float x) {
  unsigned u = __float_as_uint(x);
  u += 0x7fffu + ((u >> 16) & 1u);        // RNE
  return (unsigned short)(u >> 16);
}
__device__ __forceinline__ float bf2f(unsigned short u) {
  return __uint_as_float((unsigned)u << 16);
}
__device__ __forceinline__ void bf8_to_f(const ushort_t* p, float* o) {
  const short8 v = *(const short8*)p;
#pragma unroll
  for (int k = 0; k < 8; ++k) o[k] = bf2f((unsigned short)v[k]);
}
__device__ __forceinline__ ushort4 f4bf(float4 v) {
  ushort4 r;
  r.x = f2bf(v.x); r.y = f2bf(v.y); r.z = f2bf(v.z); r.w = f2bf(v.w);
  return r;
}

__device__ __forceinline__ float wave_sum(float v) {
#pragma unroll
  for (int off = 32; off; off >>= 1) v += __shfl_down(v, off, 64);
  return v;
}
__device__ __forceinline__ float wave_max(float v) {
#pragma unroll
  for (int off = 32; off; off >>= 1) v = fmaxf(v, __shfl_down(v, off, 64));
  return v;
}
__device__ __forceinline__ float2 blocksum2(float a, float b, float2* red, int t, int nw) {
#pragma unroll
  for (int off = 32; off; off >>= 1) {
    a += __shfl_down(a, off, 64);
    b += __shfl_down(b, off, 64);
  }
  __syncthreads();
  if ((t & 63) == 0) red[t >> 6] = make_float2(a, b);
  __syncthreads();
  float sa = 0.f, sb = 0.f;
  for (int i = 0; i < nw; ++i) { sa += red[i].x; sb += red[i].y; }
  return make_float2(sa, sb);
}

// =================== bf16 MFMA NT-GEMM, 128x128 tile ===================
// C[M,N] = A[M,K] * Bt[N,K]^T.  M,N multiples of 128, K mult of 64.
// 3-buffer ring, prefetch depth 2, ONE barrier per K-step:
//   waitcnt(cur ready) -> barrier -> STAGE(ks+2) -> setprio(1) MFMA setprio(0).
// Hazard chain: buffer read at step k is restaged at step k+1 strictly after
// the step-k+1 barrier, which all waves reach only after COMPUTE(k).
// XCD-aware z-grouped block swizzle (nz % 8 == 0) + LDS seg-XOR (0 conflicts).
// MODE 0: bf16 out, v += u[(c0+z)*512+row]*aw[(c0+z)*512+col]
// MODE 1: bf16 out, relu(v + bias[row])
// MODE 2: bf16 out, plain
// MODE 3: bf16 out, v + bias[col]
// MODE 4: f32 out, plain
template<int MODE>
__global__ __launch_bounds__(256)
void mgemm(const ushort_t* __restrict__ A, int lda, long sA,
           const ushort_t* __restrict__ Bt, int ldb, long sB,
           void* __restrict__ C, int ldc, long sC, int K,
           const float* __restrict__ bias,
           const float* __restrict__ aw, const float* __restrict__ u, int c0)
{
  __shared__ __attribute__((aligned(16))) ushort_t As[3][128 * 32];
  __shared__ __attribute__((aligned(16))) ushort_t Bs[3][128 * 32];

  // ---- XCD-aware swizzle: group all xy-tiles of one z on one XCD ----
  int bx = blockIdx.x, by = blockIdx.y, bz = blockIdx.z;
  const int nx = gridDim.x, ny = gridDim.y, nz = gridDim.z;
  if ((nz & 7) == 0) {
    const int nxy = nx * ny;
    const int L = bx + nx * (by + ny * bz);
    const int xcd = L & 7;
    const int idx = L >> 3;
    const int lz = idx / nxy;
    const int xy = idx - lz * nxy;
    bz = xcd + 8 * lz;
    bx = xy % nx;
    by = xy / nx;
  }

  const int z = bz;
  const ushort_t* Ab = A  + (long)z * sA;
  const ushort_t* Bb = Bt + (long)z * sB;
  const int tm = by * 128, tn = bx * 128;
  const int t = threadIdx.x, wv = t >> 6, ln = t & 63;
  const int lrow = ln >> 2, lseg = ln & 3;        // staging: 16 rows x 4 segs of 16B
  const int gseg = lseg ^ ((lrow >> 1) & 3);      // bank-conflict-free seg XOR
  const int frow = ln & 15, q = ln >> 4;          // fragment: m=ln&15, k-quad
  const int sw8 = (frow >> 1) & 3;
  const int aoff = (q ^ sw8) << 3;
  const int wm = (wv >> 1) * 64, wn = (wv & 1) * 64;

  float4v acc[4][4];
#pragma unroll
  for (int i = 0; i < 4; ++i)
#pragma unroll
    for (int j = 0; j < 4; ++j) acc[i][j] = (float4v)0.f;

  // stage one 128x32 slice of A and B into buffer s (4 gload_lds per thread)
  auto STAGE = [&](int s, int ks) {
    const int kc = ks * 32 + gseg * 8;
#pragma unroll
    for (int half = 0; half < 2; ++half) {
      const int rbase = wv * 32 + half * 16;
      const ushort_t* ga = Ab + (long)(tm + rbase + lrow) * lda + kc;
      const ushort_t* gb = Bb + (long)(tn + rbase + lrow) * ldb + kc;
      __builtin_amdgcn_global_load_lds(
          (const __attribute__((address_space(1))) void*)ga,
          (__attribute__((address_space(3))) void*)&As[s][rbase * 32], 16, 0, 0);
      __builtin_amdgcn_global_load_lds(
          (const __attribute__((address_space(1))) void*)gb,
          (__attribute__((address_space(3))) void*)&Bs[s][rbase * 32], 16, 0, 0);
    }
  };
  auto COMPUTE = [&](const ushort_t* Asb, const ushort_t* Bsb) {
    short8 af[4], bfr[4];
#pragma unroll
    for (int i = 0; i < 4; ++i) af[i]  = *(const short8*)&Asb[(wm + i * 16 + frow) * 32 + aoff];
#pragma unroll
    for (int j = 0; j < 4; ++j) bfr[j] = *(const short8*)&Bsb[(wn + j * 16 + frow) * 32 + aoff];
    __builtin_amdgcn_s_setprio(1);
#pragma unroll
    for (int i = 0; i < 4; ++i)
#pragma unroll
      for (int j = 0; j < 4; ++j)
        acc[i][j] = __builtin_amdgcn_mfma_f32_16x16x32_bf16(af[i], bfr[j], acc[i][j], 0, 0, 0);
    __builtin_amdgcn_s_setprio(0);
  };

  const int NS = K >> 5;   // 32-wide K-steps
  STAGE(0, 0);
  if (NS > 1) STAGE(1, 1);
  int cur = 0;
  for (int ks = 0; ks < NS; ++ks) {
    if (ks + 1 < NS) asm volatile("s_waitcnt vmcnt(4)" ::: "memory");
    else             asm volatile("s_waitcnt vmcnt(0)" ::: "memory");
    __builtin_amdgcn_s_barrier();
    if (ks + 2 < NS) {
      int nxt = cur + 2; if (nxt >= 3) nxt -= 3;
      STAGE(nxt, ks + 2);
    }
    COMPUTE(As[cur], Bs[cur]);
    ++cur; if (cur >= 3) cur -= 3;
  }

  // epilogue: C/D layout col=lane&15, row=(lane>>4)*4+reg
#pragma unroll
  for (int i = 0; i < 4; ++i) {
#pragma unroll
    for (int j = 0; j < 4; ++j) {
      const int col = tn + wn + j * 16 + (ln & 15);
#pragma unroll
      for (int reg = 0; reg < 4; ++reg) {
        const int row = tm + wm + i * 16 + (ln >> 4) * 4 + reg;
        float v = acc[i][j][reg];
        if (MODE == 0) v += u[(c0 + z) * 512 + row] * aw[(c0 + z) * 512 + col];
        else if (MODE == 1) v = fmaxf(v + bias[row], 0.f);
        else if (MODE == 3) v += bias[col];
        if (MODE == 4) ((float*)C)[(long)z * sC + (long)row * ldc + col] = v;
        else ((ushort_t*)C)[(long)z * sC + (long)row * ldc + col] = f2bf(v);
      }
    }
  }
}

// =================== transposed-weight conversions (LDS tiled) ===================
// job 0: gc1LT[d][k] = bf(gc1_W[512+k][d])      (512x512 src lower half)
// job 1: gc2WT[e][d] = bf(gc2_W[d][e])          (src 512x1024)
// job 2: cWT[k][o]   = concat_W[o][k]           (src 512x1024, f32 out)
// job 3: nWT[k][j]   = nop_W[j][k], j>=124 -> 0 (src 124x512, dst 512x128)
__global__ __launch_bounds__(256)
void k_tw(const float* __restrict__ gc1_W, const float* __restrict__ gc2_W,
          const float* __restrict__ concat_W, const float* __restrict__ nop_W,
          ushort_t* __restrict__ gc1LT, ushort_t* __restrict__ gc2WT,
          float* __restrict__ cWT, float* __restrict__ nWT)
{
  __shared__ float tile[32][33];
  const int job = blockIdx.y;
  const float* src; int sr, sc;
  if (job == 0)      { src = gc1_W + 262144; sr = 512; sc = 512;  }
  else if (job == 1) { src = gc2_W;          sr = 512; sc = 1024; }
  else if (job == 2) { src = concat_W;       sr = 512; sc = 1024; }
  else               { src = nop_W;          sr = 124; sc = 512;  }
  const int tpr = sc >> 5;
  const int ntile = ((sr + 31) >> 5) * tpr;
  if ((int)blockIdx.x >= ntile) return;
  const int tr = (blockIdx.x / tpr) * 32, tc = (blockIdx.x % tpr) * 32;
  const int t = threadIdx.x, tx = t & 31, ty = t >> 5;   // 8 rows per pass
#pragma unroll
  for (int p = 0; p < 4; ++p) {
    const int r = tr + ty + p * 8;
    tile[ty + p * 8][tx] = (r < sr) ? src[(size_t)r * sc + tc + tx] : 0.f;
  }
  __syncthreads();
#pragma unroll
  for (int p = 0; p < 4; ++p) {
    const int dr = tc + ty + p * 8;   // dst row = src col
    const int dc = tr + tx;           // dst col = src row
    const float v = tile[tx][ty + p * 8];
    if (job == 0)      gc1LT[(size_t)dr * 512 + dc] = f2bf(v);
    else if (job == 1) gc2WT[(size_t)dr * 512 + dc] = f2bf(v);
    else if (job == 2) cWT[(size_t)dr * 512 + dc] = v;
    else               nWT[(size_t)dr * 128 + dc] = v;   // dc < 128 always (sr pad)
  }
}

// =================== bulk front kernel — ONE round + full MLP ===================
// Exactly 2048 blocks (one residency round at 8 blocks/CU).
// Every block: 8 adjacency units fully unrolled (4194304 = 524288 thr x 8,
// stride 524288 -> 16 independent loads in flight), then 1-2 copy units
// straight-line, then blocks 0..63 additionally do wo_n (tiny).
__global__ __launch_bounds__(256)
void k_front2(const int* __restrict__ step, const float* __restrict__ emb,
              const float* __restrict__ last_hidden,
              const float* __restrict__ wo_W, const float* __restrict__ ot_W,
              const float* __restrict__ W_ih, const float* __restrict__ W_hh,
              const float* __restrict__ ww, const int* __restrict__ ex,
              const float* __restrict__ word_op, const int* __restrict__ seq_mask,
              ushort_t* __restrict__ woWb, ushort_t* __restrict__ otWb,
              ushort_t* __restrict__ wihb, ushort_t* __restrict__ xhb,
              ushort_t* __restrict__ adj, float* __restrict__ won, int do_adj)
{
  const int blk = blockIdx.x;
  const int t = threadIdx.x;
  const size_t u0 = (size_t)blk * 256 + t;           // < 524288

  // ---- adjacency: 8 fixed units/thread, fully unrolled ----
  if (do_adj) {
    float4 w[8]; int4 e[8];
#pragma unroll
    for (int k = 0; k < 8; ++k) {
      w[k] = ((const float4*)ww)[u0 + (size_t)k * 524288];
      e[k] = ((const int4*)ex)[u0 + (size_t)k * 524288];
    }
#pragma unroll
    for (int k = 0; k < 8; ++k) {
      ushort4 r;
      r.x = (e[k].x == 1) ? f2bf(w[k].x) : 0;
      r.y = (e[k].y == 1) ? f2bf(w[k].y) : 0;
      r.z = (e[k].z == 1) ? f2bf(w[k].z) : 0;
      r.w = (e[k].w == 1) ? f2bf(w[k].w) : 0;
      ((ushort4*)adj)[u0 + (size_t)k * 524288] = r;
    }
  }

  // ---- copies: unit A (always) + unit B (u0 < 163840) ----
  // units: [0,131072) woWb | [131072,262144) otWb | [262144,655360) wihb | [655360,688128) xhb
  if (u0 < 131072) {
    ((ushort4*)woWb)[u0] = f4bf(((const float4*)wo_W)[u0]);
    // unit B = u0 + 524288 -> wihb index i2 = u0 + 262144 in [262144,393216): all W_hh
    const size_t i2 = u0 + 262144;
    ((ushort4*)wihb)[i2] = f4bf(((const float4*)W_hh)[i2 - 196608]);
  } else if (u0 < 262144) {
    const size_t i = u0 - 131072;
    ((ushort4*)otWb)[i] = f4bf(((const float4*)ot_W)[i]);
    if (u0 < 163840) {
      // unit B -> xhb index i = u0 - 131072 in [0,32768)
      const size_t e = i * 4;
      const int z = (int)(e >> 16), b = (int)((e >> 9) & 127), k = (int)(e & 511);
      float4 v = make_float4(0.f, 0.f, 0.f, 0.f);
      if (b < 64)
        v = z ? *(const float4*)&last_hidden[b * 512 + k]
              : *(const float4*)&emb[(size_t)step[b] * 512 + k];
      ((ushort4*)xhb)[i] = f4bf(v);
    }
  } else {
    const size_t i = u0 - 262144;    // < 262144: wihb first part
    const float4 v = (i < 196608) ? ((const float4*)W_ih)[i]
                                  : ((const float4*)W_hh)[i - 196608];
    ((ushort4*)wihb)[i] = f4bf(v);
  }

  // ---- wo_n normalization: blocks 0..63, one per batch ----
  if (blk < 64) {
    const int b = blk;
    __shared__ float red[4][4];               // [wave][o]
    float4 a0 = ((const float4*)word_op)[b * 512 + t];
    float4 a1 = ((const float4*)word_op)[b * 512 + t + 256];
    if (seq_mask[b * 512 + t])       a0 = make_float4(0.f, 0.f, 0.f, 0.f);
    if (seq_mask[b * 512 + t + 256]) a1 = make_float4(0.f, 0.f, 0.f, 0.f);
    float l0 = a0.x + a1.x, l1 = a0.y + a1.y, l2 = a0.z + a1.z, l3 = a0.w + a1.w;
#pragma unroll
    for (int off = 32; off; off >>= 1) {
      l0 += __shfl_down(l0, off, 64);
      l1 += __shfl_down(l1, off, 64);
      l2 += __shfl_down(l2, off, 64);
      l3 += __shfl_down(l3, off, 64);
    }
    if ((t & 63) == 0) {
      red[t >> 6][0] = l0; red[t >> 6][1] = l1;
      red[t >> 6][2] = l2; red[t >> 6][3] = l3;
    }
    __syncthreads();
    const float tot0 = red[0][0] + red[1][0] + red[2][0] + red[3][0] + 1e-30f;
    const float tot1 = red[0][1] + red[1][1] + red[2][1] + red[3][1] + 1e-30f;
    const float tot2 = red[0][2] + red[1][2] + red[2][2] + red[3][2] + 1e-30f;
    const float tot3 = red[0][3] + red[1][3] + red[2][3] + red[3][3] + 1e-30f;
    float* w0 = won + ((size_t)b * 4 + 0) * 512;
    float* w1 = won + ((size_t)b * 4 + 1) * 512;
    float* w2 = won + ((size_t)b * 4 + 2) * 512;
    float* w3 = won + ((size_t)b * 4 + 3) * 512;
    w0[t] = a0.x / tot0; w0[t + 256] = a1.x / tot0;
    w1[t] = a0.y / tot1; w1[t + 256] = a1.y / tot1;
    w2[t] = a0.z / tot2; w2[t + 256] = a1.z / tot2;
    w3[t] = a0.w / tot3; w3[t + 256] = a1.w / tot3;
  }
}

// =================== small fused kernels ===================

// GRU gate combine; gi2 holds gi (1536x128) then gh (1536x128) f32
__global__ __launch_bounds__(256)
void k_gru(const float* __restrict__ gi2, const float* __restrict__ last_hidden,
           const float* __restrict__ b_ih, const float* __restrict__ b_hh,
           float* __restrict__ hnew, float* __restrict__ hnew_out)
{
  const int idx = blockIdx.x * 256 + threadIdx.x;
  const int b = idx >> 9, tt = idx & 511;
  const float* gh = gi2 + 196608;
  const float ir  = gi2[tt * 128 + b]          + b_ih[tt];
  const float iz  = gi2[(512 + tt) * 128 + b]  + b_ih[512 + tt];
  const float inn = gi2[(1024 + tt) * 128 + b] + b_ih[1024 + tt];
  const float hr  = gh[tt * 128 + b]          + b_hh[tt];
  const float hz  = gh[(512 + tt) * 128 + b]  + b_hh[512 + tt];
  const float hn  = gh[(1024 + tt) * 128 + b] + b_hh[1024 + tt];
  const float h   = last_hidden[idx];
  const float r = 1.f / (1.f + __expf(-(ir + hr)));
  const float z = 1.f / (1.f + __expf(-(iz + hz)));
  const float n = tanhf(inn + r * hn);
  const float o = (1.f - z) * n + z * h;
  hnew[idx] = o;
  hnew_out[idx] = o;
}

// q = h_new @ attn_W ; u = h_new @ gc1_W[:512].  grid (64,4) x 128 threads.
__global__ __launch_bounds__(128)
void k_qu(const float* __restrict__ hnew, const float* __restrict__ attn_W,
          const float* __restrict__ gc1_W, float* __restrict__ q, float* __restrict__ u)
{
  const int b = blockIdx.x, j = blockIdx.y * 128 + threadIdx.x;
  __shared__ float hs[512];
  for (int i = threadIdx.x; i < 512; i += 128) hs[i] = hnew[b * 512 + i];
  __syncthreads();
  float qa = 0.f, ua = 0.f;
  for (int h = 0; h < 512; ++h) {
    const float hv = hs[h];
    qa += hv * attn_W[(size_t)h * 512 + j];
    ua += hv * gc1_W[(size_t)h * 512 + j];
  }
  q[b * 512 + j] = qa;
  u[b * 512 + j] = ua;
}

// scores[b,s] = q[b]·enc[s,b]; also emits encbf[b][s][k] (bf16) when emit!=0.
__global__ __launch_bounds__(256)
void k_score(const float* __restrict__ q, const float* __restrict__ enc,
             float* __restrict__ scores, ushort_t* __restrict__ encb, int emit)
{
  const int b = blockIdx.x, p = blockIdx.y;
  const int t = threadIdx.x, wv = t >> 6, ln = t & 63;
  __shared__ float qs[512];
  for (int i = t; i < 512; i += 256) qs[i] = q[b * 512 + i];
  __syncthreads();
  const int e0 = ln * 8;
  const float4 q0 = *(const float4*)&qs[e0];
  const float4 q1 = *(const float4*)&qs[e0 + 4];
  for (int it = 0; it < 8; ++it) {
    const int s = p * 32 + wv * 8 + it;
    const float* e = enc + ((size_t)s * 64 + b) * 512 + e0;
    const float4 v0 = *(const float4*)e;
    const float4 v1 = *(const float4*)(e + 4);
    float a = q0.x * v0.x + q0.y * v0.y + q0.z * v0.z + q0.w * v0.w
            + q1.x * v1.x + q1.y * v1.y + q1.z * v1.z + q1.w * v1.w;
    if (emit) {
      short8 o;
      o[0] = (short)f2bf(v0.x); o[1] = (short)f2bf(v0.y);
      o[2] = (short)f2bf(v0.z); o[3] = (short)f2bf(v0.w);
      o[4] = (short)f2bf(v1.x); o[5] = (short)f2bf(v1.y);
      o[6] = (short)f2bf(v1.z); o[7] = (short)f2bf(v1.w);
      *(short8*)&encb[(size_t)b * 262144 + (size_t)s * 512 + e0] = o;
    }
    a = wave_sum(a);
    if (ln == 0) scores[b * 512 + s] = a;
  }
}

// Fused softmax + context partials.  grid (64,16) x 512.
__global__ __launch_bounds__(512)
void k_ctx2(const float* __restrict__ scores, const ushort_t* __restrict__ encb,
            const float* __restrict__ enc, float* __restrict__ aw_dout,
            float* __restrict__ aw_ws, float* __restrict__ ctxpart, int use_bf)
{
  const int b = blockIdx.x, p = blockIdx.y, t = threadIdx.x;
  const int w = t >> 6, lane = t & 63;
  __shared__ float sc[512];
  __shared__ float red[8];
  __shared__ float red2[8];
  const float v = scores[b * 512 + t];
  float m = wave_max(v);
  if (lane == 0) red[w] = m;
  __syncthreads();
  float mm = red[0];
#pragma unroll
  for (int i = 1; i < 8; ++i) mm = fmaxf(mm, red[i]);
  const float e = __expf(v - mm);
  float s = wave_sum(e);
  if (lane == 0) red2[w] = s;
  __syncthreads();
  float tot = 0.f;
#pragma unroll
  for (int i = 0; i < 8; ++i) tot += red2[i];
  const float awv = e / tot;
  sc[t] = awv;
  if (p == 0) {
    aw_dout[b * 512 + t] = awv;
    aw_ws[b * 512 + t]   = awv;
  }
  __syncthreads();
  float acc = 0.f;
  if (use_bf) {
#pragma unroll 4
    for (int si = 0; si < 32; ++si)
      acc += sc[p * 32 + si] * bf2f(encb[((size_t)b * 512 + p * 32 + si) * 512 + t]);
  } else {
#pragma unroll 4
    for (int si = 0; si < 32; ++si)
      acc += sc[p * 32 + si] * enc[((size_t)(p * 32 + si) * 64 + b) * 512 + t];
  }
  ctxpart[((size_t)b * 16 + p) * 512 + t] = acc;
}

// concat_output = relu([h_new, sum_p ctxpart] @ cWT + b).  grid (64,4) x 128.
__global__ __launch_bounds__(128)
void k_concat(const float* __restrict__ hnew, const float* __restrict__ ctxpart,
              const float* __restrict__ cWT, const float* __restrict__ bias,
              float* __restrict__ out_cc, float* __restrict__ cc_ws)
{
  const int b = blockIdx.x, o = blockIdx.y * 128 + threadIdx.x;
  __shared__ __align__(16) float cat[1024];
  for (int m = 0; m < 8; ++m) {
    const int i = threadIdx.x + 128 * m;
    if (i < 512) {
      cat[i] = hnew[b * 512 + i];
    } else {
      const int d = i - 512;
      float s = 0.f;
#pragma unroll
      for (int pp = 0; pp < 16; ++pp) s += ctxpart[((size_t)b * 16 + pp) * 512 + d];
      cat[i] = s;
    }
  }
  __syncthreads();
  float acc = bias[o];
  for (int k = 0; k < 1024; k += 4) {
    acc += cat[k]     * cWT[(size_t)k * 512 + o]
         + cat[k + 1] * cWT[(size_t)(k + 1) * 512 + o]
         + cat[k + 2] * cWT[(size_t)(k + 2) * 512 + o]
         + cat[k + 3] * cWT[(size_t)(k + 3) * 512 + o];
  }
  acc = fmaxf(acc, 0.f);
  out_cc[b * 512 + o] = acc;
  cc_ws[b * 512 + o]  = acc;
}

// adj (bf16) for chunk (CB<64 fallback)
__global__ __launch_bounds__(256)
void k_adjc(const float* __restrict__ ww, const int* __restrict__ ex,
            ushort_t* __restrict__ adj, int c0)
{
  const size_t i = (size_t)blockIdx.x * 256 + threadIdx.x;
  const size_t base4 = (size_t)c0 * 512 * 512 / 4;
  const float4 w4 = ((const float4*)ww)[base4 + i];
  const int4   e4 = ((const int4*)ex)[base4 + i];
  ushort4 r;
  r.x = (e4.x == 1) ? f2bf(w4.x) : 0;
  r.y = (e4.y == 1) ? f2bf(w4.y) : 0;
  r.z = (e4.z == 1) ? f2bf(w4.z) : 0;
  r.w = (e4.w == 1) ? f2bf(w4.w) : 0;
  ((ushort4*)adj)[i] = r;
}

// enc (bf16, batch-packed) for chunk (CB<64 fallback)
__global__ __launch_bounds__(256)
void k_encc(const float* __restrict__ enc, ushort_t* __restrict__ encb, int c0)
{
  const size_t i = (size_t)blockIdx.x * 256 + threadIdx.x;
  const size_t el = i * 4;
  const int k = el & 511;
  const int s = (el >> 9) & 511;
  const int z = el >> 18;
  const float4 v = *(const float4*)&enc[((size_t)s * 64 + c0 + z) * 512 + k];
  ushort4 r;
  r.x = f2bf(v.x); r.y = f2bf(v.y); r.z = f2bf(v.z); r.w = f2bf(v.w);
  ((ushort4*)encb)[i] = r;
}

// Barrier-free fused LN + residual + wo_n contraction.
__global__ __launch_bounds__(256)
void k_red2(const ushort_t* __restrict__ w2w, const float* __restrict__ aw,
            const float* __restrict__ hnew, const ushort_t* __restrict__ encb,
            const float* __restrict__ won, const float* __restrict__ ng,
            const float* __restrict__ nb, float* __restrict__ part, int c0)
{
  const int z = blockIdx.x, b = c0 + z, yb = blockIdx.y;
  const int t = threadIdx.x, wv = t >> 6, ln = t & 63;
  __shared__ float sw[32][5];               // won0..3, aw per s-local
  __shared__ float accs[2][4][1024];        // cross-wave combine (32 KB)
  if (t < 160) {
    const int sl = t / 5, c_ = t - sl * 5;
    const int sg = yb * 32 + sl;
    sw[sl][c_] = (c_ < 4) ? won[((size_t)b * 4 + c_) * 512 + sg] : aw[b * 512 + sg];
  }
  const int d0 = ln * 16;
  float gg[16], bb[16], hv[16];
#pragma unroll
  for (int k = 0; k < 16; k += 4) {
    *(float4*)&gg[k] = *(const float4*)&ng[d0 + k];
    *(float4*)&bb[k] = *(const float4*)&nb[d0 + k];
  }
  if (ln < 32) {
#pragma unroll
    for (int k = 0; k < 16; k += 4)
      *(float4*)&hv[k] = *(const float4*)&hnew[b * 512 + d0 + k];
  }
  float acc[4][16];
#pragma unroll
  for (int o = 0; o < 4; ++o)
#pragma unroll
    for (int k = 0; k < 16; ++k) acc[o][k] = 0.f;
  __syncthreads();
  for (int it = 0; it < 8; ++it) {
    const int sl = wv * 8 + it;
    const int s = yb * 32 + sl;
    const ushort_t* row = w2w + ((size_t)z * 512 + s) * 1024 + d0;
    float x[16];
    bf8_to_f(row, x);
    bf8_to_f(row + 8, x + 8);
    float ls = 0.f, lss = 0.f;
#pragma unroll
    for (int k = 0; k < 16; ++k) { ls += x[k]; lss += x[k] * x[k]; }
#pragma unroll
    for (int off = 32; off; off >>= 1) {
      ls  += __shfl_xor(ls,  off, 64);
      lss += __shfl_xor(lss, off, 64);
    }
    const float mean = ls * (1.f / 1024.f);
    const float var  = lss * (1.f / 1024.f) - mean * mean;
    const float inv  = rsqrtf(var + 1e-6f);
    float res[16];
    if (ln < 32) {
      const float a_ = sw[sl][4];
#pragma unroll
      for (int k = 0; k < 16; ++k) res[k] = a_ * hv[k];
    } else {
      const ushort_t* er = encb + ((size_t)z * 512 + s) * 512 + (d0 - 512);
      bf8_to_f(er, res);
      bf8_to_f(er + 8, res + 8);
    }
    const float w0 = sw[sl][0], w1 = sw[sl][1], w2 = sw[sl][2], w3 = sw[sl][3];
#pragma unroll
    for (int k = 0; k < 16; ++k) {
      const float val = (x[k] - mean) * inv * gg[k] + bb[k] + res[k];
      acc[0][k] += w0 * val; acc[1][k] += w1 * val;
      acc[2][k] += w2 * val; acc[3][k] += w3 * val;
    }
  }
  if (wv < 2) {
#pragma unroll
    for (int o = 0; o < 4; ++o)
#pragma unroll
      for (int k = 0; k < 16; k += 4)
        *(float4*)&accs[wv][o][d0 + k] = *(float4*)&acc[o][k];
  }
  __syncthreads();
  if (wv >= 2) {
#pragma unroll
    for (int o = 0; o < 4; ++o)
#pragma unroll
      for (int k = 0; k < 16; ++k)
        accs[wv - 2][o][d0 + k] += acc[o][k];
  }
  __syncthreads();
  for (int i = t; i < 4096; i += 256) {
    const int o = i >> 10, d = i & 1023;
    part[(((size_t)(b * 16 + yb) * 4 + o) << 10) + d] = accs[0][o][d] + accs[1][o][d];
  }
}

// sum 16 partials -> ctx_op bf16 (256 x 1024)
__global__ __launch_bounds__(256)
void k_psum(const float* __restrict__ part, ushort_t* __restrict__ ctxop)
{
  const int idx = blockIdx.x * 256 + threadIdx.x;   // 262144
  const int r = idx >> 10, d = idx & 1023;
  const int b = r >> 2, o = r & 3;
  float s = 0.f;
#pragma unroll
  for (int p = 0; p < 16; ++p)
    s += part[(((size_t)(b * 16 + p) * 4 + o) << 10) + d];
  ctxop[idx] = f2bf(s);
}

// relu+bias, LN1, build op_all bf16 = [s1, ops[o]]
__global__ __launch_bounds__(512)
void k_ln1(const float* __restrict__ oppre, const float* __restrict__ wo_b,
           const float* __restrict__ n1g, const float* __restrict__ n1b,
           const float* __restrict__ ops, ushort_t* __restrict__ opall)
{
  const int r = blockIdx.x, t = threadIdx.x;
  const int o = r & 3;
  __shared__ float2 red[8];
  const float val = fmaxf(oppre[(size_t)r * 512 + t] + wo_b[t], 0.f);
  const float2 ss = blocksum2(val, val * val, red, t, 8);
  const float m = ss.x * (1.f / 512.f);
  const float v = ss.y * (1.f / 512.f) - m * m;
  const float s1 = (val - m) * rsqrtf(v + 1e-6f) * n1g[t] + n1b[t];
  opall[(size_t)r * 1024 + t] = f2bf(s1);
  opall[(size_t)r * 1024 + 512 + t] = f2bf(ops[o * 512 + t]);
}

// relu+bias, LN2 + ops, dot with concat_output -> oo
__global__ __launch_bounds__(512)
void k_ln2dot(const float* __restrict__ ohpre, const float* __restrict__ ot_b,
              const float* __restrict__ n2g, const float* __restrict__ n2b,
              const float* __restrict__ ops, const float* __restrict__ cc,
              const float* __restrict__ ops_bias, float* __restrict__ oo)
{
  const int r = blockIdx.x, t = threadIdx.x;
  const int b = r >> 2, o = r & 3;
  __shared__ float2 red[8];
  const float oh = fmaxf(ohpre[(size_t)r * 512 + t] + ot_b[t], 0.f);
  const float2 ss = blocksum2(oh, oh * oh, red, t, 8);
  const float m = ss.x * (1.f / 512.f);
  const float v = ss.y * (1.f / 512.f) - m * m;
  const float opo = (oh - m) * rsqrtf(v + 1e-6f) * n2g[t] + n2b[t] + ops[o * 512 + t];
  const float p = cc[b * 512 + t] * opo;
  const float2 s3 = blocksum2(p, 0.f, red, t, 8);
  if (t == 0) oo[r] = s3.x + ops_bias[o];
}

// nop head (coalesced via nWT) + log_softmax over 128
__global__ __launch_bounds__(128)
void k_final(const float* __restrict__ oo, const float* __restrict__ cc,
             const float* __restrict__ nWT, const float* __restrict__ nop_b,
             float* __restrict__ outp)
{
  const int b = blockIdx.x, t = threadIdx.x;
  __shared__ __align__(16) float ccs[512];
  __shared__ float red[2];
  __shared__ float red2[2];
  for (int i = t; i < 512; i += 128) ccs[i] = cc[b * 512 + i];
  __syncthreads();
  float v;
  if (t < 4) {
    v = oo[b * 4 + t];
  } else {
    const int j = t - 4;
    float a = nop_b[j];
    for (int k = 0; k < 512; ++k) a += ccs[k] * nWT[k * 128 + j];
    v = a;
  }
  float m = wave_max(v);
  if ((t & 63) == 0) red[t >> 6] = m;
  __syncthreads();
  m = fmaxf(red[0], red[1]);
  const float e = __expf(v - m);
  float s = wave_sum(e);
  if ((t & 63) == 0) red2[t >> 6] = s;
  __syncthreads();
  s = red2[0] + red2[1];
  outp[b * 128 + t] = v - m - logf(s);
}

} // namespace

extern "C" void kernel_launch(void* const* d_in, const int* in_sizes, int n_in,
                              void* d_out, int out_size, void* d_ws, size_t ws_size,
                              hipStream_t stream)
{
  const int*   input_step  = (const int*)  d_in[0];
  const float* last_hidden = (const float*)d_in[1];
  const float* enc         = (const float*)d_in[2];
  const float* word_word   = (const float*)d_in[3];
  const float* word_op     = (const float*)d_in[4];
  const int*   word_exist  = (const int*)  d_in[5];
  const int*   seq_mask    = (const int*)  d_in[6];
  const float* emb         = (const float*)d_in[7];
  const float* W_ih        = (const float*)d_in[8];
  const float* W_hh        = (const float*)d_in[9];
  const float* b_ih        = (const float*)d_in[10];
  const float* b_hh        = (const float*)d_in[11];
  const float* attn_W      = (const float*)d_in[12];
  const float* concat_W    = (const float*)d_in[14];
  const float* concat_b    = (const float*)d_in[15];
  const float* ops         = (const float*)d_in[16];
  const float* ops_bias    = (const float*)d_in[17];
  const float* nop_W       = (const float*)d_in[18];
  const float* nop_b       = (const float*)d_in[19];
  const float* gc1_W       = (const float*)d_in[20];
  const float* gc1_b       = (const float*)d_in[21];
  const float* gc2_W       = (const float*)d_in[22];
  const float* gc2_b       = (const float*)d_in[23];
  const float* norm_g      = (const float*)d_in[24];
  const float* norm_b      = (const float*)d_in[25];
  const float* norm1_g     = (const float*)d_in[26];
  const float* norm1_b     = (const float*)d_in[27];
  const float* norm2_g     = (const float*)d_in[28];
  const float* norm2_b     = (const float*)d_in[29];
  const float* wo_W        = (const float*)d_in[30];
  const float* wo_b        = (const float*)d_in[31];
  const float* ot_W        = (const float*)d_in[32];
  const float* ot_b        = (const float*)d_in[33];

  float* ws  = (float*)d_ws;
  float* out = (float*)d_out;

  // ---- workspace layout (floats) ----
  size_t off = 0;
  auto take = [&](size_t n) { size_t o = off; off += n; return o; };
  const size_t o_hnew = take(32768);
  const size_t o_q    = take(32768);
  const size_t o_u    = take(32768);
  const size_t o_aw   = take(32768);
  const size_t o_scores = take(32768);
  const size_t o_ctxpart = take(524288);   // 64*16*512
  const size_t o_cc   = take(32768);
  const size_t o_won  = take(131072);
  const size_t o_oo   = take(256);
  const size_t o_gi2  = take(393216);      // 2 x 1536 x 128 f32
  const size_t o_part = take(4194304);     // 64*16*4*1024
  const size_t o_oppre = take(131072);
  const size_t o_ohpre = take(131072);
  const size_t o_gc1LT = take(131072);
  const size_t o_gc2WT = take(262144);
  const size_t o_woW   = take(262144);
  const size_t o_otW   = take(262144);
  const size_t o_cWT   = take(524288);
  const size_t o_nWT   = take(65536);
  const size_t o_wihb  = take(786432);     // 2 x 1536 x 512 bf16
  const size_t o_xhb   = take(65536);      // 2 x 128 x 512 bf16
  const size_t o_ctxop = take(131072);
  const size_t o_opall = take(131072);
  const size_t base = off;

  // pick chunk size by available workspace (constant across calls -> graph-safe)
  int CB = 16;
  if (ws_size >= (base + 64ull * 524288) * 4) CB = 64;
  else if (ws_size >= (base + 32ull * 524288) * 4) CB = 32;
  const int nch = 64 / CB;

  const size_t o_adjbf = take((size_t)CB * 131072);
  const size_t o_h1t   = take((size_t)CB * 131072);
  const size_t o_encbf = take((size_t)CB * 131072);
  const size_t o_xw1t  = take((size_t)CB * 131072);
  const size_t o_tmat  = o_xw1t;           // overlays xw1t (dead after mgemm<1>)
  const size_t o_w2w   = o_adjbf;          // overlays adjbf+h1t (dead after mgemm<2>)

  float* hnew = ws + o_hnew;
  float* q    = ws + o_q;
  float* u    = ws + o_u;
  float* aw   = ws + o_aw;
  float* scores = ws + o_scores;
  float* ctxpart = ws + o_ctxpart;
  float* cc   = ws + o_cc;
  float* won  = ws + o_won;
  float* oo   = ws + o_oo;
  float* gi2  = ws + o_gi2;
  float* part = ws + o_part;
  float* oppre = ws + o_oppre;
  float* ohpre = ws + o_ohpre;
  float* cWT  = ws + o_cWT;
  float* nWT  = ws + o_nWT;
  ushort_t* gc1LT = (ushort_t*)(ws + o_gc1LT);
  ushort_t* gc2WT = (ushort_t*)(ws + o_gc2WT);
  ushort_t* woWb  = (ushort_t*)(ws + o_woW);
  ushort_t* otWb  = (ushort_t*)(ws + o_otW);
  ushort_t* wihb  = (ushort_t*)(ws + o_wihb);
  ushort_t* xhb   = (ushort_t*)(ws + o_xhb);
  ushort_t* ctxop = (ushort_t*)(ws + o_ctxop);
  ushort_t* opall = (ushort_t*)(ws + o_opall);
  ushort_t* adjbf = (ushort_t*)(ws + o_adjbf);
  ushort_t* h1t   = (ushort_t*)(ws + o_h1t);
  ushort_t* encbf = (ushort_t*)(ws + o_encbf);
  ushort_t* xw1t  = (ushort_t*)(ws + o_xw1t);
  ushort_t* tmat  = (ushort_t*)(ws + o_tmat);
  ushort_t* w2wbf = (ushort_t*)(ws + o_w2w);

  float* out_logits = out;
  float* out_hnew   = out + 8192;
  float* out_aw     = out + 8192 + 32768;
  float* out_cc     = out + 8192 + 65536;

  const int full = (CB == 64) ? 1 : 0;

  // ---- front: transposed weights (LDS tiled) + bulk streams (1 round, MLP) ----
  k_tw<<<dim3(512, 4), 256, 0, stream>>>(gc1_W, gc2_W, concat_W, nop_W,
      gc1LT, gc2WT, cWT, nWT);
  k_front2<<<2048, 256, 0, stream>>>(input_step, emb, last_hidden,
      wo_W, ot_W, W_ih, W_hh, word_word, word_exist, word_op, seq_mask,
      woWb, otWb, wihb, xhb, adjbf, won, full);

  // ---- GRU via MFMA: gi/gh = [W_ih;W_hh] @ [x;h]^T, N padded to 128 ----
  mgemm<4><<<dim3(1, 12, 2), 256, 0, stream>>>(wihb, 512, 786432, xhb, 512, 65536,
      gi2, 128, 196608, 512, nullptr, nullptr, nullptr, 0);
  k_gru<<<128, 256, 0, stream>>>(gi2, last_hidden, b_ih, b_hh, hnew, out_hnew);

  // ---- attention + concat ----
  k_qu<<<dim3(64, 4), 128, 0, stream>>>(hnew, attn_W, gc1_W, q, u);
  k_score<<<dim3(64, 16), 256, 0, stream>>>(q, enc, scores, encbf, full);
  k_ctx2<<<dim3(64, 16), 512, 0, stream>>>(scores, encbf, enc, out_aw, aw, ctxpart, full);
  k_concat<<<dim3(64, 4), 128, 0, stream>>>(hnew, ctxpart, cWT, concat_b, out_cc, cc);

  // ---- GCN chain (bf16 MFMA), chunked ----
  for (int c = 0; c < nch; ++c) {
    const int c0 = c * CB;
    if (!full) {
      k_adjc<<<CB * 256, 256, 0, stream>>>(word_word, word_exist, adjbf, c0);
      k_encc<<<CB * 256, 256, 0, stream>>>(enc, encbf, c0);
    }
    // XW1T[d][s] = gc1LT[d][:] . enc_b[s][:] + u[b][d]*aw[b][s]
    mgemm<0><<<dim3(4, 4, CB), 256, 0, stream>>>(gc1LT, 512, 0, encbf, 512, 262144,
        xw1t, 512, 262144, 512, nullptr, aw, u, c0);
    // h1T[d][s] = relu(XW1T[d][:] . adj[s][:] + gc1_b[d])
    mgemm<1><<<dim3(4, 4, CB), 256, 0, stream>>>(xw1t, 512, 262144, adjbf, 512, 262144,
        h1t, 512, 262144, 512, gc1_b, nullptr, nullptr, 0);
    // t[s][d] = adj[s][:] . h1T[d][:]   (overlays xw1t, dead)
    mgemm<2><<<dim3(4, 4, CB), 256, 0, stream>>>(adjbf, 512, 262144, h1t, 512, 262144,
        tmat, 512, 262144, 512, nullptr, nullptr, nullptr, 0);
    // w2w[s][e] = t[s][:] . gc2WT[e][:] + gc2_b[e]   (overlays adjbf+h1t, dead)
    mgemm<3><<<dim3(8, 4, CB), 256, 0, stream>>>(tmat, 512, 262144, gc2WT, 512, 0,
        w2wbf, 1024, 524288, 512, gc2_b, nullptr, nullptr, 0);
    k_red2<<<dim3(CB, 16), 256, 0, stream>>>(w2wbf, aw, hnew, encbf, won, norm_g, norm_b, part, c0);
  }

  // ---- op head (MFMA GEMMs) + nop head + log_softmax ----
  k_psum<<<1024, 256, 0, stream>>>(part, ctxop);
  mgemm<4><<<dim3(4, 2, 1), 256, 0, stream>>>(ctxop, 1024, 0, woWb, 1024, 0,
      oppre, 512, 0, 1024, nullptr, nullptr, nullptr, 0);
  k_ln1<<<256, 512, 0, stream>>>(oppre, wo_b, norm1_g, norm1_b, ops, opall);
  mgemm<4><<<dim3(4, 2, 1), 256, 0, stream>>>(opall, 1024, 0, otWb, 1024, 0,
      ohpre, 512, 0, 1024, nullptr, nullptr, nullptr, 0);
  k_ln2dot<<<256, 512, 0, stream>>>(ohpre, ot_b, norm2_g, norm2_b, ops, cc, ops_bias, oo);
  k_final<<<64, 128, 0, stream>>>(oo, cc, nWT, nop_b, out_logits);

  (void)in_sizes; (void)n_in; (void)out_size;
}

// Round 10
// 641.278 us; speedup vs baseline: 1.1613x; 1.0209x over previous
//
#include <hip/hip_runtime.h>
#include <math.h>

namespace {

typedef unsigned short ushort_t;
typedef __attribute__((ext_vector_type(8))) short short8;
typedef __attribute__((ext_vector_type(4))) float float4v;

__device__ __forceinline__ unsigned short f2bf(float x) {
  unsigned u = __float_as_uint(x);
  u += 0x7fffu + ((u >> 16) & 1u);        // RNE
  return (unsigned short)(u >> 16);
}
__device__ __forceinline__ float bf2f(unsigned short u) {
  return __uint_as_float((unsigned)u << 16);
}
__device__ __forceinline__ void bf8_to_f(const ushort_t* p, float* o) {
  const short8 v = *(const short8*)p;
#pragma unroll
  for (int k = 0; k < 8; ++k) o[k] = bf2f((unsigned short)v[k]);
}
__device__ __forceinline__ ushort4 f4bf(float4 v) {
  ushort4 r;
  r.x = f2bf(v.x); r.y = f2bf(v.y); r.z = f2bf(v.z); r.w = f2bf(v.w);
  return r;
}

__device__ __forceinline__ float wave_sum(float v) {
#pragma unroll
  for (int off = 32; off; off >>= 1) v += __shfl_down(v, off, 64);
  return v;
}
__device__ __forceinline__ float wave_max(float v) {
#pragma unroll
  for (int off = 32; off; off >>= 1) v = fmaxf(v, __shfl_down(v, off, 64));
  return v;
}
__device__ __forceinline__ float2 blocksum2(float a, float b, float2* red, int t, int nw) {
#pragma unroll
  for (int off = 32; off; off >>= 1) {
    a += __shfl_down(a, off, 64);
    b += __shfl_down(b, off, 64);
  }
  __syncthreads();
  if ((t & 63) == 0) red[t >> 6] = make_float2(a, b);
  __syncthreads();
  float sa = 0.f, sb = 0.f;
  for (int i = 0; i < nw; ++i) { sa += red[i].x; sb += red[i].y; }
  return make_float2(sa, sb);
}

// =================== bf16 MFMA NT-GEMM, 128x128 tile (r4-verified) ===========
// Used for GRU and op-head GEMMs (mode 4).  3-buffer ring, depth-2 prefetch,
// one barrier per K-step.  XCD swizzle when nz%8==0.  LDS seg-XOR (0 conflicts).
template<int MODE>
__global__ __launch_bounds__(256)
void mgemm(const ushort_t* __restrict__ A, int lda, long sA,
           const ushort_t* __restrict__ Bt, int ldb, long sB,
           void* __restrict__ C, int ldc, long sC, int K,
           const float* __restrict__ bias,
           const float* __restrict__ aw, const float* __restrict__ u, int c0)
{
  __shared__ __attribute__((aligned(16))) ushort_t As[3][128 * 32];
  __shared__ __attribute__((aligned(16))) ushort_t Bs[3][128 * 32];

  int bx = blockIdx.x, by = blockIdx.y, bz = blockIdx.z;
  const int nx = gridDim.x, ny = gridDim.y, nz = gridDim.z;
  if ((nz & 7) == 0) {
    const int nxy = nx * ny;
    const int L = bx + nx * (by + ny * bz);
    const int xcd = L & 7;
    const int idx = L >> 3;
    const int lz = idx / nxy;
    const int xy = idx - lz * nxy;
    bz = xcd + 8 * lz;
    bx = xy % nx;
    by = xy / nx;
  }

  const int z = bz;
  const ushort_t* Ab = A  + (long)z * sA;
  const ushort_t* Bb = Bt + (long)z * sB;
  const int tm = by * 128, tn = bx * 128;
  const int t = threadIdx.x, wv = t >> 6, ln = t & 63;
  const int lrow = ln >> 2, lseg = ln & 3;        // staging: 16 rows x 4 segs of 16B
  const int gseg = lseg ^ ((lrow >> 1) & 3);      // bank-conflict-free seg XOR
  const int frow = ln & 15, q = ln >> 4;          // fragment: m=ln&15, k-quad
  const int sw8 = (frow >> 1) & 3;
  const int aoff = (q ^ sw8) << 3;
  const int wm = (wv >> 1) * 64, wn = (wv & 1) * 64;

  float4v acc[4][4];
#pragma unroll
  for (int i = 0; i < 4; ++i)
#pragma unroll
    for (int j = 0; j < 4; ++j) acc[i][j] = (float4v)0.f;

  auto STAGE = [&](int s, int ks) {
    const int kc = ks * 32 + gseg * 8;
#pragma unroll
    for (int half = 0; half < 2; ++half) {
      const int rbase = wv * 32 + half * 16;
      const ushort_t* ga = Ab + (long)(tm + rbase + lrow) * lda + kc;
      const ushort_t* gb = Bb + (long)(tn + rbase + lrow) * ldb + kc;
      __builtin_amdgcn_global_load_lds(
          (const __attribute__((address_space(1))) void*)ga,
          (__attribute__((address_space(3))) void*)&As[s][rbase * 32], 16, 0, 0);
      __builtin_amdgcn_global_load_lds(
          (const __attribute__((address_space(1))) void*)gb,
          (__attribute__((address_space(3))) void*)&Bs[s][rbase * 32], 16, 0, 0);
    }
  };
  auto COMPUTE = [&](const ushort_t* Asb, const ushort_t* Bsb) {
    short8 af[4], bfr[4];
#pragma unroll
    for (int i = 0; i < 4; ++i) af[i]  = *(const short8*)&Asb[(wm + i * 16 + frow) * 32 + aoff];
#pragma unroll
    for (int j = 0; j < 4; ++j) bfr[j] = *(const short8*)&Bsb[(wn + j * 16 + frow) * 32 + aoff];
    __builtin_amdgcn_s_setprio(1);
#pragma unroll
    for (int i = 0; i < 4; ++i)
#pragma unroll
      for (int j = 0; j < 4; ++j)
        acc[i][j] = __builtin_amdgcn_mfma_f32_16x16x32_bf16(af[i], bfr[j], acc[i][j], 0, 0, 0);
    __builtin_amdgcn_s_setprio(0);
  };

  const int NS = K >> 5;   // 32-wide K-steps
  STAGE(0, 0);
  if (NS > 1) STAGE(1, 1);
  int cur = 0;
  for (int ks = 0; ks < NS; ++ks) {
    if (ks + 1 < NS) asm volatile("s_waitcnt vmcnt(4)" ::: "memory");
    else             asm volatile("s_waitcnt vmcnt(0)" ::: "memory");
    __builtin_amdgcn_s_barrier();
    if (ks + 2 < NS) {
      int nxt = cur + 2; if (nxt >= 3) nxt -= 3;
      STAGE(nxt, ks + 2);
    }
    COMPUTE(As[cur], Bs[cur]);
    ++cur; if (cur >= 3) cur -= 3;
  }

  // epilogue: C/D layout col=lane&15, row=(lane>>4)*4+reg
#pragma unroll
  for (int i = 0; i < 4; ++i) {
#pragma unroll
    for (int j = 0; j < 4; ++j) {
      const int col = tn + wn + j * 16 + (ln & 15);
#pragma unroll
      for (int reg = 0; reg < 4; ++reg) {
        const int row = tm + wm + i * 16 + (ln >> 4) * 4 + reg;
        float v = acc[i][j][reg];
        if (MODE == 0) v += u[(c0 + z) * 512 + row] * aw[(c0 + z) * 512 + col];
        else if (MODE == 1) v = fmaxf(v + bias[row], 0.f);
        else if (MODE == 3) v += bias[col];
        if (MODE == 4) ((float*)C)[(long)z * sC + (long)row * ldc + col] = v;
        else ((ushort_t*)C)[(long)z * sC + (long)row * ldc + col] = f2bf(v);
      }
    }
  }
}

// =================== bf16 MFMA NT-GEMM, 256x256 tile (GCN chain) =============
// Raises tile arithmetic intensity 64 -> 128 FLOP/B (staging traffic halves;
// the GCN GEMMs measured BW-bound at ~4.9 TB/s staging = 312 TF with 128^2).
// 512 threads = 8 waves (2x4); per-wave output 128x64, acc[8][4].
// BK=32, 2-slot ping-pong, 64 KB LDS -> 2 blocks/CU.  Schedule per K-step:
//   STAGE(nxt) -> vmcnt(4) -> barrier -> 32 MFMA -> barrier.
// Address math (seg-XOR staging, frow/aoff fragment reads, C/D epilogue) is
// bit-identical to the verified 128^2 kernel, ranges extended.
// MODE 0: bf16 out, v += u[(c0+z)*512+row]*aw[(c0+z)*512+col]
// MODE 1: bf16 out, relu(v + bias[row])
// MODE 2: bf16 out, plain
// MODE 3: bf16 out, v + bias[col]
template<int MODE>
__global__ __launch_bounds__(512)
void mgemm2(const ushort_t* __restrict__ A, int lda, long sA,
            const ushort_t* __restrict__ Bt, int ldb, long sB,
            void* __restrict__ C, int ldc, long sC, int K,
            const float* __restrict__ bias,
            const float* __restrict__ aw, const float* __restrict__ u, int c0)
{
  __shared__ __attribute__((aligned(16))) ushort_t As[2][256 * 32];
  __shared__ __attribute__((aligned(16))) ushort_t Bs[2][256 * 32];

  // ---- XCD-aware swizzle (nz % 8 == 0) ----
  int bx = blockIdx.x, by = blockIdx.y, bz = blockIdx.z;
  const int nx = gridDim.x, ny = gridDim.y, nz = gridDim.z;
  if ((nz & 7) == 0) {
    const int nxy = nx * ny;
    const int L = bx + nx * (by + ny * bz);
    const int xcd = L & 7;
    const int idx = L >> 3;
    const int lz = idx / nxy;
    const int xy = idx - lz * nxy;
    bz = xcd + 8 * lz;
    bx = xy % nx;
    by = xy / nx;
  }

  const int z = bz;
  const ushort_t* Ab = A  + (long)z * sA;
  const ushort_t* Bb = Bt + (long)z * sB;
  const int tm = by * 256, tn = bx * 256;
  const int t = threadIdx.x, wv = t >> 6, ln = t & 63;   // wv 0..7
  const int lrow = ln >> 2, lseg = ln & 3;
  const int gseg = lseg ^ ((lrow >> 1) & 3);
  const int frow = ln & 15, q = ln >> 4;
  const int sw8 = (frow >> 1) & 3;
  const int aoff = (q ^ sw8) << 3;
  const int wm = (wv >> 2) * 128, wn = (wv & 3) * 64;    // 2x4 wave grid

  float4v acc[8][4];
#pragma unroll
  for (int i = 0; i < 8; ++i)
#pragma unroll
    for (int j = 0; j < 4; ++j) acc[i][j] = (float4v)0.f;

  // stage one 256x32 slice of A and B into slot s (4 gload_lds per thread)
  auto STAGE = [&](int s, int ks) {
    const int kc = ks * 32 + gseg * 8;
#pragma unroll
    for (int half = 0; half < 2; ++half) {
      const int rbase = wv * 32 + half * 16;             // 0..240 step 16
      const ushort_t* ga = Ab + (long)(tm + rbase + lrow) * lda + kc;
      const ushort_t* gb = Bb + (long)(tn + rbase + lrow) * ldb + kc;
      __builtin_amdgcn_global_load_lds(
          (const __attribute__((address_space(1))) void*)ga,
          (__attribute__((address_space(3))) void*)&As[s][rbase * 32], 16, 0, 0);
      __builtin_amdgcn_global_load_lds(
          (const __attribute__((address_space(1))) void*)gb,
          (__attribute__((address_space(3))) void*)&Bs[s][rbase * 32], 16, 0, 0);
    }
  };
  auto COMPUTE = [&](const ushort_t* Asb, const ushort_t* Bsb) {
    short8 af[8], bfr[4];
#pragma unroll
    for (int i = 0; i < 8; ++i) af[i]  = *(const short8*)&Asb[(wm + i * 16 + frow) * 32 + aoff];
#pragma unroll
    for (int j = 0; j < 4; ++j) bfr[j] = *(const short8*)&Bsb[(wn + j * 16 + frow) * 32 + aoff];
    __builtin_amdgcn_s_setprio(1);
#pragma unroll
    for (int i = 0; i < 8; ++i)
#pragma unroll
      for (int j = 0; j < 4; ++j)
        acc[i][j] = __builtin_amdgcn_mfma_f32_16x16x32_bf16(af[i], bfr[j], acc[i][j], 0, 0, 0);
    __builtin_amdgcn_s_setprio(0);
  };

  const int NS = K >> 5;   // 32-wide K-steps (16 for K=512)
  STAGE(0, 0);
  for (int ks = 0; ks < NS; ++ks) {
    const int cur = ks & 1;
    if (ks + 1 < NS) {
      STAGE(cur ^ 1, ks + 1);                             // restage after prev trailing barrier
      asm volatile("s_waitcnt vmcnt(4)" ::: "memory");    // cur's 4 loads complete
    } else {
      asm volatile("s_waitcnt vmcnt(0)" ::: "memory");
    }
    __builtin_amdgcn_s_barrier();
    COMPUTE(As[cur], Bs[cur]);
    __builtin_amdgcn_s_barrier();                         // cur free for restage
  }

  // epilogue: C/D layout col=lane&15, row=(lane>>4)*4+reg
#pragma unroll
  for (int i = 0; i < 8; ++i) {
#pragma unroll
    for (int j = 0; j < 4; ++j) {
      const int col = tn + wn + j * 16 + (ln & 15);
#pragma unroll
      for (int reg = 0; reg < 4; ++reg) {
        const int row = tm + wm + i * 16 + (ln >> 4) * 4 + reg;
        float v = acc[i][j][reg];
        if (MODE == 0) v += u[(c0 + z) * 512 + row] * aw[(c0 + z) * 512 + col];
        else if (MODE == 1) v = fmaxf(v + bias[row], 0.f);
        else if (MODE == 3) v += bias[col];
        ((ushort_t*)C)[(long)z * sC + (long)row * ldc + col] = f2bf(v);
      }
    }
  }
}

// =================== transposed-weight conversions (LDS tiled) ===================
__global__ __launch_bounds__(256)
void k_tw(const float* __restrict__ gc1_W, const float* __restrict__ gc2_W,
          const float* __restrict__ concat_W, const float* __restrict__ nop_W,
          ushort_t* __restrict__ gc1LT, ushort_t* __restrict__ gc2WT,
          float* __restrict__ cWT, float* __restrict__ nWT)
{
  __shared__ float tile[32][33];
  const int job = blockIdx.y;
  const float* src; int sr, sc;
  if (job == 0)      { src = gc1_W + 262144; sr = 512; sc = 512;  }
  else if (job == 1) { src = gc2_W;          sr = 512; sc = 1024; }
  else if (job == 2) { src = concat_W;       sr = 512; sc = 1024; }
  else               { src = nop_W;          sr = 124; sc = 512;  }
  const int tpr = sc >> 5;
  const int ntile = ((sr + 31) >> 5) * tpr;
  if ((int)blockIdx.x >= ntile) return;
  const int tr = (blockIdx.x / tpr) * 32, tc = (blockIdx.x % tpr) * 32;
  const int t = threadIdx.x, tx = t & 31, ty = t >> 5;   // 8 rows per pass
#pragma unroll
  for (int p = 0; p < 4; ++p) {
    const int r = tr + ty + p * 8;
    tile[ty + p * 8][tx] = (r < sr) ? src[(size_t)r * sc + tc + tx] : 0.f;
  }
  __syncthreads();
#pragma unroll
  for (int p = 0; p < 4; ++p) {
    const int dr = tc + ty + p * 8;   // dst row = src col
    const int dc = tr + tx;           // dst col = src row
    const float v = tile[tx][ty + p * 8];
    if (job == 0)      gc1LT[(size_t)dr * 512 + dc] = f2bf(v);
    else if (job == 1) gc2WT[(size_t)dr * 512 + dc] = f2bf(v);
    else if (job == 2) cWT[(size_t)dr * 512 + dc] = v;
    else               nWT[(size_t)dr * 128 + dc] = v;   // dc < 128 always (sr pad)
  }
}

// =================== bulk front kernel (frozen) ===================
__global__ __launch_bounds__(256)
void k_front2(const int* __restrict__ step, const float* __restrict__ emb,
              const float* __restrict__ last_hidden,
              const float* __restrict__ wo_W, const float* __restrict__ ot_W,
              const float* __restrict__ W_ih, const float* __restrict__ W_hh,
              const float* __restrict__ ww, const int* __restrict__ ex,
              const float* __restrict__ word_op, const int* __restrict__ seq_mask,
              ushort_t* __restrict__ woWb, ushort_t* __restrict__ otWb,
              ushort_t* __restrict__ wihb, ushort_t* __restrict__ xhb,
              ushort_t* __restrict__ adj, float* __restrict__ won, int do_adj)
{
  const int blk = blockIdx.x;
  const int t = threadIdx.x;
  const size_t u0 = (size_t)blk * 256 + t;           // < 524288

  if (do_adj) {
    float4 w[8]; int4 e[8];
#pragma unroll
    for (int k = 0; k < 8; ++k) {
      w[k] = ((const float4*)ww)[u0 + (size_t)k * 524288];
      e[k] = ((const int4*)ex)[u0 + (size_t)k * 524288];
    }
#pragma unroll
    for (int k = 0; k < 8; ++k) {
      ushort4 r;
      r.x = (e[k].x == 1) ? f2bf(w[k].x) : 0;
      r.y = (e[k].y == 1) ? f2bf(w[k].y) : 0;
      r.z = (e[k].z == 1) ? f2bf(w[k].z) : 0;
      r.w = (e[k].w == 1) ? f2bf(w[k].w) : 0;
      ((ushort4*)adj)[u0 + (size_t)k * 524288] = r;
    }
  }

  if (u0 < 131072) {
    ((ushort4*)woWb)[u0] = f4bf(((const float4*)wo_W)[u0]);
    const size_t i2 = u0 + 262144;
    ((ushort4*)wihb)[i2] = f4bf(((const float4*)W_hh)[i2 - 196608]);
  } else if (u0 < 262144) {
    const size_t i = u0 - 131072;
    ((ushort4*)otWb)[i] = f4bf(((const float4*)ot_W)[i]);
    if (u0 < 163840) {
      const size_t e = i * 4;
      const int z = (int)(e >> 16), b = (int)((e >> 9) & 127), k = (int)(e & 511);
      float4 v = make_float4(0.f, 0.f, 0.f, 0.f);
      if (b < 64)
        v = z ? *(const float4*)&last_hidden[b * 512 + k]
              : *(const float4*)&emb[(size_t)step[b] * 512 + k];
      ((ushort4*)xhb)[i] = f4bf(v);
    }
  } else {
    const size_t i = u0 - 262144;    // < 262144: wihb first part
    const float4 v = (i < 196608) ? ((const float4*)W_ih)[i]
                                  : ((const float4*)W_hh)[i - 196608];
    ((ushort4*)wihb)[i] = f4bf(v);
  }

  if (blk < 64) {
    const int b = blk;
    __shared__ float red[4][4];               // [wave][o]
    float4 a0 = ((const float4*)word_op)[b * 512 + t];
    float4 a1 = ((const float4*)word_op)[b * 512 + t + 256];
    if (seq_mask[b * 512 + t])       a0 = make_float4(0.f, 0.f, 0.f, 0.f);
    if (seq_mask[b * 512 + t + 256]) a1 = make_float4(0.f, 0.f, 0.f, 0.f);
    float l0 = a0.x + a1.x, l1 = a0.y + a1.y, l2 = a0.z + a1.z, l3 = a0.w + a1.w;
#pragma unroll
    for (int off = 32; off; off >>= 1) {
      l0 += __shfl_down(l0, off, 64);
      l1 += __shfl_down(l1, off, 64);
      l2 += __shfl_down(l2, off, 64);
      l3 += __shfl_down(l3, off, 64);
    }
    if ((t & 63) == 0) {
      red[t >> 6][0] = l0; red[t >> 6][1] = l1;
      red[t >> 6][2] = l2; red[t >> 6][3] = l3;
    }
    __syncthreads();
    const float tot0 = red[0][0] + red[1][0] + red[2][0] + red[3][0] + 1e-30f;
    const float tot1 = red[0][1] + red[1][1] + red[2][1] + red[3][1] + 1e-30f;
    const float tot2 = red[0][2] + red[1][2] + red[2][2] + red[3][2] + 1e-30f;
    const float tot3 = red[0][3] + red[1][3] + red[2][3] + red[3][3] + 1e-30f;
    float* w0 = won + ((size_t)b * 4 + 0) * 512;
    float* w1 = won + ((size_t)b * 4 + 1) * 512;
    float* w2 = won + ((size_t)b * 4 + 2) * 512;
    float* w3 = won + ((size_t)b * 4 + 3) * 512;
    w0[t] = a0.x / tot0; w0[t + 256] = a1.x / tot0;
    w1[t] = a0.y / tot1; w1[t + 256] = a1.y / tot1;
    w2[t] = a0.z / tot2; w2[t + 256] = a1.z / tot2;
    w3[t] = a0.w / tot3; w3[t + 256] = a1.w / tot3;
  }
}

// =================== small fused kernels ===================

__global__ __launch_bounds__(256)
void k_gru(const float* __restrict__ gi2, const float* __restrict__ last_hidden,
           const float* __restrict__ b_ih, const float* __restrict__ b_hh,
           float* __restrict__ hnew, float* __restrict__ hnew_out)
{
  const int idx = blockIdx.x * 256 + threadIdx.x;
  const int b = idx >> 9, tt = idx & 511;
  const float* gh = gi2 + 196608;
  const float ir  = gi2[tt * 128 + b]          + b_ih[tt];
  const float iz  = gi2[(512 + tt) * 128 + b]  + b_ih[512 + tt];
  const float inn = gi2[(1024 + tt) * 128 + b] + b_ih[1024 + tt];
  const float hr  = gh[tt * 128 + b]          + b_hh[tt];
  const float hz  = gh[(512 + tt) * 128 + b]  + b_hh[512 + tt];
  const float hn  = gh[(1024 + tt) * 128 + b] + b_hh[1024 + tt];
  const float h   = last_hidden[idx];
  const float r = 1.f / (1.f + __expf(-(ir + hr)));
  const float z = 1.f / (1.f + __expf(-(iz + hz)));
  const float n = tanhf(inn + r * hn);
  const float o = (1.f - z) * n + z * h;
  hnew[idx] = o;
  hnew_out[idx] = o;
}

__global__ __launch_bounds__(128)
void k_qu(const float* __restrict__ hnew, const float* __restrict__ attn_W,
          const float* __restrict__ gc1_W, float* __restrict__ q, float* __restrict__ u)
{
  const int b = blockIdx.x, j = blockIdx.y * 128 + threadIdx.x;
  __shared__ float hs[512];
  for (int i = threadIdx.x; i < 512; i += 128) hs[i] = hnew[b * 512 + i];
  __syncthreads();
  float qa = 0.f, ua = 0.f;
  for (int h = 0; h < 512; ++h) {
    const float hv = hs[h];
    qa += hv * attn_W[(size_t)h * 512 + j];
    ua += hv * gc1_W[(size_t)h * 512 + j];
  }
  q[b * 512 + j] = qa;
  u[b * 512 + j] = ua;
}

__global__ __launch_bounds__(256)
void k_score(const float* __restrict__ q, const float* __restrict__ enc,
             float* __restrict__ scores, ushort_t* __restrict__ encb, int emit)
{
  const int b = blockIdx.x, p = blockIdx.y;
  const int t = threadIdx.x, wv = t >> 6, ln = t & 63;
  __shared__ float qs[512];
  for (int i = t; i < 512; i += 256) qs[i] = q[b * 512 + i];
  __syncthreads();
  const int e0 = ln * 8;
  const float4 q0 = *(const float4*)&qs[e0];
  const float4 q1 = *(const float4*)&qs[e0 + 4];
  for (int it = 0; it < 8; ++it) {
    const int s = p * 32 + wv * 8 + it;
    const float* e = enc + ((size_t)s * 64 + b) * 512 + e0;
    const float4 v0 = *(const float4*)e;
    const float4 v1 = *(const float4*)(e + 4);
    float a = q0.x * v0.x + q0.y * v0.y + q0.z * v0.z + q0.w * v0.w
            + q1.x * v1.x + q1.y * v1.y + q1.z * v1.z + q1.w * v1.w;
    if (emit) {
      short8 o;
      o[0] = (short)f2bf(v0.x); o[1] = (short)f2bf(v0.y);
      o[2] = (short)f2bf(v0.z); o[3] = (short)f2bf(v0.w);
      o[4] = (short)f2bf(v1.x); o[5] = (short)f2bf(v1.y);
      o[6] = (short)f2bf(v1.z); o[7] = (short)f2bf(v1.w);
      *(short8*)&encb[(size_t)b * 262144 + (size_t)s * 512 + e0] = o;
    }
    a = wave_sum(a);
    if (ln == 0) scores[b * 512 + s] = a;
  }
}

__global__ __launch_bounds__(512)
void k_ctx2(const float* __restrict__ scores, const ushort_t* __restrict__ encb,
            const float* __restrict__ enc, float* __restrict__ aw_dout,
            float* __restrict__ aw_ws, float* __restrict__ ctxpart, int use_bf)
{
  const int b = blockIdx.x, p = blockIdx.y, t = threadIdx.x;
  const int w = t >> 6, lane = t & 63;
  __shared__ float sc[512];
  __shared__ float red[8];
  __shared__ float red2[8];
  const float v = scores[b * 512 + t];
  float m = wave_max(v);
  if (lane == 0) red[w] = m;
  __syncthreads();
  float mm = red[0];
#pragma unroll
  for (int i = 1; i < 8; ++i) mm = fmaxf(mm, red[i]);
  const float e = __expf(v - mm);
  float s = wave_sum(e);
  if (lane == 0) red2[w] = s;
  __syncthreads();
  float tot = 0.f;
#pragma unroll
  for (int i = 0; i < 8; ++i) tot += red2[i];
  const float awv = e / tot;
  sc[t] = awv;
  if (p == 0) {
    aw_dout[b * 512 + t] = awv;
    aw_ws[b * 512 + t]   = awv;
  }
  __syncthreads();
  float acc = 0.f;
  if (use_bf) {
#pragma unroll 4
    for (int si = 0; si < 32; ++si)
      acc += sc[p * 32 + si] * bf2f(encb[((size_t)b * 512 + p * 32 + si) * 512 + t]);
  } else {
#pragma unroll 4
    for (int si = 0; si < 32; ++si)
      acc += sc[p * 32 + si] * enc[((size_t)(p * 32 + si) * 64 + b) * 512 + t];
  }
  ctxpart[((size_t)b * 16 + p) * 512 + t] = acc;
}

__global__ __launch_bounds__(128)
void k_concat(const float* __restrict__ hnew, const float* __restrict__ ctxpart,
              const float* __restrict__ cWT, const float* __restrict__ bias,
              float* __restrict__ out_cc, float* __restrict__ cc_ws)
{
  const int b = blockIdx.x, o = blockIdx.y * 128 + threadIdx.x;
  __shared__ __align__(16) float cat[1024];
  for (int m = 0; m < 8; ++m) {
    const int i = threadIdx.x + 128 * m;
    if (i < 512) {
      cat[i] = hnew[b * 512 + i];
    } else {
      const int d = i - 512;
      float s = 0.f;
#pragma unroll
      for (int pp = 0; pp < 16; ++pp) s += ctxpart[((size_t)b * 16 + pp) * 512 + d];
      cat[i] = s;
    }
  }
  __syncthreads();
  float acc = bias[o];
  for (int k = 0; k < 1024; k += 4) {
    acc += cat[k]     * cWT[(size_t)k * 512 + o]
         + cat[k + 1] * cWT[(size_t)(k + 1) * 512 + o]
         + cat[k + 2] * cWT[(size_t)(k + 2) * 512 + o]
         + cat[k + 3] * cWT[(size_t)(k + 3) * 512 + o];
  }
  acc = fmaxf(acc, 0.f);
  out_cc[b * 512 + o] = acc;
  cc_ws[b * 512 + o]  = acc;
}

__global__ __launch_bounds__(256)
void k_adjc(const float* __restrict__ ww, const int* __restrict__ ex,
            ushort_t* __restrict__ adj, int c0)
{
  const size_t i = (size_t)blockIdx.x * 256 + threadIdx.x;
  const size_t base4 = (size_t)c0 * 512 * 512 / 4;
  const float4 w4 = ((const float4*)ww)[base4 + i];
  const int4   e4 = ((const int4*)ex)[base4 + i];
  ushort4 r;
  r.x = (e4.x == 1) ? f2bf(w4.x) : 0;
  r.y = (e4.y == 1) ? f2bf(w4.y) : 0;
  r.z = (e4.z == 1) ? f2bf(w4.z) : 0;
  r.w = (e4.w == 1) ? f2bf(w4.w) : 0;
  ((ushort4*)adj)[i] = r;
}

__global__ __launch_bounds__(256)
void k_encc(const float* __restrict__ enc, ushort_t* __restrict__ encb, int c0)
{
  const size_t i = (size_t)blockIdx.x * 256 + threadIdx.x;
  const size_t el = i * 4;
  const int k = el & 511;
  const int s = (el >> 9) & 511;
  const int z = el >> 18;
  const float4 v = *(const float4*)&enc[((size_t)s * 64 + c0 + z) * 512 + k];
  ushort4 r;
  r.x = f2bf(v.x); r.y = f2bf(v.y); r.z = f2bf(v.z); r.w = f2bf(v.w);
  ((ushort4*)encb)[i] = r;
}

// Barrier-free fused LN + residual + wo_n contraction.
__global__ __launch_bounds__(256)
void k_red2(const ushort_t* __restrict__ w2w, const float* __restrict__ aw,
            const float* __restrict__ hnew, const ushort_t* __restrict__ encb,
            const float* __restrict__ won, const float* __restrict__ ng,
            const float* __restrict__ nb, float* __restrict__ part, int c0)
{
  const int z = blockIdx.x, b = c0 + z, yb = blockIdx.y;
  const int t = threadIdx.x, wv = t >> 6, ln = t & 63;
  __shared__ float sw[32][5];               // won0..3, aw per s-local
  __shared__ float accs[2][4][1024];        // cross-wave combine (32 KB)
  if (t < 160) {
    const int sl = t / 5, c_ = t - sl * 5;
    const int sg = yb * 32 + sl;
    sw[sl][c_] = (c_ < 4) ? won[((size_t)b * 4 + c_) * 512 + sg] : aw[b * 512 + sg];
  }
  const int d0 = ln * 16;
  float gg[16], bb[16], hv[16];
#pragma unroll
  for (int k = 0; k < 16; k += 4) {
    *(float4*)&gg[k] = *(const float4*)&ng[d0 + k];
    *(float4*)&bb[k] = *(const float4*)&nb[d0 + k];
  }
  if (ln < 32) {
#pragma unroll
    for (int k = 0; k < 16; k += 4)
      *(float4*)&hv[k] = *(const float4*)&hnew[b * 512 + d0 + k];
  }
  float acc[4][16];
#pragma unroll
  for (int o = 0; o < 4; ++o)
#pragma unroll
    for (int k = 0; k < 16; ++k) acc[o][k] = 0.f;
  __syncthreads();
  for (int it = 0; it < 8; ++it) {
    const int sl = wv * 8 + it;
    const int s = yb * 32 + sl;
    const ushort_t* row = w2w + ((size_t)z * 512 + s) * 1024 + d0;
    float x[16];
    bf8_to_f(row, x);
    bf8_to_f(row + 8, x + 8);
    float ls = 0.f, lss = 0.f;
#pragma unroll
    for (int k = 0; k < 16; ++k) { ls += x[k]; lss += x[k] * x[k]; }
#pragma unroll
    for (int off = 32; off; off >>= 1) {
      ls  += __shfl_xor(ls,  off, 64);
      lss += __shfl_xor(lss, off, 64);
    }
    const float mean = ls * (1.f / 1024.f);
    const float var  = lss * (1.f / 1024.f) - mean * mean;
    const float inv  = rsqrtf(var + 1e-6f);
    float res[16];
    if (ln < 32) {
      const float a_ = sw[sl][4];
#pragma unroll
      for (int k = 0; k < 16; ++k) res[k] = a_ * hv[k];
    } else {
      const ushort_t* er = encb + ((size_t)z * 512 + s) * 512 + (d0 - 512);
      bf8_to_f(er, res);
      bf8_to_f(er + 8, res + 8);
    }
    const float w0 = sw[sl][0], w1 = sw[sl][1], w2 = sw[sl][2], w3 = sw[sl][3];
#pragma unroll
    for (int k = 0; k < 16; ++k) {
      const float val = (x[k] - mean) * inv * gg[k] + bb[k] + res[k];
      acc[0][k] += w0 * val; acc[1][k] += w1 * val;
      acc[2][k] += w2 * val; acc[3][k] += w3 * val;
    }
  }
  if (wv < 2) {
#pragma unroll
    for (int o = 0; o < 4; ++o)
#pragma unroll
      for (int k = 0; k < 16; k += 4)
        *(float4*)&accs[wv][o][d0 + k] = *(float4*)&acc[o][k];
  }
  __syncthreads();
  if (wv >= 2) {
#pragma unroll
    for (int o = 0; o < 4; ++o)
#pragma unroll
      for (int k = 0; k < 16; ++k)
        accs[wv - 2][o][d0 + k] += acc[o][k];
  }
  __syncthreads();
  for (int i = t; i < 4096; i += 256) {
    const int o = i >> 10, d = i & 1023;
    part[(((size_t)(b * 16 + yb) * 4 + o) << 10) + d] = accs[0][o][d] + accs[1][o][d];
  }
}

// sum 16 partials -> ctx_op bf16 (256 x 1024)
__global__ __launch_bounds__(256)
void k_psum(const float* __restrict__ part, ushort_t* __restrict__ ctxop)
{
  const int idx = blockIdx.x * 256 + threadIdx.x;   // 262144
  const int r = idx >> 10, d = idx & 1023;
  const int b = r >> 2, o = r & 3;
  float s = 0.f;
#pragma unroll
  for (int p = 0; p < 16; ++p)
    s += part[(((size_t)(b * 16 + p) * 4 + o) << 10) + d];
  ctxop[idx] = f2bf(s);
}

__global__ __launch_bounds__(512)
void k_ln1(const float* __restrict__ oppre, const float* __restrict__ wo_b,
           const float* __restrict__ n1g, const float* __restrict__ n1b,
           const float* __restrict__ ops, ushort_t* __restrict__ opall)
{
  const int r = blockIdx.x, t = threadIdx.x;
  const int o = r & 3;
  __shared__ float2 red[8];
  const float val = fmaxf(oppre[(size_t)r * 512 + t] + wo_b[t], 0.f);
  const float2 ss = blocksum2(val, val * val, red, t, 8);
  const float m = ss.x * (1.f / 512.f);
  const float v = ss.y * (1.f / 512.f) - m * m;
  const float s1 = (val - m) * rsqrtf(v + 1e-6f) * n1g[t] + n1b[t];
  opall[(size_t)r * 1024 + t] = f2bf(s1);
  opall[(size_t)r * 1024 + 512 + t] = f2bf(ops[o * 512 + t]);
}

__global__ __launch_bounds__(512)
void k_ln2dot(const float* __restrict__ ohpre, const float* __restrict__ ot_b,
              const float* __restrict__ n2g, const float* __restrict__ n2b,
              const float* __restrict__ ops, const float* __restrict__ cc,
              const float* __restrict__ ops_bias, float* __restrict__ oo)
{
  const int r = blockIdx.x, t = threadIdx.x;
  const int b = r >> 2, o = r & 3;
  __shared__ float2 red[8];
  const float oh = fmaxf(ohpre[(size_t)r * 512 + t] + ot_b[t], 0.f);
  const float2 ss = blocksum2(oh, oh * oh, red, t, 8);
  const float m = ss.x * (1.f / 512.f);
  const float v = ss.y * (1.f / 512.f) - m * m;
  const float opo = (oh - m) * rsqrtf(v + 1e-6f) * n2g[t] + n2b[t] + ops[o * 512 + t];
  const float p = cc[b * 512 + t] * opo;
  const float2 s3 = blocksum2(p, 0.f, red, t, 8);
  if (t == 0) oo[r] = s3.x + ops_bias[o];
}

__global__ __launch_bounds__(128)
void k_final(const float* __restrict__ oo, const float* __restrict__ cc,
             const float* __restrict__ nWT, const float* __restrict__ nop_b,
             float* __restrict__ outp)
{
  const int b = blockIdx.x, t = threadIdx.x;
  __shared__ __align__(16) float ccs[512];
  __shared__ float red[2];
  __shared__ float red2[2];
  for (int i = t; i < 512; i += 128) ccs[i] = cc[b * 512 + i];
  __syncthreads();
  float v;
  if (t < 4) {
    v = oo[b * 4 + t];
  } else {
    const int j = t - 4;
    float a = nop_b[j];
    for (int k = 0; k < 512; ++k) a += ccs[k] * nWT[k * 128 + j];
    v = a;
  }
  float m = wave_max(v);
  if ((t & 63) == 0) red[t >> 6] = m;
  __syncthreads();
  m = fmaxf(red[0], red[1]);
  const float e = __expf(v - m);
  float s = wave_sum(e);
  if ((t & 63) == 0) red2[t >> 6] = s;
  __syncthreads();
  s = red2[0] + red2[1];
  outp[b * 128 + t] = v - m - logf(s);
}

} // namespace

extern "C" void kernel_launch(void* const* d_in, const int* in_sizes, int n_in,
                              void* d_out, int out_size, void* d_ws, size_t ws_size,
                              hipStream_t stream)
{
  const int*   input_step  = (const int*)  d_in[0];
  const float* last_hidden = (const float*)d_in[1];
  const float* enc         = (const float*)d_in[2];
  const float* word_word   = (const float*)d_in[3];
  const float* word_op     = (const float*)d_in[4];
  const int*   word_exist  = (const int*)  d_in[5];
  const int*   seq_mask    = (const int*)  d_in[6];
  const float* emb         = (const float*)d_in[7];
  const float* W_ih        = (const float*)d_in[8];
  const float* W_hh        = (const float*)d_in[9];
  const float* b_ih        = (const float*)d_in[10];
  const float* b_hh        = (const float*)d_in[11];
  const float* attn_W      = (const float*)d_in[12];
  const float* concat_W    = (const float*)d_in[14];
  const float* concat_b    = (const float*)d_in[15];
  const float* ops         = (const float*)d_in[16];
  const float* ops_bias    = (const float*)d_in[17];
  const float* nop_W       = (const float*)d_in[18];
  const float* nop_b       = (const float*)d_in[19];
  const float* gc1_W       = (const float*)d_in[20];
  const float* gc1_b       = (const float*)d_in[21];
  const float* gc2_W       = (const float*)d_in[22];
  const float* gc2_b       = (const float*)d_in[23];
  const float* norm_g      = (const float*)d_in[24];
  const float* norm_b      = (const float*)d_in[25];
  const float* norm1_g     = (const float*)d_in[26];
  const float* norm1_b     = (const float*)d_in[27];
  const float* norm2_g     = (const float*)d_in[28];
  const float* norm2_b     = (const float*)d_in[29];
  const float* wo_W        = (const float*)d_in[30];
  const float* wo_b        = (const float*)d_in[31];
  const float* ot_W        = (const float*)d_in[32];
  const float* ot_b        = (const float*)d_in[33];

  float* ws  = (float*)d_ws;
  float* out = (float*)d_out;

  // ---- workspace layout (floats) ----
  size_t off = 0;
  auto take = [&](size_t n) { size_t o = off; off += n; return o; };
  const size_t o_hnew = take(32768);
  const size_t o_q    = take(32768);
  const size_t o_u    = take(32768);
  const size_t o_aw   = take(32768);
  const size_t o_scores = take(32768);
  const size_t o_ctxpart = take(524288);   // 64*16*512
  const size_t o_cc   = take(32768);
  const size_t o_won  = take(131072);
  const size_t o_oo   = take(256);
  const size_t o_gi2  = take(393216);      // 2 x 1536 x 128 f32
  const size_t o_part = take(4194304);     // 64*16*4*1024
  const size_t o_oppre = take(131072);
  const size_t o_ohpre = take(131072);
  const size_t o_gc1LT = take(131072);
  const size_t o_gc2WT = take(262144);
  const size_t o_woW   = take(262144);
  const size_t o_otW   = take(262144);
  const size_t o_cWT   = take(524288);
  const size_t o_nWT   = take(65536);
  const size_t o_wihb  = take(786432);     // 2 x 1536 x 512 bf16
  const size_t o_xhb   = take(65536);      // 2 x 128 x 512 bf16
  const size_t o_ctxop = take(131072);
  const size_t o_opall = take(131072);
  const size_t base = off;

  // pick chunk size by available workspace (constant across calls -> graph-safe)
  int CB = 16;
  if (ws_size >= (base + 64ull * 524288) * 4) CB = 64;
  else if (ws_size >= (base + 32ull * 524288) * 4) CB = 32;
  const int nch = 64 / CB;

  const size_t o_adjbf = take((size_t)CB * 131072);
  const size_t o_h1t   = take((size_t)CB * 131072);
  const size_t o_encbf = take((size_t)CB * 131072);
  const size_t o_xw1t  = take((size_t)CB * 131072);
  const size_t o_tmat  = o_xw1t;           // overlays xw1t (dead after mgemm<1>)
  const size_t o_w2w   = o_adjbf;          // overlays adjbf+h1t (dead after mgemm<2>)

  float* hnew = ws + o_hnew;
  float* q    = ws + o_q;
  float* u    = ws + o_u;
  float* aw   = ws + o_aw;
  float* scores = ws + o_scores;
  float* ctxpart = ws + o_ctxpart;
  float* cc   = ws + o_cc;
  float* won  = ws + o_won;
  float* oo   = ws + o_oo;
  float* gi2  = ws + o_gi2;
  float* part = ws + o_part;
  float* oppre = ws + o_oppre;
  float* ohpre = ws + o_ohpre;
  float* cWT  = ws + o_cWT;
  float* nWT  = ws + o_nWT;
  ushort_t* gc1LT = (ushort_t*)(ws + o_gc1LT);
  ushort_t* gc2WT = (ushort_t*)(ws + o_gc2WT);
  ushort_t* woWb  = (ushort_t*)(ws + o_woW);
  ushort_t* otWb  = (ushort_t*)(ws + o_otW);
  ushort_t* wihb  = (ushort_t*)(ws + o_wihb);
  ushort_t* xhb   = (ushort_t*)(ws + o_xhb);
  ushort_t* ctxop = (ushort_t*)(ws + o_ctxop);
  ushort_t* opall = (ushort_t*)(ws + o_opall);
  ushort_t* adjbf = (ushort_t*)(ws + o_adjbf);
  ushort_t* h1t   = (ushort_t*)(ws + o_h1t);
  ushort_t* encbf = (ushort_t*)(ws + o_encbf);
  ushort_t* xw1t  = (ushort_t*)(ws + o_xw1t);
  ushort_t* tmat  = (ushort_t*)(ws + o_tmat);
  ushort_t* w2wbf = (ushort_t*)(ws + o_w2w);

  float* out_logits = out;
  float* out_hnew   = out + 8192;
  float* out_aw     = out + 8192 + 32768;
  float* out_cc     = out + 8192 + 65536;

  const int full = (CB == 64) ? 1 : 0;

  // ---- front: transposed weights (LDS tiled) + bulk streams ----
  k_tw<<<dim3(512, 4), 256, 0, stream>>>(gc1_W, gc2_W, concat_W, nop_W,
      gc1LT, gc2WT, cWT, nWT);
  k_front2<<<2048, 256, 0, stream>>>(input_step, emb, last_hidden,
      wo_W, ot_W, W_ih, W_hh, word_word, word_exist, word_op, seq_mask,
      woWb, otWb, wihb, xhb, adjbf, won, full);

  // ---- GRU via MFMA: gi/gh = [W_ih;W_hh] @ [x;h]^T, N padded to 128 ----
  mgemm<4><<<dim3(1, 12, 2), 256, 0, stream>>>(wihb, 512, 786432, xhb, 512, 65536,
      gi2, 128, 196608, 512, nullptr, nullptr, nullptr, 0);
  k_gru<<<128, 256, 0, stream>>>(gi2, last_hidden, b_ih, b_hh, hnew, out_hnew);

  // ---- attention + concat ----
  k_qu<<<dim3(64, 4), 128, 0, stream>>>(hnew, attn_W, gc1_W, q, u);
  k_score<<<dim3(64, 16), 256, 0, stream>>>(q, enc, scores, encbf, full);
  k_ctx2<<<dim3(64, 16), 512, 0, stream>>>(scores, encbf, enc, out_aw, aw, ctxpart, full);
  k_concat<<<dim3(64, 4), 128, 0, stream>>>(hnew, ctxpart, cWT, concat_b, out_cc, cc);

  // ---- GCN chain (bf16 MFMA, 256x256 tiles), chunked ----
  for (int c = 0; c < nch; ++c) {
    const int c0 = c * CB;
    if (!full) {
      k_adjc<<<CB * 256, 256, 0, stream>>>(word_word, word_exist, adjbf, c0);
      k_encc<<<CB * 256, 256, 0, stream>>>(enc, encbf, c0);
    }
    // XW1T[d][s] = gc1LT[d][:] . enc_b[s][:] + u[b][d]*aw[b][s]
    mgemm2<0><<<dim3(2, 2, CB), 512, 0, stream>>>(gc1LT, 512, 0, encbf, 512, 262144,
        xw1t, 512, 262144, 512, nullptr, aw, u, c0);
    // h1T[d][s] = relu(XW1T[d][:] . adj[s][:] + gc1_b[d])
    mgemm2<1><<<dim3(2, 2, CB), 512, 0, stream>>>(xw1t, 512, 262144, adjbf, 512, 262144,
        h1t, 512, 262144, 512, gc1_b, nullptr, nullptr, 0);
    // t[s][d] = adj[s][:] . h1T[d][:]   (overlays xw1t, dead)
    mgemm2<2><<<dim3(2, 2, CB), 512, 0, stream>>>(adjbf, 512, 262144, h1t, 512, 262144,
        tmat, 512, 262144, 512, nullptr, nullptr, nullptr, 0);
    // w2w[s][e] = t[s][:] . gc2WT[e][:] + gc2_b[e]   (overlays adjbf+h1t, dead)
    mgemm2<3><<<dim3(4, 2, CB), 512, 0, stream>>>(tmat, 512, 262144, gc2WT, 512, 0,
        w2wbf, 1024, 524288, 512, gc2_b, nullptr, nullptr, 0);
    k_red2<<<dim3(CB, 16), 256, 0, stream>>>(w2wbf, aw, hnew, encbf, won, norm_g, norm_b, part, c0);
  }

  // ---- op head (MFMA GEMMs) + nop head + log_softmax ----
  k_psum<<<1024, 256, 0, stream>>>(part, ctxop);
  mgemm<4><<<dim3(4, 2, 1), 256, 0, stream>>>(ctxop, 1024, 0, woWb, 1024, 0,
      oppre, 512, 0, 1024, nullptr, nullptr, nullptr, 0);
  k_ln1<<<256, 512, 0, stream>>>(oppre, wo_b, norm1_g, norm1_b, ops, opall);
  mgemm<4><<<dim3(4, 2, 1), 256, 0, stream>>>(opall, 1024, 0, otWb, 1024, 0,
      ohpre, 512, 0, 1024, nullptr, nullptr, nullptr, 0);
  k_ln2dot<<<256, 512, 0, stream>>>(ohpre, ot_b, norm2_g, norm2_b, ops, cc, ops_bias, oo);
  k_final<<<64, 128, 0, stream>>>(oo, cc, nWT, nop_b, out_logits);

  (void)in_sizes; (void)n_in; (void)out_size;
}

// Round 11
// 597.797 us; speedup vs baseline: 1.2458x; 1.0727x over previous
//
#include <hip/hip_runtime.h>
#include <math.h>

namespace {

typedef unsigned short ushort_t;
typedef __attribute__((ext_vector_type(8))) short short8;
typedef __attribute__((ext_vector_type(4))) float float4v;
typedef __attribute__((ext_vector_type(4))) float f32x4v;
typedef __attribute__((ext_vector_type(4))) int i32x4v;

__device__ __forceinline__ unsigned short f2bf(float x) {
  unsigned u = __float_as_uint(x);
  u += 0x7fffu + ((u >> 16) & 1u);        // RNE
  return (unsigned short)(u >> 16);
}
__device__ __forceinline__ float bf2f(unsigned short u) {
  return __uint_as_float((unsigned)u << 16);
}
__device__ __forceinline__ void bf8_to_f(const ushort_t* p, float* o) {
  const short8 v = *(const short8*)p;
#pragma unroll
  for (int k = 0; k < 8; ++k) o[k] = bf2f((unsigned short)v[k]);
}
__device__ __forceinline__ ushort4 f4bf(float4 v) {
  ushort4 r;
  r.x = f2bf(v.x); r.y = f2bf(v.y); r.z = f2bf(v.z); r.w = f2bf(v.w);
  return r;
}

__device__ __forceinline__ float wave_sum(float v) {
#pragma unroll
  for (int off = 32; off; off >>= 1) v += __shfl_down(v, off, 64);
  return v;
}
__device__ __forceinline__ float wave_max(float v) {
#pragma unroll
  for (int off = 32; off; off >>= 1) v = fmaxf(v, __shfl_down(v, off, 64));
  return v;
}
__device__ __forceinline__ float2 blocksum2(float a, float b, float2* red, int t, int nw) {
#pragma unroll
  for (int off = 32; off; off >>= 1) {
    a += __shfl_down(a, off, 64);
    b += __shfl_down(b, off, 64);
  }
  __syncthreads();
  if ((t & 63) == 0) red[t >> 6] = make_float2(a, b);
  __syncthreads();
  float sa = 0.f, sb = 0.f;
  for (int i = 0; i < nw; ++i) { sa += red[i].x; sb += red[i].y; }
  return make_float2(sa, sb);
}

// =================== bf16 MFMA NT-GEMM, 128x128 tile (r4-verified) ===========
// Used for GRU and op-head GEMMs.  3-buffer ring, depth-2 prefetch,
// one barrier per K-step.  XCD swizzle when nz%8==0.  LDS seg-XOR (0 conflicts).
template<int MODE>
__global__ __launch_bounds__(256)
void mgemm(const ushort_t* __restrict__ A, int lda, long sA,
           const ushort_t* __restrict__ Bt, int ldb, long sB,
           void* __restrict__ C, int ldc, long sC, int K,
           const float* __restrict__ bias,
           const float* __restrict__ aw, const float* __restrict__ u, int c0)
{
  __shared__ __attribute__((aligned(16))) ushort_t As[3][128 * 32];
  __shared__ __attribute__((aligned(16))) ushort_t Bs[3][128 * 32];

  int bx = blockIdx.x, by = blockIdx.y, bz = blockIdx.z;
  const int nx = gridDim.x, ny = gridDim.y, nz = gridDim.z;
  if ((nz & 7) == 0) {
    const int nxy = nx * ny;
    const int L = bx + nx * (by + ny * bz);
    const int xcd = L & 7;
    const int idx = L >> 3;
    const int lz = idx / nxy;
    const int xy = idx - lz * nxy;
    bz = xcd + 8 * lz;
    bx = xy % nx;
    by = xy / nx;
  }

  const int z = bz;
  const ushort_t* Ab = A  + (long)z * sA;
  const ushort_t* Bb = Bt + (long)z * sB;
  const int tm = by * 128, tn = bx * 128;
  const int t = threadIdx.x, wv = t >> 6, ln = t & 63;
  const int lrow = ln >> 2, lseg = ln & 3;        // staging: 16 rows x 4 segs of 16B
  const int gseg = lseg ^ ((lrow >> 1) & 3);      // bank-conflict-free seg XOR
  const int frow = ln & 15, q = ln >> 4;          // fragment: m=ln&15, k-quad
  const int sw8 = (frow >> 1) & 3;
  const int aoff = (q ^ sw8) << 3;
  const int wm = (wv >> 1) * 64, wn = (wv & 1) * 64;

  float4v acc[4][4];
#pragma unroll
  for (int i = 0; i < 4; ++i)
#pragma unroll
    for (int j = 0; j < 4; ++j) acc[i][j] = (float4v)0.f;

  auto STAGE = [&](int s, int ks) {
    const int kc = ks * 32 + gseg * 8;
#pragma unroll
    for (int half = 0; half < 2; ++half) {
      const int rbase = wv * 32 + half * 16;
      const ushort_t* ga = Ab + (long)(tm + rbase + lrow) * lda + kc;
      const ushort_t* gb = Bb + (long)(tn + rbase + lrow) * ldb + kc;
      __builtin_amdgcn_global_load_lds(
          (const __attribute__((address_space(1))) void*)ga,
          (__attribute__((address_space(3))) void*)&As[s][rbase * 32], 16, 0, 0);
      __builtin_amdgcn_global_load_lds(
          (const __attribute__((address_space(1))) void*)gb,
          (__attribute__((address_space(3))) void*)&Bs[s][rbase * 32], 16, 0, 0);
    }
  };
  auto COMPUTE = [&](const ushort_t* Asb, const ushort_t* Bsb) {
    short8 af[4], bfr[4];
#pragma unroll
    for (int i = 0; i < 4; ++i) af[i]  = *(const short8*)&Asb[(wm + i * 16 + frow) * 32 + aoff];
#pragma unroll
    for (int j = 0; j < 4; ++j) bfr[j] = *(const short8*)&Bsb[(wn + j * 16 + frow) * 32 + aoff];
    __builtin_amdgcn_s_setprio(1);
#pragma unroll
    for (int i = 0; i < 4; ++i)
#pragma unroll
      for (int j = 0; j < 4; ++j)
        acc[i][j] = __builtin_amdgcn_mfma_f32_16x16x32_bf16(af[i], bfr[j], acc[i][j], 0, 0, 0);
    __builtin_amdgcn_s_setprio(0);
  };

  const int NS = K >> 5;   // 32-wide K-steps
  STAGE(0, 0);
  if (NS > 1) STAGE(1, 1);
  int cur = 0;
  for (int ks = 0; ks < NS; ++ks) {
    if (ks + 1 < NS) asm volatile("s_waitcnt vmcnt(4)" ::: "memory");
    else             asm volatile("s_waitcnt vmcnt(0)" ::: "memory");
    __builtin_amdgcn_s_barrier();
    if (ks + 2 < NS) {
      int nxt = cur + 2; if (nxt >= 3) nxt -= 3;
      STAGE(nxt, ks + 2);
    }
    COMPUTE(As[cur], Bs[cur]);
    ++cur; if (cur >= 3) cur -= 3;
  }

  // epilogue: C/D layout col=lane&15, row=(lane>>4)*4+reg
#pragma unroll
  for (int i = 0; i < 4; ++i) {
#pragma unroll
    for (int j = 0; j < 4; ++j) {
      const int col = tn + wn + j * 16 + (ln & 15);
#pragma unroll
      for (int reg = 0; reg < 4; ++reg) {
        const int row = tm + wm + i * 16 + (ln >> 4) * 4 + reg;
        float v = acc[i][j][reg];
        if (MODE == 0) v += u[(c0 + z) * 512 + row] * aw[(c0 + z) * 512 + col];
        else if (MODE == 1) v = fmaxf(v + bias[row], 0.f);
        else if (MODE == 3) v += bias[col];
        if (MODE == 4) ((float*)C)[(long)z * sC + (long)row * ldc + col] = v;
        else ((ushort_t*)C)[(long)z * sC + (long)row * ldc + col] = f2bf(v);
      }
    }
  }
}

// =================== bf16 MFMA NT-GEMM, 256x256 tile (GCN chain) =============
// 512 threads = 8 waves (2x4); per-wave output 128x64, acc[8][4].
// BK=32, 2-slot ping-pong, 64 KB LDS -> 2 blocks/CU.  Schedule per K-step:
//   STAGE(nxt) -> vmcnt(4) -> barrier -> 32 MFMA -> barrier.
template<int MODE>
__global__ __launch_bounds__(512)
void mgemm2(const ushort_t* __restrict__ A, int lda, long sA,
            const ushort_t* __restrict__ Bt, int ldb, long sB,
            void* __restrict__ C, int ldc, long sC, int K,
            const float* __restrict__ bias,
            const float* __restrict__ aw, const float* __restrict__ u, int c0)
{
  __shared__ __attribute__((aligned(16))) ushort_t As[2][256 * 32];
  __shared__ __attribute__((aligned(16))) ushort_t Bs[2][256 * 32];

  int bx = blockIdx.x, by = blockIdx.y, bz = blockIdx.z;
  const int nx = gridDim.x, ny = gridDim.y, nz = gridDim.z;
  if ((nz & 7) == 0) {
    const int nxy = nx * ny;
    const int L = bx + nx * (by + ny * bz);
    const int xcd = L & 7;
    const int idx = L >> 3;
    const int lz = idx / nxy;
    const int xy = idx - lz * nxy;
    bz = xcd + 8 * lz;
    bx = xy % nx;
    by = xy / nx;
  }

  const int z = bz;
  const ushort_t* Ab = A  + (long)z * sA;
  const ushort_t* Bb = Bt + (long)z * sB;
  const int tm = by * 256, tn = bx * 256;
  const int t = threadIdx.x, wv = t >> 6, ln = t & 63;   // wv 0..7
  const int lrow = ln >> 2, lseg = ln & 3;
  const int gseg = lseg ^ ((lrow >> 1) & 3);
  const int frow = ln & 15, q = ln >> 4;
  const int sw8 = (frow >> 1) & 3;
  const int aoff = (q ^ sw8) << 3;
  const int wm = (wv >> 2) * 128, wn = (wv & 3) * 64;    // 2x4 wave grid

  float4v acc[8][4];
#pragma unroll
  for (int i = 0; i < 8; ++i)
#pragma unroll
    for (int j = 0; j < 4; ++j) acc[i][j] = (float4v)0.f;

  auto STAGE = [&](int s, int ks) {
    const int kc = ks * 32 + gseg * 8;
#pragma unroll
    for (int half = 0; half < 2; ++half) {
      const int rbase = wv * 32 + half * 16;             // 0..240 step 16
      const ushort_t* ga = Ab + (long)(tm + rbase + lrow) * lda + kc;
      const ushort_t* gb = Bb + (long)(tn + rbase + lrow) * ldb + kc;
      __builtin_amdgcn_global_load_lds(
          (const __attribute__((address_space(1))) void*)ga,
          (__attribute__((address_space(3))) void*)&As[s][rbase * 32], 16, 0, 0);
      __builtin_amdgcn_global_load_lds(
          (const __attribute__((address_space(1))) void*)gb,
          (__attribute__((address_space(3))) void*)&Bs[s][rbase * 32], 16, 0, 0);
    }
  };
  auto COMPUTE = [&](const ushort_t* Asb, const ushort_t* Bsb) {
    short8 af[8], bfr[4];
#pragma unroll
    for (int i = 0; i < 8; ++i) af[i]  = *(const short8*)&Asb[(wm + i * 16 + frow) * 32 + aoff];
#pragma unroll
    for (int j = 0; j < 4; ++j) bfr[j] = *(const short8*)&Bsb[(wn + j * 16 + frow) * 32 + aoff];
    __builtin_amdgcn_s_setprio(1);
#pragma unroll
    for (int i = 0; i < 8; ++i)
#pragma unroll
      for (int j = 0; j < 4; ++j)
        acc[i][j] = __builtin_amdgcn_mfma_f32_16x16x32_bf16(af[i], bfr[j], acc[i][j], 0, 0, 0);
    __builtin_amdgcn_s_setprio(0);
  };

  const int NS = K >> 5;   // 32-wide K-steps (16 for K=512)
  STAGE(0, 0);
  for (int ks = 0; ks < NS; ++ks) {
    const int cur = ks & 1;
    if (ks + 1 < NS) {
      STAGE(cur ^ 1, ks + 1);
      asm volatile("s_waitcnt vmcnt(4)" ::: "memory");
    } else {
      asm volatile("s_waitcnt vmcnt(0)" ::: "memory");
    }
    __builtin_amdgcn_s_barrier();
    COMPUTE(As[cur], Bs[cur]);
    __builtin_amdgcn_s_barrier();
  }

  // epilogue: C/D layout col=lane&15, row=(lane>>4)*4+reg
#pragma unroll
  for (int i = 0; i < 8; ++i) {
#pragma unroll
    for (int j = 0; j < 4; ++j) {
      const int col = tn + wn + j * 16 + (ln & 15);
#pragma unroll
      for (int reg = 0; reg < 4; ++reg) {
        const int row = tm + wm + i * 16 + (ln >> 4) * 4 + reg;
        float v = acc[i][j][reg];
        if (MODE == 0) v += u[(c0 + z) * 512 + row] * aw[(c0 + z) * 512 + col];
        else if (MODE == 1) v = fmaxf(v + bias[row], 0.f);
        else if (MODE == 3) v += bias[col];
        ((ushort_t*)C)[(long)z * sC + (long)row * ldc + col] = f2bf(v);
      }
    }
  }
}

// =================== transposed-weight conversions (LDS tiled) ===================
__global__ __launch_bounds__(256)
void k_tw(const float* __restrict__ gc1_W, const float* __restrict__ gc2_W,
          const float* __restrict__ concat_W, const float* __restrict__ nop_W,
          ushort_t* __restrict__ gc1LT, ushort_t* __restrict__ gc2WT,
          float* __restrict__ cWT, float* __restrict__ nWT)
{
  __shared__ float tile[32][33];
  const int job = blockIdx.y;
  const float* src; int sr, sc;
  if (job == 0)      { src = gc1_W + 262144; sr = 512; sc = 512;  }
  else if (job == 1) { src = gc2_W;          sr = 512; sc = 1024; }
  else if (job == 2) { src = concat_W;       sr = 512; sc = 1024; }
  else               { src = nop_W;          sr = 124; sc = 512;  }
  const int tpr = sc >> 5;
  const int ntile = ((sr + 31) >> 5) * tpr;
  if ((int)blockIdx.x >= ntile) return;
  const int tr = (blockIdx.x / tpr) * 32, tc = (blockIdx.x % tpr) * 32;
  const int t = threadIdx.x, tx = t & 31, ty = t >> 5;   // 8 rows per pass
#pragma unroll
  for (int p = 0; p < 4; ++p) {
    const int r = tr + ty + p * 8;
    tile[ty + p * 8][tx] = (r < sr) ? src[(size_t)r * sc + tc + tx] : 0.f;
  }
  __syncthreads();
#pragma unroll
  for (int p = 0; p < 4; ++p) {
    const int dr = tc + ty + p * 8;   // dst row = src col
    const int dc = tr + tx;           // dst col = src row
    const float v = tile[tx][ty + p * 8];
    if (job == 0)      gc1LT[(size_t)dr * 512 + dc] = f2bf(v);
    else if (job == 1) gc2WT[(size_t)dr * 512 + dc] = f2bf(v);
    else if (job == 2) cWT[(size_t)dr * 512 + dc] = v;
    else               nWT[(size_t)dr * 128 + dc] = v;   // dc < 128 always (sr pad)
  }
}

// =================== bulk front kernel — nt-loads on adjacency stream ========
// The 128 MB read-once ww/ex stream now uses __builtin_nontemporal_load
// (no-allocate) to relieve L2/L3 fill pressure against the write stream.
__global__ __launch_bounds__(256)
void k_front2(const int* __restrict__ step, const float* __restrict__ emb,
              const float* __restrict__ last_hidden,
              const float* __restrict__ wo_W, const float* __restrict__ ot_W,
              const float* __restrict__ W_ih, const float* __restrict__ W_hh,
              const float* __restrict__ ww, const int* __restrict__ ex,
              const float* __restrict__ word_op, const int* __restrict__ seq_mask,
              ushort_t* __restrict__ woWb, ushort_t* __restrict__ otWb,
              ushort_t* __restrict__ wihb, ushort_t* __restrict__ xhb,
              ushort_t* __restrict__ adj, float* __restrict__ won, int do_adj)
{
  const int blk = blockIdx.x;
  const int t = threadIdx.x;
  const size_t u0 = (size_t)blk * 256 + t;           // < 524288

  // ---- adjacency: 8 fixed units/thread, fully unrolled, NT loads ----
  if (do_adj) {
    f32x4v w[8]; i32x4v e[8];
#pragma unroll
    for (int k = 0; k < 8; ++k) {
      w[k] = __builtin_nontemporal_load((const f32x4v*)ww + u0 + (size_t)k * 524288);
      e[k] = __builtin_nontemporal_load((const i32x4v*)ex + u0 + (size_t)k * 524288);
    }
#pragma unroll
    for (int k = 0; k < 8; ++k) {
      ushort4 r;
      r.x = (e[k][0] == 1) ? f2bf(w[k][0]) : 0;
      r.y = (e[k][1] == 1) ? f2bf(w[k][1]) : 0;
      r.z = (e[k][2] == 1) ? f2bf(w[k][2]) : 0;
      r.w = (e[k][3] == 1) ? f2bf(w[k][3]) : 0;
      ((ushort4*)adj)[u0 + (size_t)k * 524288] = r;
    }
  }

  // ---- copies: unit A (always) + unit B (u0 < 163840) ----
  if (u0 < 131072) {
    ((ushort4*)woWb)[u0] = f4bf(((const float4*)wo_W)[u0]);
    const size_t i2 = u0 + 262144;
    ((ushort4*)wihb)[i2] = f4bf(((const float4*)W_hh)[i2 - 196608]);
  } else if (u0 < 262144) {
    const size_t i = u0 - 131072;
    ((ushort4*)otWb)[i] = f4bf(((const float4*)ot_W)[i]);
    if (u0 < 163840) {
      const size_t e = i * 4;
      const int z = (int)(e >> 16), b = (int)((e >> 9) & 127), k = (int)(e & 511);
      float4 v = make_float4(0.f, 0.f, 0.f, 0.f);
      if (b < 64)
        v = z ? *(const float4*)&last_hidden[b * 512 + k]
              : *(const float4*)&emb[(size_t)step[b] * 512 + k];
      ((ushort4*)xhb)[i] = f4bf(v);
    }
  } else {
    const size_t i = u0 - 262144;    // < 262144: wihb first part
    const float4 v = (i < 196608) ? ((const float4*)W_ih)[i]
                                  : ((const float4*)W_hh)[i - 196608];
    ((ushort4*)wihb)[i] = f4bf(v);
  }

  // ---- wo_n normalization: blocks 0..63, one per batch ----
  if (blk < 64) {
    const int b = blk;
    __shared__ float red[4][4];               // [wave][o]
    float4 a0 = ((const float4*)word_op)[b * 512 + t];
    float4 a1 = ((const float4*)word_op)[b * 512 + t + 256];
    if (seq_mask[b * 512 + t])       a0 = make_float4(0.f, 0.f, 0.f, 0.f);
    if (seq_mask[b * 512 + t + 256]) a1 = make_float4(0.f, 0.f, 0.f, 0.f);
    float l0 = a0.x + a1.x, l1 = a0.y + a1.y, l2 = a0.z + a1.z, l3 = a0.w + a1.w;
#pragma unroll
    for (int off = 32; off; off >>= 1) {
      l0 += __shfl_down(l0, off, 64);
      l1 += __shfl_down(l1, off, 64);
      l2 += __shfl_down(l2, off, 64);
      l3 += __shfl_down(l3, off, 64);
    }
    if ((t & 63) == 0) {
      red[t >> 6][0] = l0; red[t >> 6][1] = l1;
      red[t >> 6][2] = l2; red[t >> 6][3] = l3;
    }
    __syncthreads();
    const float tot0 = red[0][0] + red[1][0] + red[2][0] + red[3][0] + 1e-30f;
    const float tot1 = red[0][1] + red[1][1] + red[2][1] + red[3][1] + 1e-30f;
    const float tot2 = red[0][2] + red[1][2] + red[2][2] + red[3][2] + 1e-30f;
    const float tot3 = red[0][3] + red[1][3] + red[2][3] + red[3][3] + 1e-30f;
    float* w0 = won + ((size_t)b * 4 + 0) * 512;
    float* w1 = won + ((size_t)b * 4 + 1) * 512;
    float* w2 = won + ((size_t)b * 4 + 2) * 512;
    float* w3 = won + ((size_t)b * 4 + 3) * 512;
    w0[t] = a0.x / tot0; w0[t + 256] = a1.x / tot0;
    w1[t] = a0.y / tot1; w1[t + 256] = a1.y / tot1;
    w2[t] = a0.z / tot2; w2[t + 256] = a1.z / tot2;
    w3[t] = a0.w / tot3; w3[t + 256] = a1.w / tot3;
  }
}

// =================== small fused kernels ===================

__global__ __launch_bounds__(256)
void k_gru(const float* __restrict__ gi2, const float* __restrict__ last_hidden,
           const float* __restrict__ b_ih, const float* __restrict__ b_hh,
           float* __restrict__ hnew, float* __restrict__ hnew_out)
{
  const int idx = blockIdx.x * 256 + threadIdx.x;
  const int b = idx >> 9, tt = idx & 511;
  const float* gh = gi2 + 196608;
  const float ir  = gi2[tt * 128 + b]          + b_ih[tt];
  const float iz  = gi2[(512 + tt) * 128 + b]  + b_ih[512 + tt];
  const float inn = gi2[(1024 + tt) * 128 + b] + b_ih[1024 + tt];
  const float hr  = gh[tt * 128 + b]          + b_hh[tt];
  const float hz  = gh[(512 + tt) * 128 + b]  + b_hh[512 + tt];
  const float hn  = gh[(1024 + tt) * 128 + b] + b_hh[1024 + tt];
  const float h   = last_hidden[idx];
  const float r = 1.f / (1.f + __expf(-(ir + hr)));
  const float z = 1.f / (1.f + __expf(-(iz + hz)));
  const float n = tanhf(inn + r * hn);
  const float o = (1.f - z) * n + z * h;
  hnew[idx] = o;
  hnew_out[idx] = o;
}

__global__ __launch_bounds__(128)
void k_qu(const float* __restrict__ hnew, const float* __restrict__ attn_W,
          const float* __restrict__ gc1_W, float* __restrict__ q, float* __restrict__ u)
{
  const int b = blockIdx.x, j = blockIdx.y * 128 + threadIdx.x;
  __shared__ float hs[512];
  for (int i = threadIdx.x; i < 512; i += 128) hs[i] = hnew[b * 512 + i];
  __syncthreads();
  float qa = 0.f, ua = 0.f;
  for (int h = 0; h < 512; ++h) {
    const float hv = hs[h];
    qa += hv * attn_W[(size_t)h * 512 + j];
    ua += hv * gc1_W[(size_t)h * 512 + j];
  }
  q[b * 512 + j] = qa;
  u[b * 512 + j] = ua;
}

__global__ __launch_bounds__(256)
void k_score(const float* __restrict__ q, const float* __restrict__ enc,
             float* __restrict__ scores, ushort_t* __restrict__ encb, int emit)
{
  const int b = blockIdx.x, p = blockIdx.y;
  const int t = threadIdx.x, wv = t >> 6, ln = t & 63;
  __shared__ float qs[512];
  for (int i = t; i < 512; i += 256) qs[i] = q[b * 512 + i];
  __syncthreads();
  const int e0 = ln * 8;
  const float4 q0 = *(const float4*)&qs[e0];
  const float4 q1 = *(const float4*)&qs[e0 + 4];
  for (int it = 0; it < 8; ++it) {
    const int s = p * 32 + wv * 8 + it;
    const float* e = enc + ((size_t)s * 64 + b) * 512 + e0;
    const float4 v0 = *(const float4*)e;
    const float4 v1 = *(const float4*)(e + 4);
    float a = q0.x * v0.x + q0.y * v0.y + q0.z * v0.z + q0.w * v0.w
            + q1.x * v1.x + q1.y * v1.y + q1.z * v1.z + q1.w * v1.w;
    if (emit) {
      short8 o;
      o[0] = (short)f2bf(v0.x); o[1] = (short)f2bf(v0.y);
      o[2] = (short)f2bf(v0.z); o[3] = (short)f2bf(v0.w);
      o[4] = (short)f2bf(v1.x); o[5] = (short)f2bf(v1.y);
      o[6] = (short)f2bf(v1.z); o[7] = (short)f2bf(v1.w);
      *(short8*)&encb[(size_t)b * 262144 + (size_t)s * 512 + e0] = o;
    }
    a = wave_sum(a);
    if (ln == 0) scores[b * 512 + s] = a;
  }
}

__global__ __launch_bounds__(512)
void k_ctx2(const float* __restrict__ scores, const ushort_t* __restrict__ encb,
            const float* __restrict__ enc, float* __restrict__ aw_dout,
            float* __restrict__ aw_ws, float* __restrict__ ctxpart, int use_bf)
{
  const int b = blockIdx.x, p = blockIdx.y, t = threadIdx.x;
  const int w = t >> 6, lane = t & 63;
  __shared__ float sc[512];
  __shared__ float red[8];
  __shared__ float red2[8];
  const float v = scores[b * 512 + t];
  float m = wave_max(v);
  if (lane == 0) red[w] = m;
  __syncthreads();
  float mm = red[0];
#pragma unroll
  for (int i = 1; i < 8; ++i) mm = fmaxf(mm, red[i]);
  const float e = __expf(v - mm);
  float s = wave_sum(e);
  if (lane == 0) red2[w] = s;
  __syncthreads();
  float tot = 0.f;
#pragma unroll
  for (int i = 0; i < 8; ++i) tot += red2[i];
  const float awv = e / tot;
  sc[t] = awv;
  if (p == 0) {
    aw_dout[b * 512 + t] = awv;
    aw_ws[b * 512 + t]   = awv;
  }
  __syncthreads();
  float acc = 0.f;
  if (use_bf) {
#pragma unroll 4
    for (int si = 0; si < 32; ++si)
      acc += sc[p * 32 + si] * bf2f(encb[((size_t)b * 512 + p * 32 + si) * 512 + t]);
  } else {
#pragma unroll 4
    for (int si = 0; si < 32; ++si)
      acc += sc[p * 32 + si] * enc[((size_t)(p * 32 + si) * 64 + b) * 512 + t];
  }
  ctxpart[((size_t)b * 16 + p) * 512 + t] = acc;
}

__global__ __launch_bounds__(128)
void k_concat(const float* __restrict__ hnew, const float* __restrict__ ctxpart,
              const float* __restrict__ cWT, const float* __restrict__ bias,
              float* __restrict__ out_cc, float* __restrict__ cc_ws)
{
  const int b = blockIdx.x, o = blockIdx.y * 128 + threadIdx.x;
  __shared__ __align__(16) float cat[1024];
  for (int m = 0; m < 8; ++m) {
    const int i = threadIdx.x + 128 * m;
    if (i < 512) {
      cat[i] = hnew[b * 512 + i];
    } else {
      const int d = i - 512;
      float s = 0.f;
#pragma unroll
      for (int pp = 0; pp < 16; ++pp) s += ctxpart[((size_t)b * 16 + pp) * 512 + d];
      cat[i] = s;
    }
  }
  __syncthreads();
  float acc = bias[o];
  for (int k = 0; k < 1024; k += 4) {
    acc += cat[k]     * cWT[(size_t)k * 512 + o]
         + cat[k + 1] * cWT[(size_t)(k + 1) * 512 + o]
         + cat[k + 2] * cWT[(size_t)(k + 2) * 512 + o]
         + cat[k + 3] * cWT[(size_t)(k + 3) * 512 + o];
  }
  acc = fmaxf(acc, 0.f);
  out_cc[b * 512 + o] = acc;
  cc_ws[b * 512 + o]  = acc;
}

__global__ __launch_bounds__(256)
void k_adjc(const float* __restrict__ ww, const int* __restrict__ ex,
            ushort_t* __restrict__ adj, int c0)
{
  const size_t i = (size_t)blockIdx.x * 256 + threadIdx.x;
  const size_t base4 = (size_t)c0 * 512 * 512 / 4;
  const float4 w4 = ((const float4*)ww)[base4 + i];
  const int4   e4 = ((const int4*)ex)[base4 + i];
  ushort4 r;
  r.x = (e4.x == 1) ? f2bf(w4.x) : 0;
  r.y = (e4.y == 1) ? f2bf(w4.y) : 0;
  r.z = (e4.z == 1) ? f2bf(w4.z) : 0;
  r.w = (e4.w == 1) ? f2bf(w4.w) : 0;
  ((ushort4*)adj)[i] = r;
}

__global__ __launch_bounds__(256)
void k_encc(const float* __restrict__ enc, ushort_t* __restrict__ encb, int c0)
{
  const size_t i = (size_t)blockIdx.x * 256 + threadIdx.x;
  const size_t el = i * 4;
  const int k = el & 511;
  const int s = (el >> 9) & 511;
  const int z = el >> 18;
  const float4 v = *(const float4*)&enc[((size_t)s * 64 + c0 + z) * 512 + k];
  ushort4 r;
  r.x = f2bf(v.x); r.y = f2bf(v.y); r.z = f2bf(v.z); r.w = f2bf(v.w);
  ((ushort4*)encb)[i] = r;
}

// Barrier-free fused LN + residual + wo_n contraction.
__global__ __launch_bounds__(256)
void k_red2(const ushort_t* __restrict__ w2w, const float* __restrict__ aw,
            const float* __restrict__ hnew, const ushort_t* __restrict__ encb,
            const float* __restrict__ won, const float* __restrict__ ng,
            const float* __restrict__ nb, float* __restrict__ part, int c0)
{
  const int z = blockIdx.x, b = c0 + z, yb = blockIdx.y;
  const int t = threadIdx.x, wv = t >> 6, ln = t & 63;
  __shared__ float sw[32][5];               // won0..3, aw per s-local
  __shared__ float accs[2][4][1024];        // cross-wave combine (32 KB)
  if (t < 160) {
    const int sl = t / 5, c_ = t - sl * 5;
    const int sg = yb * 32 + sl;
    sw[sl][c_] = (c_ < 4) ? won[((size_t)b * 4 + c_) * 512 + sg] : aw[b * 512 + sg];
  }
  const int d0 = ln * 16;
  float gg[16], bb[16], hv[16];
#pragma unroll
  for (int k = 0; k < 16; k += 4) {
    *(float4*)&gg[k] = *(const float4*)&ng[d0 + k];
    *(float4*)&bb[k] = *(const float4*)&nb[d0 + k];
  }
  if (ln < 32) {
#pragma unroll
    for (int k = 0; k < 16; k += 4)
      *(float4*)&hv[k] = *(const float4*)&hnew[b * 512 + d0 + k];
  }
  float acc[4][16];
#pragma unroll
  for (int o = 0; o < 4; ++o)
#pragma unroll
    for (int k = 0; k < 16; ++k) acc[o][k] = 0.f;
  __syncthreads();
  for (int it = 0; it < 8; ++it) {
    const int sl = wv * 8 + it;
    const int s = yb * 32 + sl;
    const ushort_t* row = w2w + ((size_t)z * 512 + s) * 1024 + d0;
    float x[16];
    bf8_to_f(row, x);
    bf8_to_f(row + 8, x + 8);
    float ls = 0.f, lss = 0.f;
#pragma unroll
    for (int k = 0; k < 16; ++k) { ls += x[k]; lss += x[k] * x[k]; }
#pragma unroll
    for (int off = 32; off; off >>= 1) {
      ls  += __shfl_xor(ls,  off, 64);
      lss += __shfl_xor(lss, off, 64);
    }
    const float mean = ls * (1.f / 1024.f);
    const float var  = lss * (1.f / 1024.f) - mean * mean;
    const float inv  = rsqrtf(var + 1e-6f);
    float res[16];
    if (ln < 32) {
      const float a_ = sw[sl][4];
#pragma unroll
      for (int k = 0; k < 16; ++k) res[k] = a_ * hv[k];
    } else {
      const ushort_t* er = encb + ((size_t)z * 512 + s) * 512 + (d0 - 512);
      bf8_to_f(er, res);
      bf8_to_f(er + 8, res + 8);
    }
    const float w0 = sw[sl][0], w1 = sw[sl][1], w2 = sw[sl][2], w3 = sw[sl][3];
#pragma unroll
    for (int k = 0; k < 16; ++k) {
      const float val = (x[k] - mean) * inv * gg[k] + bb[k] + res[k];
      acc[0][k] += w0 * val; acc[1][k] += w1 * val;
      acc[2][k] += w2 * val; acc[3][k] += w3 * val;
    }
  }
  if (wv < 2) {
#pragma unroll
    for (int o = 0; o < 4; ++o)
#pragma unroll
      for (int k = 0; k < 16; k += 4)
        *(float4*)&accs[wv][o][d0 + k] = *(float4*)&acc[o][k];
  }
  __syncthreads();
  if (wv >= 2) {
#pragma unroll
    for (int o = 0; o < 4; ++o)
#pragma unroll
      for (int k = 0; k < 16; ++k)
        accs[wv - 2][o][d0 + k] += acc[o][k];
  }
  __syncthreads();
  for (int i = t; i < 4096; i += 256) {
    const int o = i >> 10, d = i & 1023;
    part[(((size_t)(b * 16 + yb) * 4 + o) << 10) + d] = accs[0][o][d] + accs[1][o][d];
  }
}

// sum 16 partials -> ctx_op bf16 (256 x 1024)
__global__ __launch_bounds__(256)
void k_psum(const float* __restrict__ part, ushort_t* __restrict__ ctxop)
{
  const int idx = blockIdx.x * 256 + threadIdx.x;   // 262144
  const int r = idx >> 10, d = idx & 1023;
  const int b = r >> 2, o = r & 3;
  float s = 0.f;
#pragma unroll
  for (int p = 0; p < 16; ++p)
    s += part[(((size_t)(b * 16 + p) * 4 + o) << 10) + d];
  ctxop[idx] = f2bf(s);
}

__global__ __launch_bounds__(512)
void k_ln1(const float* __restrict__ oppre, const float* __restrict__ wo_b,
           const float* __restrict__ n1g, const float* __restrict__ n1b,
           const float* __restrict__ ops, ushort_t* __restrict__ opall)
{
  const int r = blockIdx.x, t = threadIdx.x;
  const int o = r & 3;
  __shared__ float2 red[8];
  const float val = fmaxf(oppre[(size_t)r * 512 + t] + wo_b[t], 0.f);
  const float2 ss = blocksum2(val, val * val, red, t, 8);
  const float m = ss.x * (1.f / 512.f);
  const float v = ss.y * (1.f / 512.f) - m * m;
  const float s1 = (val - m) * rsqrtf(v + 1e-6f) * n1g[t] + n1b[t];
  opall[(size_t)r * 1024 + t] = f2bf(s1);
  opall[(size_t)r * 1024 + 512 + t] = f2bf(ops[o * 512 + t]);
}

__global__ __launch_bounds__(512)
void k_ln2dot(const float* __restrict__ ohpre, const float* __restrict__ ot_b,
              const float* __restrict__ n2g, const float* __restrict__ n2b,
              const float* __restrict__ ops, const float* __restrict__ cc,
              const float* __restrict__ ops_bias, float* __restrict__ oo)
{
  const int r = blockIdx.x, t = threadIdx.x;
  const int b = r >> 2, o = r & 3;
  __shared__ float2 red[8];
  const float oh = fmaxf(ohpre[(size_t)r * 512 + t] + ot_b[t], 0.f);
  const float2 ss = blocksum2(oh, oh * oh, red, t, 8);
  const float m = ss.x * (1.f / 512.f);
  const float v = ss.y * (1.f / 512.f) - m * m;
  const float opo = (oh - m) * rsqrtf(v + 1e-6f) * n2g[t] + n2b[t] + ops[o * 512 + t];
  const float p = cc[b * 512 + t] * opo;
  const float2 s3 = blocksum2(p, 0.f, red, t, 8);
  if (t == 0) oo[r] = s3.x + ops_bias[o];
}

__global__ __launch_bounds__(128)
void k_final(const float* __restrict__ oo, const float* __restrict__ cc,
             const float* __restrict__ nWT, const float* __restrict__ nop_b,
             float* __restrict__ outp)
{
  const int b = blockIdx.x, t = threadIdx.x;
  __shared__ __align__(16) float ccs[512];
  __shared__ float red[2];
  __shared__ float red2[2];
  for (int i = t; i < 512; i += 128) ccs[i] = cc[b * 512 + i];
  __syncthreads();
  float v;
  if (t < 4) {
    v = oo[b * 4 + t];
  } else {
    const int j = t - 4;
    float a = nop_b[j];
    for (int k = 0; k < 512; ++k) a += ccs[k] * nWT[k * 128 + j];
    v = a;
  }
  float m = wave_max(v);
  if ((t & 63) == 0) red[t >> 6] = m;
  __syncthreads();
  m = fmaxf(red[0], red[1]);
  const float e = __expf(v - m);
  float s = wave_sum(e);
  if ((t & 63) == 0) red2[t >> 6] = s;
  __syncthreads();
  s = red2[0] + red2[1];
  outp[b * 128 + t] = v - m - logf(s);
}

} // namespace

extern "C" void kernel_launch(void* const* d_in, const int* in_sizes, int n_in,
                              void* d_out, int out_size, void* d_ws, size_t ws_size,
                              hipStream_t stream)
{
  const int*   input_step  = (const int*)  d_in[0];
  const float* last_hidden = (const float*)d_in[1];
  const float* enc         = (const float*)d_in[2];
  const float* word_word   = (const float*)d_in[3];
  const float* word_op     = (const float*)d_in[4];
  const int*   word_exist  = (const int*)  d_in[5];
  const int*   seq_mask    = (const int*)  d_in[6];
  const float* emb         = (const float*)d_in[7];
  const float* W_ih        = (const float*)d_in[8];
  const float* W_hh        = (const float*)d_in[9];
  const float* b_ih        = (const float*)d_in[10];
  const float* b_hh        = (const float*)d_in[11];
  const float* attn_W      = (const float*)d_in[12];
  const float* concat_W    = (const float*)d_in[14];
  const float* concat_b    = (const float*)d_in[15];
  const float* ops         = (const float*)d_in[16];
  const float* ops_bias    = (const float*)d_in[17];
  const float* nop_W       = (const float*)d_in[18];
  const float* nop_b       = (const float*)d_in[19];
  const float* gc1_W       = (const float*)d_in[20];
  const float* gc1_b       = (const float*)d_in[21];
  const float* gc2_W       = (const float*)d_in[22];
  const float* gc2_b       = (const float*)d_in[23];
  const float* norm_g      = (const float*)d_in[24];
  const float* norm_b      = (const float*)d_in[25];
  const float* norm1_g     = (const float*)d_in[26];
  const float* norm1_b     = (const float*)d_in[27];
  const float* norm2_g     = (const float*)d_in[28];
  const float* norm2_b     = (const float*)d_in[29];
  const float* wo_W        = (const float*)d_in[30];
  const float* wo_b        = (const float*)d_in[31];
  const float* ot_W        = (const float*)d_in[32];
  const float* ot_b        = (const float*)d_in[33];

  float* ws  = (float*)d_ws;
  float* out = (float*)d_out;

  // ---- workspace layout (floats) ----
  size_t off = 0;
  auto take = [&](size_t n) { size_t o = off; off += n; return o; };
  const size_t o_hnew = take(32768);
  const size_t o_q    = take(32768);
  const size_t o_u    = take(32768);
  const size_t o_aw   = take(32768);
  const size_t o_scores = take(32768);
  const size_t o_ctxpart = take(524288);   // 64*16*512
  const size_t o_cc   = take(32768);
  const size_t o_won  = take(131072);
  const size_t o_oo   = take(256);
  const size_t o_gi2  = take(393216);      // 2 x 1536 x 128 f32
  const size_t o_part = take(4194304);     // 64*16*4*1024
  const size_t o_oppre = take(131072);
  const size_t o_ohpre = take(131072);
  const size_t o_gc1LT = take(131072);
  const size_t o_gc2WT = take(262144);
  const size_t o_woW   = take(262144);
  const size_t o_otW   = take(262144);
  const size_t o_cWT   = take(524288);
  const size_t o_nWT   = take(65536);
  const size_t o_wihb  = take(786432);     // 2 x 1536 x 512 bf16
  const size_t o_xhb   = take(65536);      // 2 x 128 x 512 bf16
  const size_t o_ctxop = take(131072);
  const size_t o_opall = take(131072);
  const size_t base = off;

  // pick chunk size by available workspace (constant across calls -> graph-safe)
  int CB = 16;
  if (ws_size >= (base + 64ull * 524288) * 4) CB = 64;
  else if (ws_size >= (base + 32ull * 524288) * 4) CB = 32;
  const int nch = 64 / CB;

  const size_t o_adjbf = take((size_t)CB * 131072);
  const size_t o_h1t   = take((size_t)CB * 131072);
  const size_t o_encbf = take((size_t)CB * 131072);
  const size_t o_xw1t  = take((size_t)CB * 131072);
  const size_t o_tmat  = o_xw1t;           // overlays xw1t (dead after mgemm<1>)
  const size_t o_w2w   = o_adjbf;          // overlays adjbf+h1t (dead after mgemm<2>)

  float* hnew = ws + o_hnew;
  float* q    = ws + o_q;
  float* u    = ws + o_u;
  float* aw   = ws + o_aw;
  float* scores = ws + o_scores;
  float* ctxpart = ws + o_ctxpart;
  float* cc   = ws + o_cc;
  float* won  = ws + o_won;
  float* oo   = ws + o_oo;
  float* gi2  = ws + o_gi2;
  float* part = ws + o_part;
  float* oppre = ws + o_oppre;
  float* ohpre = ws + o_ohpre;
  float* cWT  = ws + o_cWT;
  float* nWT  = ws + o_nWT;
  ushort_t* gc1LT = (ushort_t*)(ws + o_gc1LT);
  ushort_t* gc2WT = (ushort_t*)(ws + o_gc2WT);
  ushort_t* woWb  = (ushort_t*)(ws + o_woW);
  ushort_t* otWb  = (ushort_t*)(ws + o_otW);
  ushort_t* wihb  = (ushort_t*)(ws + o_wihb);
  ushort_t* xhb   = (ushort_t*)(ws + o_xhb);
  ushort_t* ctxop = (ushort_t*)(ws + o_ctxop);
  ushort_t* opall = (ushort_t*)(ws + o_opall);
  ushort_t* adjbf = (ushort_t*)(ws + o_adjbf);
  ushort_t* h1t   = (ushort_t*)(ws + o_h1t);
  ushort_t* encbf = (ushort_t*)(ws + o_encbf);
  ushort_t* xw1t  = (ushort_t*)(ws + o_xw1t);
  ushort_t* tmat  = (ushort_t*)(ws + o_tmat);
  ushort_t* w2wbf = (ushort_t*)(ws + o_w2w);

  float* out_logits = out;
  float* out_hnew   = out + 8192;
  float* out_aw     = out + 8192 + 32768;
  float* out_cc     = out + 8192 + 65536;

  const int full = (CB == 64) ? 1 : 0;

  // ---- front: transposed weights (LDS tiled) + bulk streams ----
  k_tw<<<dim3(512, 4), 256, 0, stream>>>(gc1_W, gc2_W, concat_W, nop_W,
      gc1LT, gc2WT, cWT, nWT);
  k_front2<<<2048, 256, 0, stream>>>(input_step, emb, last_hidden,
      wo_W, ot_W, W_ih, W_hh, word_word, word_exist, word_op, seq_mask,
      woWb, otWb, wihb, xhb, adjbf, won, full);

  // ---- GRU via MFMA: gi/gh = [W_ih;W_hh] @ [x;h]^T, N padded to 128 ----
  mgemm<4><<<dim3(1, 12, 2), 256, 0, stream>>>(wihb, 512, 786432, xhb, 512, 65536,
      gi2, 128, 196608, 512, nullptr, nullptr, nullptr, 0);
  k_gru<<<128, 256, 0, stream>>>(gi2, last_hidden, b_ih, b_hh, hnew, out_hnew);

  // ---- attention + concat ----
  k_qu<<<dim3(64, 4), 128, 0, stream>>>(hnew, attn_W, gc1_W, q, u);
  k_score<<<dim3(64, 16), 256, 0, stream>>>(q, enc, scores, encbf, full);
  k_ctx2<<<dim3(64, 16), 512, 0, stream>>>(scores, encbf, enc, out_aw, aw, ctxpart, full);
  k_concat<<<dim3(64, 4), 128, 0, stream>>>(hnew, ctxpart, cWT, concat_b, out_cc, cc);

  // ---- GCN chain (bf16 MFMA, 256x256 tiles), chunked ----
  for (int c = 0; c < nch; ++c) {
    const int c0 = c * CB;
    if (!full) {
      k_adjc<<<CB * 256, 256, 0, stream>>>(word_word, word_exist, adjbf, c0);
      k_encc<<<CB * 256, 256, 0, stream>>>(enc, encbf, c0);
    }
    // XW1T[d][s] = gc1LT[d][:] . enc_b[s][:] + u[b][d]*aw[b][s]
    mgemm2<0><<<dim3(2, 2, CB), 512, 0, stream>>>(gc1LT, 512, 0, encbf, 512, 262144,
        xw1t, 512, 262144, 512, nullptr, aw, u, c0);
    // h1T[d][s] = relu(XW1T[d][:] . adj[s][:] + gc1_b[d])
    mgemm2<1><<<dim3(2, 2, CB), 512, 0, stream>>>(xw1t, 512, 262144, adjbf, 512, 262144,
        h1t, 512, 262144, 512, gc1_b, nullptr, nullptr, 0);
    // t[s][d] = adj[s][:] . h1T[d][:]   (overlays xw1t, dead)
    mgemm2<2><<<dim3(2, 2, CB), 512, 0, stream>>>(adjbf, 512, 262144, h1t, 512, 262144,
        tmat, 512, 262144, 512, nullptr, nullptr, nullptr, 0);
    // w2w[s][e] = t[s][:] . gc2WT[e][:] + gc2_b[e]   (overlays adjbf+h1t, dead)
    mgemm2<3><<<dim3(4, 2, CB), 512, 0, stream>>>(tmat, 512, 262144, gc2WT, 512, 0,
        w2wbf, 1024, 524288, 512, gc2_b, nullptr, nullptr, 0);
    k_red2<<<dim3(CB, 16), 256, 0, stream>>>(w2wbf, aw, hnew, encbf, won, norm_g, norm_b, part, c0);
  }

  // ---- op head (MFMA GEMMs) + nop head + log_softmax ----
  k_psum<<<1024, 256, 0, stream>>>(part, ctxop);
  mgemm<4><<<dim3(4, 2, 1), 256, 0, stream>>>(ctxop, 1024, 0, woWb, 1024, 0,
      oppre, 512, 0, 1024, nullptr, nullptr, nullptr, 0);
  k_ln1<<<256, 512, 0, stream>>>(oppre, wo_b, norm1_g, norm1_b, ops, opall);
  mgemm<4><<<dim3(4, 2, 1), 256, 0, stream>>>(opall, 1024, 0, otWb, 1024, 0,
      ohpre, 512, 0, 1024, nullptr, nullptr, nullptr, 0);
  k_ln2dot<<<256, 512, 0, stream>>>(ohpre, ot_b, norm2_g, norm2_b, ops, cc, ops_bias, oo);
  k_final<<<64, 128, 0, stream>>>(oo, cc, nWT, nop_b, out_logits);

  (void)in_sizes; (void)n_in; (void)out_size;
}

// Round 12
// 588.293 us; speedup vs baseline: 1.2659x; 1.0162x over previous
//
#include <hip/hip_runtime.h>
#include <math.h>

namespace {

typedef unsigned short ushort_t;
typedef __attribute__((ext_vector_type(8))) short short8;
typedef __attribute__((ext_vector_type(4))) float float4v;
typedef __attribute__((ext_vector_type(4))) float f32x4v;
typedef __attribute__((ext_vector_type(4))) int i32x4v;

__device__ __forceinline__ unsigned short f2bf(float x) {
  unsigned u = __float_as_uint(x);
  u += 0x7fffu + ((u >> 16) & 1u);        // RNE
  return (unsigned short)(u >> 16);
}
__device__ __forceinline__ float bf2f(unsigned short u) {
  return __uint_as_float((unsigned)u << 16);
}
__device__ __forceinline__ void bf8_to_f(const ushort_t* p, float* o) {
  const short8 v = *(const short8*)p;
#pragma unroll
  for (int k = 0; k < 8; ++k) o[k] = bf2f((unsigned short)v[k]);
}
__device__ __forceinline__ void bf8_to_f_nt(const ushort_t* p, float* o) {
  const short8 v = __builtin_nontemporal_load((const short8*)p);
#pragma unroll
  for (int k = 0; k < 8; ++k) o[k] = bf2f((unsigned short)v[k]);
}
__device__ __forceinline__ ushort4 f4bf(float4 v) {
  ushort4 r;
  r.x = f2bf(v.x); r.y = f2bf(v.y); r.z = f2bf(v.z); r.w = f2bf(v.w);
  return r;
}

__device__ __forceinline__ float wave_sum(float v) {
#pragma unroll
  for (int off = 32; off; off >>= 1) v += __shfl_down(v, off, 64);
  return v;
}
__device__ __forceinline__ float wave_max(float v) {
#pragma unroll
  for (int off = 32; off; off >>= 1) v = fmaxf(v, __shfl_down(v, off, 64));
  return v;
}
__device__ __forceinline__ float2 blocksum2(float a, float b, float2* red, int t, int nw) {
#pragma unroll
  for (int off = 32; off; off >>= 1) {
    a += __shfl_down(a, off, 64);
    b += __shfl_down(b, off, 64);
  }
  __syncthreads();
  if ((t & 63) == 0) red[t >> 6] = make_float2(a, b);
  __syncthreads();
  float sa = 0.f, sb = 0.f;
  for (int i = 0; i < nw; ++i) { sa += red[i].x; sb += red[i].y; }
  return make_float2(sa, sb);
}

// =================== bf16 MFMA NT-GEMM, 128x128 tile (r4-verified) ===========
// Used for GRU and op-head GEMMs.  3-buffer ring, depth-2 prefetch,
// one barrier per K-step.  XCD swizzle when nz%8==0.  LDS seg-XOR (0 conflicts).
template<int MODE>
__global__ __launch_bounds__(256)
void mgemm(const ushort_t* __restrict__ A, int lda, long sA,
           const ushort_t* __restrict__ Bt, int ldb, long sB,
           void* __restrict__ C, int ldc, long sC, int K,
           const float* __restrict__ bias,
           const float* __restrict__ aw, const float* __restrict__ u, int c0)
{
  __shared__ __attribute__((aligned(16))) ushort_t As[3][128 * 32];
  __shared__ __attribute__((aligned(16))) ushort_t Bs[3][128 * 32];

  int bx = blockIdx.x, by = blockIdx.y, bz = blockIdx.z;
  const int nx = gridDim.x, ny = gridDim.y, nz = gridDim.z;
  if ((nz & 7) == 0) {
    const int nxy = nx * ny;
    const int L = bx + nx * (by + ny * bz);
    const int xcd = L & 7;
    const int idx = L >> 3;
    const int lz = idx / nxy;
    const int xy = idx - lz * nxy;
    bz = xcd + 8 * lz;
    bx = xy % nx;
    by = xy / nx;
  }

  const int z = bz;
  const ushort_t* Ab = A  + (long)z * sA;
  const ushort_t* Bb = Bt + (long)z * sB;
  const int tm = by * 128, tn = bx * 128;
  const int t = threadIdx.x, wv = t >> 6, ln = t & 63;
  const int lrow = ln >> 2, lseg = ln & 3;        // staging: 16 rows x 4 segs of 16B
  const int gseg = lseg ^ ((lrow >> 1) & 3);      // bank-conflict-free seg XOR
  const int frow = ln & 15, q = ln >> 4;          // fragment: m=ln&15, k-quad
  const int sw8 = (frow >> 1) & 3;
  const int aoff = (q ^ sw8) << 3;
  const int wm = (wv >> 1) * 64, wn = (wv & 1) * 64;

  float4v acc[4][4];
#pragma unroll
  for (int i = 0; i < 4; ++i)
#pragma unroll
    for (int j = 0; j < 4; ++j) acc[i][j] = (float4v)0.f;

  auto STAGE = [&](int s, int ks) {
    const int kc = ks * 32 + gseg * 8;
#pragma unroll
    for (int half = 0; half < 2; ++half) {
      const int rbase = wv * 32 + half * 16;
      const ushort_t* ga = Ab + (long)(tm + rbase + lrow) * lda + kc;
      const ushort_t* gb = Bb + (long)(tn + rbase + lrow) * ldb + kc;
      __builtin_amdgcn_global_load_lds(
          (const __attribute__((address_space(1))) void*)ga,
          (__attribute__((address_space(3))) void*)&As[s][rbase * 32], 16, 0, 0);
      __builtin_amdgcn_global_load_lds(
          (const __attribute__((address_space(1))) void*)gb,
          (__attribute__((address_space(3))) void*)&Bs[s][rbase * 32], 16, 0, 0);
    }
  };
  auto COMPUTE = [&](const ushort_t* Asb, const ushort_t* Bsb) {
    short8 af[4], bfr[4];
#pragma unroll
    for (int i = 0; i < 4; ++i) af[i]  = *(const short8*)&Asb[(wm + i * 16 + frow) * 32 + aoff];
#pragma unroll
    for (int j = 0; j < 4; ++j) bfr[j] = *(const short8*)&Bsb[(wn + j * 16 + frow) * 32 + aoff];
    __builtin_amdgcn_s_setprio(1);
#pragma unroll
    for (int i = 0; i < 4; ++i)
#pragma unroll
      for (int j = 0; j < 4; ++j)
        acc[i][j] = __builtin_amdgcn_mfma_f32_16x16x32_bf16(af[i], bfr[j], acc[i][j], 0, 0, 0);
    __builtin_amdgcn_s_setprio(0);
  };

  const int NS = K >> 5;   // 32-wide K-steps
  STAGE(0, 0);
  if (NS > 1) STAGE(1, 1);
  int cur = 0;
  for (int ks = 0; ks < NS; ++ks) {
    if (ks + 1 < NS) asm volatile("s_waitcnt vmcnt(4)" ::: "memory");
    else             asm volatile("s_waitcnt vmcnt(0)" ::: "memory");
    __builtin_amdgcn_s_barrier();
    if (ks + 2 < NS) {
      int nxt = cur + 2; if (nxt >= 3) nxt -= 3;
      STAGE(nxt, ks + 2);
    }
    COMPUTE(As[cur], Bs[cur]);
    ++cur; if (cur >= 3) cur -= 3;
  }

  // epilogue: C/D layout col=lane&15, row=(lane>>4)*4+reg
#pragma unroll
  for (int i = 0; i < 4; ++i) {
#pragma unroll
    for (int j = 0; j < 4; ++j) {
      const int col = tn + wn + j * 16 + (ln & 15);
#pragma unroll
      for (int reg = 0; reg < 4; ++reg) {
        const int row = tm + wm + i * 16 + (ln >> 4) * 4 + reg;
        float v = acc[i][j][reg];
        if (MODE == 0) v += u[(c0 + z) * 512 + row] * aw[(c0 + z) * 512 + col];
        else if (MODE == 1) v = fmaxf(v + bias[row], 0.f);
        else if (MODE == 3) v += bias[col];
        if (MODE == 4) ((float*)C)[(long)z * sC + (long)row * ldc + col] = v;
        else ((ushort_t*)C)[(long)z * sC + (long)row * ldc + col] = f2bf(v);
      }
    }
  }
}

// =================== bf16 MFMA NT-GEMM, 256xBN tile (GCN chain) ==============
// BN=256: per-wave 128x64, acc[8][4], LDS 64KB -> 2 blocks/CU.
// BN=128: per-wave 128x32, acc[8][2], LDS 48KB -> 3 blocks/CU (fixes the
//   1-block/CU residency hole modes 0-2 had with 2x2 grids at BN=256).
// 512 threads = 8 waves (2Mx4N).  BK=32, 2-slot ping-pong; per K-step:
//   STAGE(nxt) -> vmcnt(loads-in-flight) -> barrier -> MFMA -> barrier.
template<int MODE, int BN = 256>
__global__ __launch_bounds__(512)
void mgemm2(const ushort_t* __restrict__ A, int lda, long sA,
            const ushort_t* __restrict__ Bt, int ldb, long sB,
            void* __restrict__ C, int ldc, long sC, int K,
            const float* __restrict__ bias,
            const float* __restrict__ aw, const float* __restrict__ u, int c0)
{
  constexpr int NJ = BN / 64;          // j-tiles per wave (4 or 2)
  constexpr int BPASS = BN / 128;      // B staging passes per wave (2 or 1)
  __shared__ __attribute__((aligned(16))) ushort_t As[2][256 * 32];
  __shared__ __attribute__((aligned(16))) ushort_t Bs[2][BN * 32];

  int bx = blockIdx.x, by = blockIdx.y, bz = blockIdx.z;
  const int nx = gridDim.x, ny = gridDim.y, nz = gridDim.z;
  if ((nz & 7) == 0) {
    const int nxy = nx * ny;
    const int L = bx + nx * (by + ny * bz);
    const int xcd = L & 7;
    const int idx = L >> 3;
    const int lz = idx / nxy;
    const int xy = idx - lz * nxy;
    bz = xcd + 8 * lz;
    bx = xy % nx;
    by = xy / nx;
  }

  const int z = bz;
  const ushort_t* Ab = A  + (long)z * sA;
  const ushort_t* Bb = Bt + (long)z * sB;
  const int tm = by * 256, tn = bx * BN;
  const int t = threadIdx.x, wv = t >> 6, ln = t & 63;   // wv 0..7
  const int lrow = ln >> 2, lseg = ln & 3;
  const int gseg = lseg ^ ((lrow >> 1) & 3);
  const int frow = ln & 15, q = ln >> 4;
  const int sw8 = (frow >> 1) & 3;
  const int aoff = (q ^ sw8) << 3;
  const int wm = (wv >> 2) * 128, wn = (wv & 3) * (BN / 4);  // 2x4 wave grid

  float4v acc[8][NJ];
#pragma unroll
  for (int i = 0; i < 8; ++i)
#pragma unroll
    for (int j = 0; j < NJ; ++j) acc[i][j] = (float4v)0.f;

  // stage one 256x32 A-slice and BNx32 B-slice into slot s
  auto STAGE = [&](int s, int ks) {
    const int kc = ks * 32 + gseg * 8;
#pragma unroll
    for (int half = 0; half < 2; ++half) {
      const int rbase = wv * 32 + half * 16;             // A: 0..240 step 16
      const ushort_t* ga = Ab + (long)(tm + rbase + lrow) * lda + kc;
      __builtin_amdgcn_global_load_lds(
          (const __attribute__((address_space(1))) void*)ga,
          (__attribute__((address_space(3))) void*)&As[s][rbase * 32], 16, 0, 0);
    }
#pragma unroll
    for (int half = 0; half < BPASS; ++half) {
      const int rbase = wv * (16 * BPASS) + half * 16;   // B: covers BN rows
      const ushort_t* gb = Bb + (long)(tn + rbase + lrow) * ldb + kc;
      __builtin_amdgcn_global_load_lds(
          (const __attribute__((address_space(1))) void*)gb,
          (__attribute__((address_space(3))) void*)&Bs[s][rbase * 32], 16, 0, 0);
    }
  };
  auto COMPUTE = [&](const ushort_t* Asb, const ushort_t* Bsb) {
    short8 af[8], bfr[NJ];
#pragma unroll
    for (int i = 0; i < 8; ++i)  af[i]  = *(const short8*)&Asb[(wm + i * 16 + frow) * 32 + aoff];
#pragma unroll
    for (int j = 0; j < NJ; ++j) bfr[j] = *(const short8*)&Bsb[(wn + j * 16 + frow) * 32 + aoff];
    __builtin_amdgcn_s_setprio(1);
#pragma unroll
    for (int i = 0; i < 8; ++i)
#pragma unroll
      for (int j = 0; j < NJ; ++j)
        acc[i][j] = __builtin_amdgcn_mfma_f32_16x16x32_bf16(af[i], bfr[j], acc[i][j], 0, 0, 0);
    __builtin_amdgcn_s_setprio(0);
  };

  const int NS = K >> 5;   // 32-wide K-steps (16 for K=512)
  STAGE(0, 0);
  for (int ks = 0; ks < NS; ++ks) {
    const int cur = ks & 1;
    if (ks + 1 < NS) {
      STAGE(cur ^ 1, ks + 1);
      if constexpr (BN == 256) asm volatile("s_waitcnt vmcnt(4)" ::: "memory");
      else                     asm volatile("s_waitcnt vmcnt(3)" ::: "memory");
    } else {
      asm volatile("s_waitcnt vmcnt(0)" ::: "memory");
    }
    __builtin_amdgcn_s_barrier();
    COMPUTE(As[cur], Bs[cur]);
    __builtin_amdgcn_s_barrier();
  }

  // epilogue: C/D layout col=lane&15, row=(lane>>4)*4+reg
#pragma unroll
  for (int i = 0; i < 8; ++i) {
#pragma unroll
    for (int j = 0; j < NJ; ++j) {
      const int col = tn + wn + j * 16 + (ln & 15);
#pragma unroll
      for (int reg = 0; reg < 4; ++reg) {
        const int row = tm + wm + i * 16 + (ln >> 4) * 4 + reg;
        float v = acc[i][j][reg];
        if (MODE == 0) v += u[(c0 + z) * 512 + row] * aw[(c0 + z) * 512 + col];
        else if (MODE == 1) v = fmaxf(v + bias[row], 0.f);
        else if (MODE == 3) v += bias[col];
        ((ushort_t*)C)[(long)z * sC + (long)row * ldc + col] = f2bf(v);
      }
    }
  }
}

// =================== transposed-weight conversions (LDS tiled) ===================
__global__ __launch_bounds__(256)
void k_tw(const float* __restrict__ gc1_W, const float* __restrict__ gc2_W,
          const float* __restrict__ concat_W, const float* __restrict__ nop_W,
          ushort_t* __restrict__ gc1LT, ushort_t* __restrict__ gc2WT,
          float* __restrict__ cWT, float* __restrict__ nWT)
{
  __shared__ float tile[32][33];
  const int job = blockIdx.y;
  const float* src; int sr, sc;
  if (job == 0)      { src = gc1_W + 262144; sr = 512; sc = 512;  }
  else if (job == 1) { src = gc2_W;          sr = 512; sc = 1024; }
  else if (job == 2) { src = concat_W;       sr = 512; sc = 1024; }
  else               { src = nop_W;          sr = 124; sc = 512;  }
  const int tpr = sc >> 5;
  const int ntile = ((sr + 31) >> 5) * tpr;
  if ((int)blockIdx.x >= ntile) return;
  const int tr = (blockIdx.x / tpr) * 32, tc = (blockIdx.x % tpr) * 32;
  const int t = threadIdx.x, tx = t & 31, ty = t >> 5;   // 8 rows per pass
#pragma unroll
  for (int p = 0; p < 4; ++p) {
    const int r = tr + ty + p * 8;
    tile[ty + p * 8][tx] = (r < sr) ? src[(size_t)r * sc + tc + tx] : 0.f;
  }
  __syncthreads();
#pragma unroll
  for (int p = 0; p < 4; ++p) {
    const int dr = tc + ty + p * 8;   // dst row = src col
    const int dc = tr + tx;           // dst col = src row
    const float v = tile[tx][ty + p * 8];
    if (job == 0)      gc1LT[(size_t)dr * 512 + dc] = f2bf(v);
    else if (job == 1) gc2WT[(size_t)dr * 512 + dc] = f2bf(v);
    else if (job == 2) cWT[(size_t)dr * 512 + dc] = v;
    else               nWT[(size_t)dr * 128 + dc] = v;   // dc < 128 always (sr pad)
  }
}

// =================== bulk front kernel — nt-loads on adjacency stream ========
__global__ __launch_bounds__(256)
void k_front2(const int* __restrict__ step, const float* __restrict__ emb,
              const float* __restrict__ last_hidden,
              const float* __restrict__ wo_W, const float* __restrict__ ot_W,
              const float* __restrict__ W_ih, const float* __restrict__ W_hh,
              const float* __restrict__ ww, const int* __restrict__ ex,
              const float* __restrict__ word_op, const int* __restrict__ seq_mask,
              ushort_t* __restrict__ woWb, ushort_t* __restrict__ otWb,
              ushort_t* __restrict__ wihb, ushort_t* __restrict__ xhb,
              ushort_t* __restrict__ adj, float* __restrict__ won, int do_adj)
{
  const int blk = blockIdx.x;
  const int t = threadIdx.x;
  const size_t u0 = (size_t)blk * 256 + t;           // < 524288

  // ---- adjacency: 8 fixed units/thread, fully unrolled, NT loads ----
  if (do_adj) {
    f32x4v w[8]; i32x4v e[8];
#pragma unroll
    for (int k = 0; k < 8; ++k) {
      w[k] = __builtin_nontemporal_load((const f32x4v*)ww + u0 + (size_t)k * 524288);
      e[k] = __builtin_nontemporal_load((const i32x4v*)ex + u0 + (size_t)k * 524288);
    }
#pragma unroll
    for (int k = 0; k < 8; ++k) {
      ushort4 r;
      r.x = (e[k][0] == 1) ? f2bf(w[k][0]) : 0;
      r.y = (e[k][1] == 1) ? f2bf(w[k][1]) : 0;
      r.z = (e[k][2] == 1) ? f2bf(w[k][2]) : 0;
      r.w = (e[k][3] == 1) ? f2bf(w[k][3]) : 0;
      ((ushort4*)adj)[u0 + (size_t)k * 524288] = r;
    }
  }

  // ---- copies: unit A (always) + unit B (u0 < 163840) ----
  if (u0 < 131072) {
    ((ushort4*)woWb)[u0] = f4bf(((const float4*)wo_W)[u0]);
    const size_t i2 = u0 + 262144;
    ((ushort4*)wihb)[i2] = f4bf(((const float4*)W_hh)[i2 - 196608]);
  } else if (u0 < 262144) {
    const size_t i = u0 - 131072;
    ((ushort4*)otWb)[i] = f4bf(((const float4*)ot_W)[i]);
    if (u0 < 163840) {
      const size_t e = i * 4;
      const int z = (int)(e >> 16), b = (int)((e >> 9) & 127), k = (int)(e & 511);
      float4 v = make_float4(0.f, 0.f, 0.f, 0.f);
      if (b < 64)
        v = z ? *(const float4*)&last_hidden[b * 512 + k]
              : *(const float4*)&emb[(size_t)step[b] * 512 + k];
      ((ushort4*)xhb)[i] = f4bf(v);
    }
  } else {
    const size_t i = u0 - 262144;    // < 262144: wihb first part
    const float4 v = (i < 196608) ? ((const float4*)W_ih)[i]
                                  : ((const float4*)W_hh)[i - 196608];
    ((ushort4*)wihb)[i] = f4bf(v);
  }

  // ---- wo_n normalization: blocks 0..63, one per batch ----
  if (blk < 64) {
    const int b = blk;
    __shared__ float red[4][4];               // [wave][o]
    float4 a0 = ((const float4*)word_op)[b * 512 + t];
    float4 a1 = ((const float4*)word_op)[b * 512 + t + 256];
    if (seq_mask[b * 512 + t])       a0 = make_float4(0.f, 0.f, 0.f, 0.f);
    if (seq_mask[b * 512 + t + 256]) a1 = make_float4(0.f, 0.f, 0.f, 0.f);
    float l0 = a0.x + a1.x, l1 = a0.y + a1.y, l2 = a0.z + a1.z, l3 = a0.w + a1.w;
#pragma unroll
    for (int off = 32; off; off >>= 1) {
      l0 += __shfl_down(l0, off, 64);
      l1 += __shfl_down(l1, off, 64);
      l2 += __shfl_down(l2, off, 64);
      l3 += __shfl_down(l3, off, 64);
    }
    if ((t & 63) == 0) {
      red[t >> 6][0] = l0; red[t >> 6][1] = l1;
      red[t >> 6][2] = l2; red[t >> 6][3] = l3;
    }
    __syncthreads();
    const float tot0 = red[0][0] + red[1][0] + red[2][0] + red[3][0] + 1e-30f;
    const float tot1 = red[0][1] + red[1][1] + red[2][1] + red[3][1] + 1e-30f;
    const float tot2 = red[0][2] + red[1][2] + red[2][2] + red[3][2] + 1e-30f;
    const float tot3 = red[0][3] + red[1][3] + red[2][3] + red[3][3] + 1e-30f;
    float* w0 = won + ((size_t)b * 4 + 0) * 512;
    float* w1 = won + ((size_t)b * 4 + 1) * 512;
    float* w2 = won + ((size_t)b * 4 + 2) * 512;
    float* w3 = won + ((size_t)b * 4 + 3) * 512;
    w0[t] = a0.x / tot0; w0[t + 256] = a1.x / tot0;
    w1[t] = a0.y / tot1; w1[t + 256] = a1.y / tot1;
    w2[t] = a0.z / tot2; w2[t + 256] = a1.z / tot2;
    w3[t] = a0.w / tot3; w3[t + 256] = a1.w / tot3;
  }
}

// =================== small fused kernels ===================

__global__ __launch_bounds__(256)
void k_gru(const float* __restrict__ gi2, const float* __restrict__ last_hidden,
           const float* __restrict__ b_ih, const float* __restrict__ b_hh,
           float* __restrict__ hnew, float* __restrict__ hnew_out)
{
  const int idx = blockIdx.x * 256 + threadIdx.x;
  const int b = idx >> 9, tt = idx & 511;
  const float* gh = gi2 + 196608;
  const float ir  = gi2[tt * 128 + b]          + b_ih[tt];
  const float iz  = gi2[(512 + tt) * 128 + b]  + b_ih[512 + tt];
  const float inn = gi2[(1024 + tt) * 128 + b] + b_ih[1024 + tt];
  const float hr  = gh[tt * 128 + b]          + b_hh[tt];
  const float hz  = gh[(512 + tt) * 128 + b]  + b_hh[512 + tt];
  const float hn  = gh[(1024 + tt) * 128 + b] + b_hh[1024 + tt];
  const float h   = last_hidden[idx];
  const float r = 1.f / (1.f + __expf(-(ir + hr)));
  const float z = 1.f / (1.f + __expf(-(iz + hz)));
  const float n = tanhf(inn + r * hn);
  const float o = (1.f - z) * n + z * h;
  hnew[idx] = o;
  hnew_out[idx] = o;
}

__global__ __launch_bounds__(128)
void k_qu(const float* __restrict__ hnew, const float* __restrict__ attn_W,
          const float* __restrict__ gc1_W, float* __restrict__ q, float* __restrict__ u)
{
  const int b = blockIdx.x, j = blockIdx.y * 128 + threadIdx.x;
  __shared__ float hs[512];
  for (int i = threadIdx.x; i < 512; i += 128) hs[i] = hnew[b * 512 + i];
  __syncthreads();
  float qa = 0.f, ua = 0.f;
  for (int h = 0; h < 512; ++h) {
    const float hv = hs[h];
    qa += hv * attn_W[(size_t)h * 512 + j];
    ua += hv * gc1_W[(size_t)h * 512 + j];
  }
  q[b * 512 + j] = qa;
  u[b * 512 + j] = ua;
}

__global__ __launch_bounds__(256)
void k_score(const float* __restrict__ q, const float* __restrict__ enc,
             float* __restrict__ scores, ushort_t* __restrict__ encb, int emit)
{
  const int b = blockIdx.x, p = blockIdx.y;
  const int t = threadIdx.x, wv = t >> 6, ln = t & 63;
  __shared__ float qs[512];
  for (int i = t; i < 512; i += 256) qs[i] = q[b * 512 + i];
  __syncthreads();
  const int e0 = ln * 8;
  const float4 q0 = *(const float4*)&qs[e0];
  const float4 q1 = *(const float4*)&qs[e0 + 4];
  for (int it = 0; it < 8; ++it) {
    const int s = p * 32 + wv * 8 + it;
    const float* e = enc + ((size_t)s * 64 + b) * 512 + e0;
    const float4 v0 = *(const float4*)e;
    const float4 v1 = *(const float4*)(e + 4);
    float a = q0.x * v0.x + q0.y * v0.y + q0.z * v0.z + q0.w * v0.w
            + q1.x * v1.x + q1.y * v1.y + q1.z * v1.z + q1.w * v1.w;
    if (emit) {
      short8 o;
      o[0] = (short)f2bf(v0.x); o[1] = (short)f2bf(v0.y);
      o[2] = (short)f2bf(v0.z); o[3] = (short)f2bf(v0.w);
      o[4] = (short)f2bf(v1.x); o[5] = (short)f2bf(v1.y);
      o[6] = (short)f2bf(v1.z); o[7] = (short)f2bf(v1.w);
      *(short8*)&encb[(size_t)b * 262144 + (size_t)s * 512 + e0] = o;
    }
    a = wave_sum(a);
    if (ln == 0) scores[b * 512 + s] = a;
  }
}

__global__ __launch_bounds__(512)
void k_ctx2(const float* __restrict__ scores, const ushort_t* __restrict__ encb,
            const float* __restrict__ enc, float* __restrict__ aw_dout,
            float* __restrict__ aw_ws, float* __restrict__ ctxpart, int use_bf)
{
  const int b = blockIdx.x, p = blockIdx.y, t = threadIdx.x;
  const int w = t >> 6, lane = t & 63;
  __shared__ float sc[512];
  __shared__ float red[8];
  __shared__ float red2[8];
  const float v = scores[b * 512 + t];
  float m = wave_max(v);
  if (lane == 0) red[w] = m;
  __syncthreads();
  float mm = red[0];
#pragma unroll
  for (int i = 1; i < 8; ++i) mm = fmaxf(mm, red[i]);
  const float e = __expf(v - mm);
  float s = wave_sum(e);
  if (lane == 0) red2[w] = s;
  __syncthreads();
  float tot = 0.f;
#pragma unroll
  for (int i = 0; i < 8; ++i) tot += red2[i];
  const float awv = e / tot;
  sc[t] = awv;
  if (p == 0) {
    aw_dout[b * 512 + t] = awv;
    aw_ws[b * 512 + t]   = awv;
  }
  __syncthreads();
  float acc = 0.f;
  if (use_bf) {
#pragma unroll 4
    for (int si = 0; si < 32; ++si)
      acc += sc[p * 32 + si] * bf2f(encb[((size_t)b * 512 + p * 32 + si) * 512 + t]);
  } else {
#pragma unroll 4
    for (int si = 0; si < 32; ++si)
      acc += sc[p * 32 + si] * enc[((size_t)(p * 32 + si) * 64 + b) * 512 + t];
  }
  ctxpart[((size_t)b * 16 + p) * 512 + t] = acc;
}

__global__ __launch_bounds__(128)
void k_concat(const float* __restrict__ hnew, const float* __restrict__ ctxpart,
              const float* __restrict__ cWT, const float* __restrict__ bias,
              float* __restrict__ out_cc, float* __restrict__ cc_ws)
{
  const int b = blockIdx.x, o = blockIdx.y * 128 + threadIdx.x;
  __shared__ __align__(16) float cat[1024];
  for (int m = 0; m < 8; ++m) {
    const int i = threadIdx.x + 128 * m;
    if (i < 512) {
      cat[i] = hnew[b * 512 + i];
    } else {
      const int d = i - 512;
      float s = 0.f;
#pragma unroll
      for (int pp = 0; pp < 16; ++pp) s += ctxpart[((size_t)b * 16 + pp) * 512 + d];
      cat[i] = s;
    }
  }
  __syncthreads();
  float acc = bias[o];
  for (int k = 0; k < 1024; k += 4) {
    acc += cat[k]     * cWT[(size_t)k * 512 + o]
         + cat[k + 1] * cWT[(size_t)(k + 1) * 512 + o]
         + cat[k + 2] * cWT[(size_t)(k + 2) * 512 + o]
         + cat[k + 3] * cWT[(size_t)(k + 3) * 512 + o];
  }
  acc = fmaxf(acc, 0.f);
  out_cc[b * 512 + o] = acc;
  cc_ws[b * 512 + o]  = acc;
}

__global__ __launch_bounds__(256)
void k_adjc(const float* __restrict__ ww, const int* __restrict__ ex,
            ushort_t* __restrict__ adj, int c0)
{
  const size_t i = (size_t)blockIdx.x * 256 + threadIdx.x;
  const size_t base4 = (size_t)c0 * 512 * 512 / 4;
  const float4 w4 = ((const float4*)ww)[base4 + i];
  const int4   e4 = ((const int4*)ex)[base4 + i];
  ushort4 r;
  r.x = (e4.x == 1) ? f2bf(w4.x) : 0;
  r.y = (e4.y == 1) ? f2bf(w4.y) : 0;
  r.z = (e4.z == 1) ? f2bf(w4.z) : 0;
  r.w = (e4.w == 1) ? f2bf(w4.w) : 0;
  ((ushort4*)adj)[i] = r;
}

__global__ __launch_bounds__(256)
void k_encc(const float* __restrict__ enc, ushort_t* __restrict__ encb, int c0)
{
  const size_t i = (size_t)blockIdx.x * 256 + threadIdx.x;
  const size_t el = i * 4;
  const int k = el & 511;
  const int s = (el >> 9) & 511;
  const int z = el >> 18;
  const float4 v = *(const float4*)&enc[((size_t)s * 64 + c0 + z) * 512 + k];
  ushort4 r;
  r.x = f2bf(v.x); r.y = f2bf(v.y); r.z = f2bf(v.z); r.w = f2bf(v.w);
  ((ushort4*)encb)[i] = r;
}

// Barrier-free fused LN + residual + wo_n contraction.  NT loads on the
// read-once w2w / encb streams (no-allocate; relieves L2 fill pressure).
__global__ __launch_bounds__(256)
void k_red2(const ushort_t* __restrict__ w2w, const float* __restrict__ aw,
            const float* __restrict__ hnew, const ushort_t* __restrict__ encb,
            const float* __restrict__ won, const float* __restrict__ ng,
            const float* __restrict__ nb, float* __restrict__ part, int c0)
{
  const int z = blockIdx.x, b = c0 + z, yb = blockIdx.y;
  const int t = threadIdx.x, wv = t >> 6, ln = t & 63;
  __shared__ float sw[32][5];               // won0..3, aw per s-local
  __shared__ float accs[2][4][1024];        // cross-wave combine (32 KB)
  if (t < 160) {
    const int sl = t / 5, c_ = t - sl * 5;
    const int sg = yb * 32 + sl;
    sw[sl][c_] = (c_ < 4) ? won[((size_t)b * 4 + c_) * 512 + sg] : aw[b * 512 + sg];
  }
  const int d0 = ln * 16;
  float gg[16], bb[16], hv[16];
#pragma unroll
  for (int k = 0; k < 16; k += 4) {
    *(float4*)&gg[k] = *(const float4*)&ng[d0 + k];
    *(float4*)&bb[k] = *(const float4*)&nb[d0 + k];
  }
  if (ln < 32) {
#pragma unroll
    for (int k = 0; k < 16; k += 4)
      *(float4*)&hv[k] = *(const float4*)&hnew[b * 512 + d0 + k];
  }
  float acc[4][16];
#pragma unroll
  for (int o = 0; o < 4; ++o)
#pragma unroll
    for (int k = 0; k < 16; ++k) acc[o][k] = 0.f;
  __syncthreads();
  for (int it = 0; it < 8; ++it) {
    const int sl = wv * 8 + it;
    const int s = yb * 32 + sl;
    const ushort_t* row = w2w + ((size_t)z * 512 + s) * 1024 + d0;
    float x[16];
    bf8_to_f_nt(row, x);
    bf8_to_f_nt(row + 8, x + 8);
    float ls = 0.f, lss = 0.f;
#pragma unroll
    for (int k = 0; k < 16; ++k) { ls += x[k]; lss += x[k] * x[k]; }
#pragma unroll
    for (int off = 32; off; off >>= 1) {
      ls  += __shfl_xor(ls,  off, 64);
      lss += __shfl_xor(lss, off, 64);
    }
    const float mean = ls * (1.f / 1024.f);
    const float var  = lss * (1.f / 1024.f) - mean * mean;
    const float inv  = rsqrtf(var + 1e-6f);
    float res[16];
    if (ln < 32) {
      const float a_ = sw[sl][4];
#pragma unroll
      for (int k = 0; k < 16; ++k) res[k] = a_ * hv[k];
    } else {
      const ushort_t* er = encb + ((size_t)z * 512 + s) * 512 + (d0 - 512);
      bf8_to_f_nt(er, res);
      bf8_to_f_nt(er + 8, res + 8);
    }
    const float w0 = sw[sl][0], w1 = sw[sl][1], w2 = sw[sl][2], w3 = sw[sl][3];
#pragma unroll
    for (int k = 0; k < 16; ++k) {
      const float val = (x[k] - mean) * inv * gg[k] + bb[k] + res[k];
      acc[0][k] += w0 * val; acc[1][k] += w1 * val;
      acc[2][k] += w2 * val; acc[3][k] += w3 * val;
    }
  }
  if (wv < 2) {
#pragma unroll
    for (int o = 0; o < 4; ++o)
#pragma unroll
      for (int k = 0; k < 16; k += 4)
        *(float4*)&accs[wv][o][d0 + k] = *(float4*)&acc[o][k];
  }
  __syncthreads();
  if (wv >= 2) {
#pragma unroll
    for (int o = 0; o < 4; ++o)
#pragma unroll
      for (int k = 0; k < 16; ++k)
        accs[wv - 2][o][d0 + k] += acc[o][k];
  }
  __syncthreads();
  for (int i = t; i < 4096; i += 256) {
    const int o = i >> 10, d = i & 1023;
    part[(((size_t)(b * 16 + yb) * 4 + o) << 10) + d] = accs[0][o][d] + accs[1][o][d];
  }
}

// sum 16 partials -> ctx_op bf16 (256 x 1024)
__global__ __launch_bounds__(256)
void k_psum(const float* __restrict__ part, ushort_t* __restrict__ ctxop)
{
  const int idx = blockIdx.x * 256 + threadIdx.x;   // 262144
  const int r = idx >> 10, d = idx & 1023;
  const int b = r >> 2, o = r & 3;
  float s = 0.f;
#pragma unroll
  for (int p = 0; p < 16; ++p)
    s += part[(((size_t)(b * 16 + p) * 4 + o) << 10) + d];
  ctxop[idx] = f2bf(s);
}

__global__ __launch_bounds__(512)
void k_ln1(const float* __restrict__ oppre, const float* __restrict__ wo_b,
           const float* __restrict__ n1g, const float* __restrict__ n1b,
           const float* __restrict__ ops, ushort_t* __restrict__ opall)
{
  const int r = blockIdx.x, t = threadIdx.x;
  const int o = r & 3;
  __shared__ float2 red[8];
  const float val = fmaxf(oppre[(size_t)r * 512 + t] + wo_b[t], 0.f);
  const float2 ss = blocksum2(val, val * val, red, t, 8);
  const float m = ss.x * (1.f / 512.f);
  const float v = ss.y * (1.f / 512.f) - m * m;
  const float s1 = (val - m) * rsqrtf(v + 1e-6f) * n1g[t] + n1b[t];
  opall[(size_t)r * 1024 + t] = f2bf(s1);
  opall[(size_t)r * 1024 + 512 + t] = f2bf(ops[o * 512 + t]);
}

__global__ __launch_bounds__(512)
void k_ln2dot(const float* __restrict__ ohpre, const float* __restrict__ ot_b,
              const float* __restrict__ n2g, const float* __restrict__ n2b,
              const float* __restrict__ ops, const float* __restrict__ cc,
              const float* __restrict__ ops_bias, float* __restrict__ oo)
{
  const int r = blockIdx.x, t = threadIdx.x;
  const int b = r >> 2, o = r & 3;
  __shared__ float2 red[8];
  const float oh = fmaxf(ohpre[(size_t)r * 512 + t] + ot_b[t], 0.f);
  const float2 ss = blocksum2(oh, oh * oh, red, t, 8);
  const float m = ss.x * (1.f / 512.f);
  const float v = ss.y * (1.f / 512.f) - m * m;
  const float opo = (oh - m) * rsqrtf(v + 1e-6f) * n2g[t] + n2b[t] + ops[o * 512 + t];
  const float p = cc[b * 512 + t] * opo;
  const float2 s3 = blocksum2(p, 0.f, red, t, 8);
  if (t == 0) oo[r] = s3.x + ops_bias[o];
}

__global__ __launch_bounds__(128)
void k_final(const float* __restrict__ oo, const float* __restrict__ cc,
             const float* __restrict__ nWT, const float* __restrict__ nop_b,
             float* __restrict__ outp)
{
  const int b = blockIdx.x, t = threadIdx.x;
  __shared__ __align__(16) float ccs[512];
  __shared__ float red[2];
  __shared__ float red2[2];
  for (int i = t; i < 512; i += 128) ccs[i] = cc[b * 512 + i];
  __syncthreads();
  float v;
  if (t < 4) {
    v = oo[b * 4 + t];
  } else {
    const int j = t - 4;
    float a = nop_b[j];
    for (int k = 0; k < 512; ++k) a += ccs[k] * nWT[k * 128 + j];
    v = a;
  }
  float m = wave_max(v);
  if ((t & 63) == 0) red[t >> 6] = m;
  __syncthreads();
  m = fmaxf(red[0], red[1]);
  const float e = __expf(v - m);
  float s = wave_sum(e);
  if ((t & 63) == 0) red2[t >> 6] = s;
  __syncthreads();
  s = red2[0] + red2[1];
  outp[b * 128 + t] = v - m - logf(s);
}

} // namespace

extern "C" void kernel_launch(void* const* d_in, const int* in_sizes, int n_in,
                              void* d_out, int out_size, void* d_ws, size_t ws_size,
                              hipStream_t stream)
{
  const int*   input_step  = (const int*)  d_in[0];
  const float* last_hidden = (const float*)d_in[1];
  const float* enc         = (const float*)d_in[2];
  const float* word_word   = (const float*)d_in[3];
  const float* word_op     = (const float*)d_in[4];
  const int*   word_exist  = (const int*)  d_in[5];
  const int*   seq_mask    = (const int*)  d_in[6];
  const float* emb         = (const float*)d_in[7];
  const float* W_ih        = (const float*)d_in[8];
  const float* W_hh        = (const float*)d_in[9];
  const float* b_ih        = (const float*)d_in[10];
  const float* b_hh        = (const float*)d_in[11];
  const float* attn_W      = (const float*)d_in[12];
  const float* concat_W    = (const float*)d_in[14];
  const float* concat_b    = (const float*)d_in[15];
  const float* ops         = (const float*)d_in[16];
  const float* ops_bias    = (const float*)d_in[17];
  const float* nop_W       = (const float*)d_in[18];
  const float* nop_b       = (const float*)d_in[19];
  const float* gc1_W       = (const float*)d_in[20];
  const float* gc1_b       = (const float*)d_in[21];
  const float* gc2_W       = (const float*)d_in[22];
  const float* gc2_b       = (const float*)d_in[23];
  const float* norm_g      = (const float*)d_in[24];
  const float* norm_b      = (const float*)d_in[25];
  const float* norm1_g     = (const float*)d_in[26];
  const float* norm1_b     = (const float*)d_in[27];
  const float* norm2_g     = (const float*)d_in[28];
  const float* norm2_b     = (const float*)d_in[29];
  const float* wo_W        = (const float*)d_in[30];
  const float* wo_b        = (const float*)d_in[31];
  const float* ot_W        = (const float*)d_in[32];
  const float* ot_b        = (const float*)d_in[33];

  float* ws  = (float*)d_ws;
  float* out = (float*)d_out;

  // ---- workspace layout (floats) ----
  size_t off = 0;
  auto take = [&](size_t n) { size_t o = off; off += n; return o; };
  const size_t o_hnew = take(32768);
  const size_t o_q    = take(32768);
  const size_t o_u    = take(32768);
  const size_t o_aw   = take(32768);
  const size_t o_scores = take(32768);
  const size_t o_ctxpart = take(524288);   // 64*16*512
  const size_t o_cc   = take(32768);
  const size_t o_won  = take(131072);
  const size_t o_oo   = take(256);
  const size_t o_gi2  = take(393216);      // 2 x 1536 x 128 f32
  const size_t o_part = take(4194304);     // 64*16*4*1024
  const size_t o_oppre = take(131072);
  const size_t o_ohpre = take(131072);
  const size_t o_gc1LT = take(131072);
  const size_t o_gc2WT = take(262144);
  const size_t o_woW   = take(262144);
  const size_t o_otW   = take(262144);
  const size_t o_cWT   = take(524288);
  const size_t o_nWT   = take(65536);
  const size_t o_wihb  = take(786432);     // 2 x 1536 x 512 bf16
  const size_t o_xhb   = take(65536);      // 2 x 128 x 512 bf16
  const size_t o_ctxop = take(131072);
  const size_t o_opall = take(131072);
  const size_t base = off;

  // pick chunk size by available workspace (constant across calls -> graph-safe)
  int CB = 16;
  if (ws_size >= (base + 64ull * 524288) * 4) CB = 64;
  else if (ws_size >= (base + 32ull * 524288) * 4) CB = 32;
  const int nch = 64 / CB;

  const size_t o_adjbf = take((size_t)CB * 131072);
  const size_t o_h1t   = take((size_t)CB * 131072);
  const size_t o_encbf = take((size_t)CB * 131072);
  const size_t o_xw1t  = take((size_t)CB * 131072);
  const size_t o_tmat  = o_xw1t;           // overlays xw1t (dead after mgemm2<1>)
  const size_t o_w2w   = o_adjbf;          // overlays adjbf+h1t (dead after mgemm2<2>)

  float* hnew = ws + o_hnew;
  float* q    = ws + o_q;
  float* u    = ws + o_u;
  float* aw   = ws + o_aw;
  float* scores = ws + o_scores;
  float* ctxpart = ws + o_ctxpart;
  float* cc   = ws + o_cc;
  float* won  = ws + o_won;
  float* oo   = ws + o_oo;
  float* gi2  = ws + o_gi2;
  float* part = ws + o_part;
  float* oppre = ws + o_oppre;
  float* ohpre = ws + o_ohpre;
  float* cWT  = ws + o_cWT;
  float* nWT  = ws + o_nWT;
  ushort_t* gc1LT = (ushort_t*)(ws + o_gc1LT);
  ushort_t* gc2WT = (ushort_t*)(ws + o_gc2WT);
  ushort_t* woWb  = (ushort_t*)(ws + o_woW);
  ushort_t* otWb  = (ushort_t*)(ws + o_otW);
  ushort_t* wihb  = (ushort_t*)(ws + o_wihb);
  ushort_t* xhb   = (ushort_t*)(ws + o_xhb);
  ushort_t* ctxop = (ushort_t*)(ws + o_ctxop);
  ushort_t* opall = (ushort_t*)(ws + o_opall);
  ushort_t* adjbf = (ushort_t*)(ws + o_adjbf);
  ushort_t* h1t   = (ushort_t*)(ws + o_h1t);
  ushort_t* encbf = (ushort_t*)(ws + o_encbf);
  ushort_t* xw1t  = (ushort_t*)(ws + o_xw1t);
  ushort_t* tmat  = (ushort_t*)(ws + o_tmat);
  ushort_t* w2wbf = (ushort_t*)(ws + o_w2w);

  float* out_logits = out;
  float* out_hnew   = out + 8192;
  float* out_aw     = out + 8192 + 32768;
  float* out_cc     = out + 8192 + 65536;

  const int full = (CB == 64) ? 1 : 0;

  // ---- front: transposed weights (LDS tiled) + bulk streams ----
  k_tw<<<dim3(512, 4), 256, 0, stream>>>(gc1_W, gc2_W, concat_W, nop_W,
      gc1LT, gc2WT, cWT, nWT);
  k_front2<<<2048, 256, 0, stream>>>(input_step, emb, last_hidden,
      wo_W, ot_W, W_ih, W_hh, word_word, word_exist, word_op, seq_mask,
      woWb, otWb, wihb, xhb, adjbf, won, full);

  // ---- GRU via MFMA: gi/gh = [W_ih;W_hh] @ [x;h]^T, N padded to 128 ----
  mgemm<4><<<dim3(1, 12, 2), 256, 0, stream>>>(wihb, 512, 786432, xhb, 512, 65536,
      gi2, 128, 196608, 512, nullptr, nullptr, nullptr, 0);
  k_gru<<<128, 256, 0, stream>>>(gi2, last_hidden, b_ih, b_hh, hnew, out_hnew);

  // ---- attention + concat ----
  k_qu<<<dim3(64, 4), 128, 0, stream>>>(hnew, attn_W, gc1_W, q, u);
  k_score<<<dim3(64, 16), 256, 0, stream>>>(q, enc, scores, encbf, full);
  k_ctx2<<<dim3(64, 16), 512, 0, stream>>>(scores, encbf, enc, out_aw, aw, ctxpart, full);
  k_concat<<<dim3(64, 4), 128, 0, stream>>>(hnew, ctxpart, cWT, concat_b, out_cc, cc);

  // ---- GCN chain (bf16 MFMA): 256x128 tiles (full residency) + 256x256 G3 ----
  for (int c = 0; c < nch; ++c) {
    const int c0 = c * CB;
    if (!full) {
      k_adjc<<<CB * 256, 256, 0, stream>>>(word_word, word_exist, adjbf, c0);
      k_encc<<<CB * 256, 256, 0, stream>>>(enc, encbf, c0);
    }
    // XW1T[d][s] = gc1LT[d][:] . enc_b[s][:] + u[b][d]*aw[b][s]
    mgemm2<0, 128><<<dim3(4, 2, CB), 512, 0, stream>>>(gc1LT, 512, 0, encbf, 512, 262144,
        xw1t, 512, 262144, 512, nullptr, aw, u, c0);
    // h1T[d][s] = relu(XW1T[d][:] . adj[s][:] + gc1_b[d])
    mgemm2<1, 128><<<dim3(4, 2, CB), 512, 0, stream>>>(xw1t, 512, 262144, adjbf, 512, 262144,
        h1t, 512, 262144, 512, gc1_b, nullptr, nullptr, 0);
    // t[s][d] = adj[s][:] . h1T[d][:]   (overlays xw1t, dead)
    mgemm2<2, 128><<<dim3(4, 2, CB), 512, 0, stream>>>(adjbf, 512, 262144, h1t, 512, 262144,
        tmat, 512, 262144, 512, nullptr, nullptr, nullptr, 0);
    // w2w[s][e] = t[s][:] . gc2WT[e][:] + gc2_b[e]   (overlays adjbf+h1t, dead)
    mgemm2<3, 256><<<dim3(4, 2, CB), 512, 0, stream>>>(tmat, 512, 262144, gc2WT, 512, 0,
        w2wbf, 1024, 524288, 512, gc2_b, nullptr, nullptr, 0);
    k_red2<<<dim3(CB, 16), 256, 0, stream>>>(w2wbf, aw, hnew, encbf, won, norm_g, norm_b, part, c0);
  }

  // ---- op head (MFMA GEMMs) + nop head + log_softmax ----
  k_psum<<<1024, 256, 0, stream>>>(part, ctxop);
  mgemm<4><<<dim3(4, 2, 1), 256, 0, stream>>>(ctxop, 1024, 0, woWb, 1024, 0,
      oppre, 512, 0, 1024, nullptr, nullptr, nullptr, 0);
  k_ln1<<<256, 512, 0, stream>>>(oppre, wo_b, norm1_g, norm1_b, ops, opall);
  mgemm<4><<<dim3(4, 2, 1), 256, 0, stream>>>(opall, 1024, 0, otWb, 1024, 0,
      ohpre, 512, 0, 1024, nullptr, nullptr, nullptr, 0);
  k_ln2dot<<<256, 512, 0, stream>>>(ohpre, ot_b, norm2_g, norm2_b, ops, cc, ops_bias, oo);
  k_final<<<64, 128, 0, stream>>>(oo, cc, nWT, nop_b, out_logits);

  (void)in_sizes; (void)n_in; (void)out_size;
}

// Round 13
// 582.269 us; speedup vs baseline: 1.2790x; 1.0103x over previous
//
#include <hip/hip_runtime.h>
#include <math.h>

namespace {

typedef unsigned short ushort_t;
typedef __attribute__((ext_vector_type(8))) short short8;
typedef __attribute__((ext_vector_type(4))) float float4v;
typedef __attribute__((ext_vector_type(4))) float f32x4v;
typedef __attribute__((ext_vector_type(4))) int i32x4v;

__device__ __forceinline__ unsigned short f2bf(float x) {
  unsigned u = __float_as_uint(x);
  u += 0x7fffu + ((u >> 16) & 1u);        // RNE
  return (unsigned short)(u >> 16);
}
__device__ __forceinline__ float bf2f(unsigned short u) {
  return __uint_as_float((unsigned)u << 16);
}
__device__ __forceinline__ void bf8_to_f(const ushort_t* p, float* o) {
  const short8 v = *(const short8*)p;
#pragma unroll
  for (int k = 0; k < 8; ++k) o[k] = bf2f((unsigned short)v[k]);
}
__device__ __forceinline__ void bf8_to_f_nt(const ushort_t* p, float* o) {
  const short8 v = __builtin_nontemporal_load((const short8*)p);
#pragma unroll
  for (int k = 0; k < 8; ++k) o[k] = bf2f((unsigned short)v[k]);
}
__device__ __forceinline__ ushort4 f4bf(float4 v) {
  ushort4 r;
  r.x = f2bf(v.x); r.y = f2bf(v.y); r.z = f2bf(v.z); r.w = f2bf(v.w);
  return r;
}

__device__ __forceinline__ float wave_sum(float v) {
#pragma unroll
  for (int off = 32; off; off >>= 1) v += __shfl_down(v, off, 64);
  return v;
}
__device__ __forceinline__ float wave_max(float v) {
#pragma unroll
  for (int off = 32; off; off >>= 1) v = fmaxf(v, __shfl_down(v, off, 64));
  return v;
}
__device__ __forceinline__ float2 blocksum2(float a, float b, float2* red, int t, int nw) {
#pragma unroll
  for (int off = 32; off; off >>= 1) {
    a += __shfl_down(a, off, 64);
    b += __shfl_down(b, off, 64);
  }
  __syncthreads();
  if ((t & 63) == 0) red[t >> 6] = make_float2(a, b);
  __syncthreads();
  float sa = 0.f, sb = 0.f;
  for (int i = 0; i < nw; ++i) { sa += red[i].x; sb += red[i].y; }
  return make_float2(sa, sb);
}

// =================== bf16 MFMA NT-GEMM, 128x128 tile (r4-verified) ===========
// Used for GRU and op-head GEMMs.  3-buffer ring, depth-2 prefetch,
// one barrier per K-step.  XCD swizzle when nz%8==0.  LDS seg-XOR (0 conflicts).
template<int MODE>
__global__ __launch_bounds__(256)
void mgemm(const ushort_t* __restrict__ A, int lda, long sA,
           const ushort_t* __restrict__ Bt, int ldb, long sB,
           void* __restrict__ C, int ldc, long sC, int K,
           const float* __restrict__ bias,
           const float* __restrict__ aw, const float* __restrict__ u, int c0)
{
  __shared__ __attribute__((aligned(16))) ushort_t As[3][128 * 32];
  __shared__ __attribute__((aligned(16))) ushort_t Bs[3][128 * 32];

  int bx = blockIdx.x, by = blockIdx.y, bz = blockIdx.z;
  const int nx = gridDim.x, ny = gridDim.y, nz = gridDim.z;
  if ((nz & 7) == 0) {
    const int nxy = nx * ny;
    const int L = bx + nx * (by + ny * bz);
    const int xcd = L & 7;
    const int idx = L >> 3;
    const int lz = idx / nxy;
    const int xy = idx - lz * nxy;
    bz = xcd + 8 * lz;
    bx = xy % nx;
    by = xy / nx;
  }

  const int z = bz;
  const ushort_t* Ab = A  + (long)z * sA;
  const ushort_t* Bb = Bt + (long)z * sB;
  const int tm = by * 128, tn = bx * 128;
  const int t = threadIdx.x, wv = t >> 6, ln = t & 63;
  const int lrow = ln >> 2, lseg = ln & 3;        // staging: 16 rows x 4 segs of 16B
  const int gseg = lseg ^ ((lrow >> 1) & 3);      // bank-conflict-free seg XOR
  const int frow = ln & 15, q = ln >> 4;          // fragment: m=ln&15, k-quad
  const int sw8 = (frow >> 1) & 3;
  const int aoff = (q ^ sw8) << 3;
  const int wm = (wv >> 1) * 64, wn = (wv & 1) * 64;

  float4v acc[4][4];
#pragma unroll
  for (int i = 0; i < 4; ++i)
#pragma unroll
    for (int j = 0; j < 4; ++j) acc[i][j] = (float4v)0.f;

  auto STAGE = [&](int s, int ks) {
    const int kc = ks * 32 + gseg * 8;
#pragma unroll
    for (int half = 0; half < 2; ++half) {
      const int rbase = wv * 32 + half * 16;
      const ushort_t* ga = Ab + (long)(tm + rbase + lrow) * lda + kc;
      const ushort_t* gb = Bb + (long)(tn + rbase + lrow) * ldb + kc;
      __builtin_amdgcn_global_load_lds(
          (const __attribute__((address_space(1))) void*)ga,
          (__attribute__((address_space(3))) void*)&As[s][rbase * 32], 16, 0, 0);
      __builtin_amdgcn_global_load_lds(
          (const __attribute__((address_space(1))) void*)gb,
          (__attribute__((address_space(3))) void*)&Bs[s][rbase * 32], 16, 0, 0);
    }
  };
  auto COMPUTE = [&](const ushort_t* Asb, const ushort_t* Bsb) {
    short8 af[4], bfr[4];
#pragma unroll
    for (int i = 0; i < 4; ++i) af[i]  = *(const short8*)&Asb[(wm + i * 16 + frow) * 32 + aoff];
#pragma unroll
    for (int j = 0; j < 4; ++j) bfr[j] = *(const short8*)&Bsb[(wn + j * 16 + frow) * 32 + aoff];
    __builtin_amdgcn_s_setprio(1);
#pragma unroll
    for (int i = 0; i < 4; ++i)
#pragma unroll
      for (int j = 0; j < 4; ++j)
        acc[i][j] = __builtin_amdgcn_mfma_f32_16x16x32_bf16(af[i], bfr[j], acc[i][j], 0, 0, 0);
    __builtin_amdgcn_s_setprio(0);
  };

  const int NS = K >> 5;   // 32-wide K-steps
  STAGE(0, 0);
  if (NS > 1) STAGE(1, 1);
  int cur = 0;
  for (int ks = 0; ks < NS; ++ks) {
    if (ks + 1 < NS) asm volatile("s_waitcnt vmcnt(4)" ::: "memory");
    else             asm volatile("s_waitcnt vmcnt(0)" ::: "memory");
    __builtin_amdgcn_s_barrier();
    if (ks + 2 < NS) {
      int nxt = cur + 2; if (nxt >= 3) nxt -= 3;
      STAGE(nxt, ks + 2);
    }
    COMPUTE(As[cur], Bs[cur]);
    ++cur; if (cur >= 3) cur -= 3;
  }

  // epilogue: C/D layout col=lane&15, row=(lane>>4)*4+reg
#pragma unroll
  for (int i = 0; i < 4; ++i) {
#pragma unroll
    for (int j = 0; j < 4; ++j) {
      const int col = tn + wn + j * 16 + (ln & 15);
#pragma unroll
      for (int reg = 0; reg < 4; ++reg) {
        const int row = tm + wm + i * 16 + (ln >> 4) * 4 + reg;
        float v = acc[i][j][reg];
        if (MODE == 0) v += u[(c0 + z) * 512 + row] * aw[(c0 + z) * 512 + col];
        else if (MODE == 1) v = fmaxf(v + bias[row], 0.f);
        else if (MODE == 3) v += bias[col];
        if (MODE == 4) ((float*)C)[(long)z * sC + (long)row * ldc + col] = v;
        else ((ushort_t*)C)[(long)z * sC + (long)row * ldc + col] = f2bf(v);
      }
    }
  }
}

// =================== bf16 MFMA NT-GEMM, 256x128 tile (GCN chain) =============
// r4-verified 3-slot ring scaled to 512 threads (8 waves, 2Mx4N): depth-2
// prefetch, ONE barrier per K-step, counted vmcnt (3 loads/thread/step ->
// steady vmcnt(3), tail 0).  LDS 72 KB -> 2 blocks/CU; per-wave out 128x32.
// Hazard: slot staged at step ks was last read at COMPUTE(ks-1); the step-ks
// barrier (after each wave's ds_reads have fed its MFMAs) separates them.
template<int MODE>
__global__ __launch_bounds__(512)
void mgemm2(const ushort_t* __restrict__ A, int lda, long sA,
            const ushort_t* __restrict__ Bt, int ldb, long sB,
            void* __restrict__ C, int ldc, long sC, int K,
            const float* __restrict__ bias,
            const float* __restrict__ aw, const float* __restrict__ u, int c0)
{
  __shared__ __attribute__((aligned(16))) ushort_t As[3][256 * 32];
  __shared__ __attribute__((aligned(16))) ushort_t Bs[3][128 * 32];

  int bx = blockIdx.x, by = blockIdx.y, bz = blockIdx.z;
  const int nx = gridDim.x, ny = gridDim.y, nz = gridDim.z;
  if ((nz & 7) == 0) {
    const int nxy = nx * ny;
    const int L = bx + nx * (by + ny * bz);
    const int xcd = L & 7;
    const int idx = L >> 3;
    const int lz = idx / nxy;
    const int xy = idx - lz * nxy;
    bz = xcd + 8 * lz;
    bx = xy % nx;
    by = xy / nx;
  }

  const int z = bz;
  const ushort_t* Ab = A  + (long)z * sA;
  const ushort_t* Bb = Bt + (long)z * sB;
  const int tm = by * 256, tn = bx * 128;
  const int t = threadIdx.x, wv = t >> 6, ln = t & 63;   // wv 0..7
  const int lrow = ln >> 2, lseg = ln & 3;
  const int gseg = lseg ^ ((lrow >> 1) & 3);
  const int frow = ln & 15, q = ln >> 4;
  const int sw8 = (frow >> 1) & 3;
  const int aoff = (q ^ sw8) << 3;
  const int wm = (wv >> 2) * 128, wn = (wv & 3) * 32;    // 2x4 wave grid

  float4v acc[8][2];
#pragma unroll
  for (int i = 0; i < 8; ++i)
#pragma unroll
    for (int j = 0; j < 2; ++j) acc[i][j] = (float4v)0.f;

  // stage one 256x32 A-slice (2 passes) + 128x32 B-slice (1 pass): 3 loads/thr
  auto STAGE = [&](int s, int ks) {
    const int kc = ks * 32 + gseg * 8;
#pragma unroll
    for (int half = 0; half < 2; ++half) {
      const int rbase = wv * 32 + half * 16;             // A: 0..240 step 16
      const ushort_t* ga = Ab + (long)(tm + rbase + lrow) * lda + kc;
      __builtin_amdgcn_global_load_lds(
          (const __attribute__((address_space(1))) void*)ga,
          (__attribute__((address_space(3))) void*)&As[s][rbase * 32], 16, 0, 0);
    }
    {
      const int rbase = wv * 16;                          // B: 0..112 step 16
      const ushort_t* gb = Bb + (long)(tn + rbase + lrow) * ldb + kc;
      __builtin_amdgcn_global_load_lds(
          (const __attribute__((address_space(1))) void*)gb,
          (__attribute__((address_space(3))) void*)&Bs[s][rbase * 32], 16, 0, 0);
    }
  };
  auto COMPUTE = [&](const ushort_t* Asb, const ushort_t* Bsb) {
    short8 af[8], bfr[2];
#pragma unroll
    for (int i = 0; i < 8; ++i) af[i]  = *(const short8*)&Asb[(wm + i * 16 + frow) * 32 + aoff];
#pragma unroll
    for (int j = 0; j < 2; ++j) bfr[j] = *(const short8*)&Bsb[(wn + j * 16 + frow) * 32 + aoff];
    __builtin_amdgcn_s_setprio(1);
#pragma unroll
    for (int i = 0; i < 8; ++i)
#pragma unroll
      for (int j = 0; j < 2; ++j)
        acc[i][j] = __builtin_amdgcn_mfma_f32_16x16x32_bf16(af[i], bfr[j], acc[i][j], 0, 0, 0);
    __builtin_amdgcn_s_setprio(0);
  };

  const int NS = K >> 5;   // 32-wide K-steps (16 for K=512)
  STAGE(0, 0);
  if (NS > 1) STAGE(1, 1);
  int cur = 0;
  for (int ks = 0; ks < NS; ++ks) {
    if (ks + 1 < NS) asm volatile("s_waitcnt vmcnt(3)" ::: "memory");
    else             asm volatile("s_waitcnt vmcnt(0)" ::: "memory");
    __builtin_amdgcn_s_barrier();
    if (ks + 2 < NS) {
      int nxt = cur + 2; if (nxt >= 3) nxt -= 3;
      STAGE(nxt, ks + 2);
    }
    COMPUTE(As[cur], Bs[cur]);
    ++cur; if (cur >= 3) cur -= 3;
  }

  // epilogue: C/D layout col=lane&15, row=(lane>>4)*4+reg
#pragma unroll
  for (int i = 0; i < 8; ++i) {
#pragma unroll
    for (int j = 0; j < 2; ++j) {
      const int col = tn + wn + j * 16 + (ln & 15);
#pragma unroll
      for (int reg = 0; reg < 4; ++reg) {
        const int row = tm + wm + i * 16 + (ln >> 4) * 4 + reg;
        float v = acc[i][j][reg];
        if (MODE == 0) v += u[(c0 + z) * 512 + row] * aw[(c0 + z) * 512 + col];
        else if (MODE == 1) v = fmaxf(v + bias[row], 0.f);
        else if (MODE == 3) v += bias[col];
        ((ushort_t*)C)[(long)z * sC + (long)row * ldc + col] = f2bf(v);
      }
    }
  }
}

// =================== transposed-weight conversions (LDS tiled) ===================
__global__ __launch_bounds__(256)
void k_tw(const float* __restrict__ gc1_W, const float* __restrict__ gc2_W,
          const float* __restrict__ concat_W, const float* __restrict__ nop_W,
          ushort_t* __restrict__ gc1LT, ushort_t* __restrict__ gc2WT,
          float* __restrict__ cWT, float* __restrict__ nWT)
{
  __shared__ float tile[32][33];
  const int job = blockIdx.y;
  const float* src; int sr, sc;
  if (job == 0)      { src = gc1_W + 262144; sr = 512; sc = 512;  }
  else if (job == 1) { src = gc2_W;          sr = 512; sc = 1024; }
  else if (job == 2) { src = concat_W;       sr = 512; sc = 1024; }
  else               { src = nop_W;          sr = 124; sc = 512;  }
  const int tpr = sc >> 5;
  const int ntile = ((sr + 31) >> 5) * tpr;
  if ((int)blockIdx.x >= ntile) return;
  const int tr = (blockIdx.x / tpr) * 32, tc = (blockIdx.x % tpr) * 32;
  const int t = threadIdx.x, tx = t & 31, ty = t >> 5;   // 8 rows per pass
#pragma unroll
  for (int p = 0; p < 4; ++p) {
    const int r = tr + ty + p * 8;
    tile[ty + p * 8][tx] = (r < sr) ? src[(size_t)r * sc + tc + tx] : 0.f;
  }
  __syncthreads();
#pragma unroll
  for (int p = 0; p < 4; ++p) {
    const int dr = tc + ty + p * 8;   // dst row = src col
    const int dc = tr + tx;           // dst col = src row
    const float v = tile[tx][ty + p * 8];
    if (job == 0)      gc1LT[(size_t)dr * 512 + dc] = f2bf(v);
    else if (job == 1) gc2WT[(size_t)dr * 512 + dc] = f2bf(v);
    else if (job == 2) cWT[(size_t)dr * 512 + dc] = v;
    else               nWT[(size_t)dr * 128 + dc] = v;   // dc < 128 always (sr pad)
  }
}

// =================== bulk front kernel — nt-loads on adjacency stream ========
__global__ __launch_bounds__(256)
void k_front2(const int* __restrict__ step, const float* __restrict__ emb,
              const float* __restrict__ last_hidden,
              const float* __restrict__ wo_W, const float* __restrict__ ot_W,
              const float* __restrict__ W_ih, const float* __restrict__ W_hh,
              const float* __restrict__ ww, const int* __restrict__ ex,
              const float* __restrict__ word_op, const int* __restrict__ seq_mask,
              ushort_t* __restrict__ woWb, ushort_t* __restrict__ otWb,
              ushort_t* __restrict__ wihb, ushort_t* __restrict__ xhb,
              ushort_t* __restrict__ adj, float* __restrict__ won, int do_adj)
{
  const int blk = blockIdx.x;
  const int t = threadIdx.x;
  const size_t u0 = (size_t)blk * 256 + t;           // < 524288

  // ---- adjacency: 8 fixed units/thread, fully unrolled, NT loads ----
  if (do_adj) {
    f32x4v w[8]; i32x4v e[8];
#pragma unroll
    for (int k = 0; k < 8; ++k) {
      w[k] = __builtin_nontemporal_load((const f32x4v*)ww + u0 + (size_t)k * 524288);
      e[k] = __builtin_nontemporal_load((const i32x4v*)ex + u0 + (size_t)k * 524288);
    }
#pragma unroll
    for (int k = 0; k < 8; ++k) {
      ushort4 r;
      r.x = (e[k][0] == 1) ? f2bf(w[k][0]) : 0;
      r.y = (e[k][1] == 1) ? f2bf(w[k][1]) : 0;
      r.z = (e[k][2] == 1) ? f2bf(w[k][2]) : 0;
      r.w = (e[k][3] == 1) ? f2bf(w[k][3]) : 0;
      ((ushort4*)adj)[u0 + (size_t)k * 524288] = r;
    }
  }

  // ---- copies: unit A (always) + unit B (u0 < 163840) ----
  if (u0 < 131072) {
    ((ushort4*)woWb)[u0] = f4bf(((const float4*)wo_W)[u0]);
    const size_t i2 = u0 + 262144;
    ((ushort4*)wihb)[i2] = f4bf(((const float4*)W_hh)[i2 - 196608]);
  } else if (u0 < 262144) {
    const size_t i = u0 - 131072;
    ((ushort4*)otWb)[i] = f4bf(((const float4*)ot_W)[i]);
    if (u0 < 163840) {
      const size_t e = i * 4;
      const int z = (int)(e >> 16), b = (int)((e >> 9) & 127), k = (int)(e & 511);
      float4 v = make_float4(0.f, 0.f, 0.f, 0.f);
      if (b < 64)
        v = z ? *(const float4*)&last_hidden[b * 512 + k]
              : *(const float4*)&emb[(size_t)step[b] * 512 + k];
      ((ushort4*)xhb)[i] = f4bf(v);
    }
  } else {
    const size_t i = u0 - 262144;    // < 262144: wihb first part
    const float4 v = (i < 196608) ? ((const float4*)W_ih)[i]
                                  : ((const float4*)W_hh)[i - 196608];
    ((ushort4*)wihb)[i] = f4bf(v);
  }

  // ---- wo_n normalization: blocks 0..63, one per batch ----
  if (blk < 64) {
    const int b = blk;
    __shared__ float red[4][4];               // [wave][o]
    float4 a0 = ((const float4*)word_op)[b * 512 + t];
    float4 a1 = ((const float4*)word_op)[b * 512 + t + 256];
    if (seq_mask[b * 512 + t])       a0 = make_float4(0.f, 0.f, 0.f, 0.f);
    if (seq_mask[b * 512 + t + 256]) a1 = make_float4(0.f, 0.f, 0.f, 0.f);
    float l0 = a0.x + a1.x, l1 = a0.y + a1.y, l2 = a0.z + a1.z, l3 = a0.w + a1.w;
#pragma unroll
    for (int off = 32; off; off >>= 1) {
      l0 += __shfl_down(l0, off, 64);
      l1 += __shfl_down(l1, off, 64);
      l2 += __shfl_down(l2, off, 64);
      l3 += __shfl_down(l3, off, 64);
    }
    if ((t & 63) == 0) {
      red[t >> 6][0] = l0; red[t >> 6][1] = l1;
      red[t >> 6][2] = l2; red[t >> 6][3] = l3;
    }
    __syncthreads();
    const float tot0 = red[0][0] + red[1][0] + red[2][0] + red[3][0] + 1e-30f;
    const float tot1 = red[0][1] + red[1][1] + red[2][1] + red[3][1] + 1e-30f;
    const float tot2 = red[0][2] + red[1][2] + red[2][2] + red[3][2] + 1e-30f;
    const float tot3 = red[0][3] + red[1][3] + red[2][3] + red[3][3] + 1e-30f;
    float* w0 = won + ((size_t)b * 4 + 0) * 512;
    float* w1 = won + ((size_t)b * 4 + 1) * 512;
    float* w2 = won + ((size_t)b * 4 + 2) * 512;
    float* w3 = won + ((size_t)b * 4 + 3) * 512;
    w0[t] = a0.x / tot0; w0[t + 256] = a1.x / tot0;
    w1[t] = a0.y / tot1; w1[t + 256] = a1.y / tot1;
    w2[t] = a0.z / tot2; w2[t + 256] = a1.z / tot2;
    w3[t] = a0.w / tot3; w3[t + 256] = a1.w / tot3;
  }
}

// =================== small fused kernels ===================

__global__ __launch_bounds__(256)
void k_gru(const float* __restrict__ gi2, const float* __restrict__ last_hidden,
           const float* __restrict__ b_ih, const float* __restrict__ b_hh,
           float* __restrict__ hnew, float* __restrict__ hnew_out)
{
  const int idx = blockIdx.x * 256 + threadIdx.x;
  const int b = idx >> 9, tt = idx & 511;
  const float* gh = gi2 + 196608;
  const float ir  = gi2[tt * 128 + b]          + b_ih[tt];
  const float iz  = gi2[(512 + tt) * 128 + b]  + b_ih[512 + tt];
  const float inn = gi2[(1024 + tt) * 128 + b] + b_ih[1024 + tt];
  const float hr  = gh[tt * 128 + b]          + b_hh[tt];
  const float hz  = gh[(512 + tt) * 128 + b]  + b_hh[512 + tt];
  const float hn  = gh[(1024 + tt) * 128 + b] + b_hh[1024 + tt];
  const float h   = last_hidden[idx];
  const float r = 1.f / (1.f + __expf(-(ir + hr)));
  const float z = 1.f / (1.f + __expf(-(iz + hz)));
  const float n = tanhf(inn + r * hn);
  const float o = (1.f - z) * n + z * h;
  hnew[idx] = o;
  hnew_out[idx] = o;
}

__global__ __launch_bounds__(128)
void k_qu(const float* __restrict__ hnew, const float* __restrict__ attn_W,
          const float* __restrict__ gc1_W, float* __restrict__ q, float* __restrict__ u)
{
  const int b = blockIdx.x, j = blockIdx.y * 128 + threadIdx.x;
  __shared__ float hs[512];
  for (int i = threadIdx.x; i < 512; i += 128) hs[i] = hnew[b * 512 + i];
  __syncthreads();
  float qa = 0.f, ua = 0.f;
  for (int h = 0; h < 512; ++h) {
    const float hv = hs[h];
    qa += hv * attn_W[(size_t)h * 512 + j];
    ua += hv * gc1_W[(size_t)h * 512 + j];
  }
  q[b * 512 + j] = qa;
  u[b * 512 + j] = ua;
}

__global__ __launch_bounds__(256)
void k_score(const float* __restrict__ q, const float* __restrict__ enc,
             float* __restrict__ scores, ushort_t* __restrict__ encb, int emit)
{
  const int b = blockIdx.x, p = blockIdx.y;
  const int t = threadIdx.x, wv = t >> 6, ln = t & 63;
  __shared__ float qs[512];
  for (int i = t; i < 512; i += 256) qs[i] = q[b * 512 + i];
  __syncthreads();
  const int e0 = ln * 8;
  const float4 q0 = *(const float4*)&qs[e0];
  const float4 q1 = *(const float4*)&qs[e0 + 4];
  for (int it = 0; it < 8; ++it) {
    const int s = p * 32 + wv * 8 + it;
    const float* e = enc + ((size_t)s * 64 + b) * 512 + e0;
    const float4 v0 = *(const float4*)e;
    const float4 v1 = *(const float4*)(e + 4);
    float a = q0.x * v0.x + q0.y * v0.y + q0.z * v0.z + q0.w * v0.w
            + q1.x * v1.x + q1.y * v1.y + q1.z * v1.z + q1.w * v1.w;
    if (emit) {
      short8 o;
      o[0] = (short)f2bf(v0.x); o[1] = (short)f2bf(v0.y);
      o[2] = (short)f2bf(v0.z); o[3] = (short)f2bf(v0.w);
      o[4] = (short)f2bf(v1.x); o[5] = (short)f2bf(v1.y);
      o[6] = (short)f2bf(v1.z); o[7] = (short)f2bf(v1.w);
      *(short8*)&encb[(size_t)b * 262144 + (size_t)s * 512 + e0] = o;
    }
    a = wave_sum(a);
    if (ln == 0) scores[b * 512 + s] = a;
  }
}

__global__ __launch_bounds__(512)
void k_ctx2(const float* __restrict__ scores, const ushort_t* __restrict__ encb,
            const float* __restrict__ enc, float* __restrict__ aw_dout,
            float* __restrict__ aw_ws, float* __restrict__ ctxpart, int use_bf)
{
  const int b = blockIdx.x, p = blockIdx.y, t = threadIdx.x;
  const int w = t >> 6, lane = t & 63;
  __shared__ float sc[512];
  __shared__ float red[8];
  __shared__ float red2[8];
  const float v = scores[b * 512 + t];
  float m = wave_max(v);
  if (lane == 0) red[w] = m;
  __syncthreads();
  float mm = red[0];
#pragma unroll
  for (int i = 1; i < 8; ++i) mm = fmaxf(mm, red[i]);
  const float e = __expf(v - mm);
  float s = wave_sum(e);
  if (lane == 0) red2[w] = s;
  __syncthreads();
  float tot = 0.f;
#pragma unroll
  for (int i = 0; i < 8; ++i) tot += red2[i];
  const float awv = e / tot;
  sc[t] = awv;
  if (p == 0) {
    aw_dout[b * 512 + t] = awv;
    aw_ws[b * 512 + t]   = awv;
  }
  __syncthreads();
  float acc = 0.f;
  if (use_bf) {
#pragma unroll 4
    for (int si = 0; si < 32; ++si)
      acc += sc[p * 32 + si] * bf2f(encb[((size_t)b * 512 + p * 32 + si) * 512 + t]);
  } else {
#pragma unroll 4
    for (int si = 0; si < 32; ++si)
      acc += sc[p * 32 + si] * enc[((size_t)(p * 32 + si) * 64 + b) * 512 + t];
  }
  ctxpart[((size_t)b * 16 + p) * 512 + t] = acc;
}

__global__ __launch_bounds__(128)
void k_concat(const float* __restrict__ hnew, const float* __restrict__ ctxpart,
              const float* __restrict__ cWT, const float* __restrict__ bias,
              float* __restrict__ out_cc, float* __restrict__ cc_ws)
{
  const int b = blockIdx.x, o = blockIdx.y * 128 + threadIdx.x;
  __shared__ __align__(16) float cat[1024];
  for (int m = 0; m < 8; ++m) {
    const int i = threadIdx.x + 128 * m;
    if (i < 512) {
      cat[i] = hnew[b * 512 + i];
    } else {
      const int d = i - 512;
      float s = 0.f;
#pragma unroll
      for (int pp = 0; pp < 16; ++pp) s += ctxpart[((size_t)b * 16 + pp) * 512 + d];
      cat[i] = s;
    }
  }
  __syncthreads();
  float acc = bias[o];
  for (int k = 0; k < 1024; k += 4) {
    acc += cat[k]     * cWT[(size_t)k * 512 + o]
         + cat[k + 1] * cWT[(size_t)(k + 1) * 512 + o]
         + cat[k + 2] * cWT[(size_t)(k + 2) * 512 + o]
         + cat[k + 3] * cWT[(size_t)(k + 3) * 512 + o];
  }
  acc = fmaxf(acc, 0.f);
  out_cc[b * 512 + o] = acc;
  cc_ws[b * 512 + o]  = acc;
}

__global__ __launch_bounds__(256)
void k_adjc(const float* __restrict__ ww, const int* __restrict__ ex,
            ushort_t* __restrict__ adj, int c0)
{
  const size_t i = (size_t)blockIdx.x * 256 + threadIdx.x;
  const size_t base4 = (size_t)c0 * 512 * 512 / 4;
  const float4 w4 = ((const float4*)ww)[base4 + i];
  const int4   e4 = ((const int4*)ex)[base4 + i];
  ushort4 r;
  r.x = (e4.x == 1) ? f2bf(w4.x) : 0;
  r.y = (e4.y == 1) ? f2bf(w4.y) : 0;
  r.z = (e4.z == 1) ? f2bf(w4.z) : 0;
  r.w = (e4.w == 1) ? f2bf(w4.w) : 0;
  ((ushort4*)adj)[i] = r;
}

__global__ __launch_bounds__(256)
void k_encc(const float* __restrict__ enc, ushort_t* __restrict__ encb, int c0)
{
  const size_t i = (size_t)blockIdx.x * 256 + threadIdx.x;
  const size_t el = i * 4;
  const int k = el & 511;
  const int s = (el >> 9) & 511;
  const int z = el >> 18;
  const float4 v = *(const float4*)&enc[((size_t)s * 64 + c0 + z) * 512 + k];
  ushort4 r;
  r.x = f2bf(v.x); r.y = f2bf(v.y); r.z = f2bf(v.z); r.w = f2bf(v.w);
  ((ushort4*)encb)[i] = r;
}

// Barrier-free fused LN + residual + wo_n contraction.  NT loads on the
// read-once w2w / encb streams.
__global__ __launch_bounds__(256)
void k_red2(const ushort_t* __restrict__ w2w, const float* __restrict__ aw,
            const float* __restrict__ hnew, const ushort_t* __restrict__ encb,
            const float* __restrict__ won, const float* __restrict__ ng,
            const float* __restrict__ nb, float* __restrict__ part, int c0)
{
  const int z = blockIdx.x, b = c0 + z, yb = blockIdx.y;
  const int t = threadIdx.x, wv = t >> 6, ln = t & 63;
  __shared__ float sw[32][5];               // won0..3, aw per s-local
  __shared__ float accs[2][4][1024];        // cross-wave combine (32 KB)
  if (t < 160) {
    const int sl = t / 5, c_ = t - sl * 5;
    const int sg = yb * 32 + sl;
    sw[sl][c_] = (c_ < 4) ? won[((size_t)b * 4 + c_) * 512 + sg] : aw[b * 512 + sg];
  }
  const int d0 = ln * 16;
  float gg[16], bb[16], hv[16];
#pragma unroll
  for (int k = 0; k < 16; k += 4) {
    *(float4*)&gg[k] = *(const float4*)&ng[d0 + k];
    *(float4*)&bb[k] = *(const float4*)&nb[d0 + k];
  }
  if (ln < 32) {
#pragma unroll
    for (int k = 0; k < 16; k += 4)
      *(float4*)&hv[k] = *(const float4*)&hnew[b * 512 + d0 + k];
  }
  float acc[4][16];
#pragma unroll
  for (int o = 0; o < 4; ++o)
#pragma unroll
    for (int k = 0; k < 16; ++k) acc[o][k] = 0.f;
  __syncthreads();
  for (int it = 0; it < 8; ++it) {
    const int sl = wv * 8 + it;
    const int s = yb * 32 + sl;
    const ushort_t* row = w2w + ((size_t)z * 512 + s) * 1024 + d0;
    float x[16];
    bf8_to_f_nt(row, x);
    bf8_to_f_nt(row + 8, x + 8);
    float ls = 0.f, lss = 0.f;
#pragma unroll
    for (int k = 0; k < 16; ++k) { ls += x[k]; lss += x[k] * x[k]; }
#pragma unroll
    for (int off = 32; off; off >>= 1) {
      ls  += __shfl_xor(ls,  off, 64);
      lss += __shfl_xor(lss, off, 64);
    }
    const float mean = ls * (1.f / 1024.f);
    const float var  = lss * (1.f / 1024.f) - mean * mean;
    const float inv  = rsqrtf(var + 1e-6f);
    float res[16];
    if (ln < 32) {
      const float a_ = sw[sl][4];
#pragma unroll
      for (int k = 0; k < 16; ++k) res[k] = a_ * hv[k];
    } else {
      const ushort_t* er = encb + ((size_t)z * 512 + s) * 512 + (d0 - 512);
      bf8_to_f_nt(er, res);
      bf8_to_f_nt(er + 8, res + 8);
    }
    const float w0 = sw[sl][0], w1 = sw[sl][1], w2 = sw[sl][2], w3 = sw[sl][3];
#pragma unroll
    for (int k = 0; k < 16; ++k) {
      const float val = (x[k] - mean) * inv * gg[k] + bb[k] + res[k];
      acc[0][k] += w0 * val; acc[1][k] += w1 * val;
      acc[2][k] += w2 * val; acc[3][k] += w3 * val;
    }
  }
  if (wv < 2) {
#pragma unroll
    for (int o = 0; o < 4; ++o)
#pragma unroll
      for (int k = 0; k < 16; k += 4)
        *(float4*)&accs[wv][o][d0 + k] = *(float4*)&acc[o][k];
  }
  __syncthreads();
  if (wv >= 2) {
#pragma unroll
    for (int o = 0; o < 4; ++o)
#pragma unroll
      for (int k = 0; k < 16; ++k)
        accs[wv - 2][o][d0 + k] += acc[o][k];
  }
  __syncthreads();
  for (int i = t; i < 4096; i += 256) {
    const int o = i >> 10, d = i & 1023;
    part[(((size_t)(b * 16 + yb) * 4 + o) << 10) + d] = accs[0][o][d] + accs[1][o][d];
  }
}

// sum 16 partials -> ctx_op bf16 (256 x 1024)
__global__ __launch_bounds__(256)
void k_psum(const float* __restrict__ part, ushort_t* __restrict__ ctxop)
{
  const int idx = blockIdx.x * 256 + threadIdx.x;   // 262144
  const int r = idx >> 10, d = idx & 1023;
  const int b = r >> 2, o = r & 3;
  float s = 0.f;
#pragma unroll
  for (int p = 0; p < 16; ++p)
    s += part[(((size_t)(b * 16 + p) * 4 + o) << 10) + d];
  ctxop[idx] = f2bf(s);
}

__global__ __launch_bounds__(512)
void k_ln1(const float* __restrict__ oppre, const float* __restrict__ wo_b,
           const float* __restrict__ n1g, const float* __restrict__ n1b,
           const float* __restrict__ ops, ushort_t* __restrict__ opall)
{
  const int r = blockIdx.x, t = threadIdx.x;
  const int o = r & 3;
  __shared__ float2 red[8];
  const float val = fmaxf(oppre[(size_t)r * 512 + t] + wo_b[t], 0.f);
  const float2 ss = blocksum2(val, val * val, red, t, 8);
  const float m = ss.x * (1.f / 512.f);
  const float v = ss.y * (1.f / 512.f) - m * m;
  const float s1 = (val - m) * rsqrtf(v + 1e-6f) * n1g[t] + n1b[t];
  opall[(size_t)r * 1024 + t] = f2bf(s1);
  opall[(size_t)r * 1024 + 512 + t] = f2bf(ops[o * 512 + t]);
}

__global__ __launch_bounds__(512)
void k_ln2dot(const float* __restrict__ ohpre, const float* __restrict__ ot_b,
              const float* __restrict__ n2g, const float* __restrict__ n2b,
              const float* __restrict__ ops, const float* __restrict__ cc,
              const float* __restrict__ ops_bias, float* __restrict__ oo)
{
  const int r = blockIdx.x, t = threadIdx.x;
  const int b = r >> 2, o = r & 3;
  __shared__ float2 red[8];
  const float oh = fmaxf(ohpre[(size_t)r * 512 + t] + ot_b[t], 0.f);
  const float2 ss = blocksum2(oh, oh * oh, red, t, 8);
  const float m = ss.x * (1.f / 512.f);
  const float v = ss.y * (1.f / 512.f) - m * m;
  const float opo = (oh - m) * rsqrtf(v + 1e-6f) * n2g[t] + n2b[t] + ops[o * 512 + t];
  const float p = cc[b * 512 + t] * opo;
  const float2 s3 = blocksum2(p, 0.f, red, t, 8);
  if (t == 0) oo[r] = s3.x + ops_bias[o];
}

__global__ __launch_bounds__(128)
void k_final(const float* __restrict__ oo, const float* __restrict__ cc,
             const float* __restrict__ nWT, const float* __restrict__ nop_b,
             float* __restrict__ outp)
{
  const int b = blockIdx.x, t = threadIdx.x;
  __shared__ __align__(16) float ccs[512];
  __shared__ float red[2];
  __shared__ float red2[2];
  for (int i = t; i < 512; i += 128) ccs[i] = cc[b * 512 + i];
  __syncthreads();
  float v;
  if (t < 4) {
    v = oo[b * 4 + t];
  } else {
    const int j = t - 4;
    float a = nop_b[j];
    for (int k = 0; k < 512; ++k) a += ccs[k] * nWT[k * 128 + j];
    v = a;
  }
  float m = wave_max(v);
  if ((t & 63) == 0) red[t >> 6] = m;
  __syncthreads();
  m = fmaxf(red[0], red[1]);
  const float e = __expf(v - m);
  float s = wave_sum(e);
  if ((t & 63) == 0) red2[t >> 6] = s;
  __syncthreads();
  s = red2[0] + red2[1];
  outp[b * 128 + t] = v - m - logf(s);
}

} // namespace

extern "C" void kernel_launch(void* const* d_in, const int* in_sizes, int n_in,
                              void* d_out, int out_size, void* d_ws, size_t ws_size,
                              hipStream_t stream)
{
  const int*   input_step  = (const int*)  d_in[0];
  const float* last_hidden = (const float*)d_in[1];
  const float* enc         = (const float*)d_in[2];
  const float* word_word   = (const float*)d_in[3];
  const float* word_op     = (const float*)d_in[4];
  const int*   word_exist  = (const int*)  d_in[5];
  const int*   seq_mask    = (const int*)  d_in[6];
  const float* emb         = (const float*)d_in[7];
  const float* W_ih        = (const float*)d_in[8];
  const float* W_hh        = (const float*)d_in[9];
  const float* b_ih        = (const float*)d_in[10];
  const float* b_hh        = (const float*)d_in[11];
  const float* attn_W      = (const float*)d_in[12];
  const float* concat_W    = (const float*)d_in[14];
  const float* concat_b    = (const float*)d_in[15];
  const float* ops         = (const float*)d_in[16];
  const float* ops_bias    = (const float*)d_in[17];
  const float* nop_W       = (const float*)d_in[18];
  const float* nop_b       = (const float*)d_in[19];
  const float* gc1_W       = (const float*)d_in[20];
  const float* gc1_b       = (const float*)d_in[21];
  const float* gc2_W       = (const float*)d_in[22];
  const float* gc2_b       = (const float*)d_in[23];
  const float* norm_g      = (const float*)d_in[24];
  const float* norm_b      = (const float*)d_in[25];
  const float* norm1_g     = (const float*)d_in[26];
  const float* norm1_b     = (const float*)d_in[27];
  const float* norm2_g     = (const float*)d_in[28];
  const float* norm2_b     = (const float*)d_in[29];
  const float* wo_W        = (const float*)d_in[30];
  const float* wo_b        = (const float*)d_in[31];
  const float* ot_W        = (const float*)d_in[32];
  const float* ot_b        = (const float*)d_in[33];

  float* ws  = (float*)d_ws;
  float* out = (float*)d_out;

  // ---- workspace layout (floats) ----
  size_t off = 0;
  auto take = [&](size_t n) { size_t o = off; off += n; return o; };
  const size_t o_hnew = take(32768);
  const size_t o_q    = take(32768);
  const size_t o_u    = take(32768);
  const size_t o_aw   = take(32768);
  const size_t o_scores = take(32768);
  const size_t o_ctxpart = take(524288);   // 64*16*512
  const size_t o_cc   = take(32768);
  const size_t o_won  = take(131072);
  const size_t o_oo   = take(256);
  const size_t o_gi2  = take(393216);      // 2 x 1536 x 128 f32
  const size_t o_part = take(4194304);     // 64*16*4*1024
  const size_t o_oppre = take(131072);
  const size_t o_ohpre = take(131072);
  const size_t o_gc1LT = take(131072);
  const size_t o_gc2WT = take(262144);
  const size_t o_woW   = take(262144);
  const size_t o_otW   = take(262144);
  const size_t o_cWT   = take(524288);
  const size_t o_nWT   = take(65536);
  const size_t o_wihb  = take(786432);     // 2 x 1536 x 512 bf16
  const size_t o_xhb   = take(65536);      // 2 x 128 x 512 bf16
  const size_t o_ctxop = take(131072);
  const size_t o_opall = take(131072);
  const size_t base = off;

  // pick chunk size by available workspace (constant across calls -> graph-safe)
  int CB = 16;
  if (ws_size >= (base + 64ull * 524288) * 4) CB = 64;
  else if (ws_size >= (base + 32ull * 524288) * 4) CB = 32;
  const int nch = 64 / CB;

  const size_t o_adjbf = take((size_t)CB * 131072);
  const size_t o_h1t   = take((size_t)CB * 131072);
  const size_t o_encbf = take((size_t)CB * 131072);
  const size_t o_xw1t  = take((size_t)CB * 131072);
  const size_t o_tmat  = o_xw1t;           // overlays xw1t (dead after mgemm2<1>)
  const size_t o_w2w   = o_adjbf;          // overlays adjbf+h1t (dead after mgemm2<2>)

  float* hnew = ws + o_hnew;
  float* q    = ws + o_q;
  float* u    = ws + o_u;
  float* aw   = ws + o_aw;
  float* scores = ws + o_scores;
  float* ctxpart = ws + o_ctxpart;
  float* cc   = ws + o_cc;
  float* won  = ws + o_won;
  float* oo   = ws + o_oo;
  float* gi2  = ws + o_gi2;
  float* part = ws + o_part;
  float* oppre = ws + o_oppre;
  float* ohpre = ws + o_ohpre;
  float* cWT  = ws + o_cWT;
  float* nWT  = ws + o_nWT;
  ushort_t* gc1LT = (ushort_t*)(ws + o_gc1LT);
  ushort_t* gc2WT = (ushort_t*)(ws + o_gc2WT);
  ushort_t* woWb  = (ushort_t*)(ws + o_woW);
  ushort_t* otWb  = (ushort_t*)(ws + o_otW);
  ushort_t* wihb  = (ushort_t*)(ws + o_wihb);
  ushort_t* xhb   = (ushort_t*)(ws + o_xhb);
  ushort_t* ctxop = (ushort_t*)(ws + o_ctxop);
  ushort_t* opall = (ushort_t*)(ws + o_opall);
  ushort_t* adjbf = (ushort_t*)(ws + o_adjbf);
  ushort_t* h1t   = (ushort_t*)(ws + o_h1t);
  ushort_t* encbf = (ushort_t*)(ws + o_encbf);
  ushort_t* xw1t  = (ushort_t*)(ws + o_xw1t);
  ushort_t* tmat  = (ushort_t*)(ws + o_tmat);
  ushort_t* w2wbf = (ushort_t*)(ws + o_w2w);

  float* out_logits = out;
  float* out_hnew   = out + 8192;
  float* out_aw     = out + 8192 + 32768;
  float* out_cc     = out + 8192 + 65536;

  const int full = (CB == 64) ? 1 : 0;

  // ---- front: transposed weights (LDS tiled) + bulk streams ----
  k_tw<<<dim3(512, 4), 256, 0, stream>>>(gc1_W, gc2_W, concat_W, nop_W,
      gc1LT, gc2WT, cWT, nWT);
  k_front2<<<2048, 256, 0, stream>>>(input_step, emb, last_hidden,
      wo_W, ot_W, W_ih, W_hh, word_word, word_exist, word_op, seq_mask,
      woWb, otWb, wihb, xhb, adjbf, won, full);

  // ---- GRU via MFMA: gi/gh = [W_ih;W_hh] @ [x;h]^T, N padded to 128 ----
  mgemm<4><<<dim3(1, 12, 2), 256, 0, stream>>>(wihb, 512, 786432, xhb, 512, 65536,
      gi2, 128, 196608, 512, nullptr, nullptr, nullptr, 0);
  k_gru<<<128, 256, 0, stream>>>(gi2, last_hidden, b_ih, b_hh, hnew, out_hnew);

  // ---- attention + concat ----
  k_qu<<<dim3(64, 4), 128, 0, stream>>>(hnew, attn_W, gc1_W, q, u);
  k_score<<<dim3(64, 16), 256, 0, stream>>>(q, enc, scores, encbf, full);
  k_ctx2<<<dim3(64, 16), 512, 0, stream>>>(scores, encbf, enc, out_aw, aw, ctxpart, full);
  k_concat<<<dim3(64, 4), 128, 0, stream>>>(hnew, ctxpart, cWT, concat_b, out_cc, cc);

  // ---- GCN chain (bf16 MFMA, 256x128 tiles, 3-slot depth-2 ring) ----
  for (int c = 0; c < nch; ++c) {
    const int c0 = c * CB;
    if (!full) {
      k_adjc<<<CB * 256, 256, 0, stream>>>(word_word, word_exist, adjbf, c0);
      k_encc<<<CB * 256, 256, 0, stream>>>(enc, encbf, c0);
    }
    // XW1T[d][s] = gc1LT[d][:] . enc_b[s][:] + u[b][d]*aw[b][s]
    mgemm2<0><<<dim3(4, 2, CB), 512, 0, stream>>>(gc1LT, 512, 0, encbf, 512, 262144,
        xw1t, 512, 262144, 512, nullptr, aw, u, c0);
    // h1T[d][s] = relu(XW1T[d][:] . adj[s][:] + gc1_b[d])
    mgemm2<1><<<dim3(4, 2, CB), 512, 0, stream>>>(xw1t, 512, 262144, adjbf, 512, 262144,
        h1t, 512, 262144, 512, gc1_b, nullptr, nullptr, 0);
    // t[s][d] = adj[s][:] . h1T[d][:]   (overlays xw1t, dead)
    mgemm2<2><<<dim3(4, 2, CB), 512, 0, stream>>>(adjbf, 512, 262144, h1t, 512, 262144,
        tmat, 512, 262144, 512, nullptr, nullptr, nullptr, 0);
    // w2w[s][e] = t[s][:] . gc2WT[e][:] + gc2_b[e]   (overlays adjbf+h1t, dead)
    mgemm2<3><<<dim3(8, 2, CB), 512, 0, stream>>>(tmat, 512, 262144, gc2WT, 512, 0,
        w2wbf, 1024, 524288, 512, gc2_b, nullptr, nullptr, 0);
    k_red2<<<dim3(CB, 16), 256, 0, stream>>>(w2wbf, aw, hnew, encbf, won, norm_g, norm_b, part, c0);
  }

  // ---- op head (MFMA GEMMs) + nop head + log_softmax ----
  k_psum<<<1024, 256, 0, stream>>>(part, ctxop);
  mgemm<4><<<dim3(4, 2, 1), 256, 0, stream>>>(ctxop, 1024, 0, woWb, 1024, 0,
      oppre, 512, 0, 1024, nullptr, nullptr, nullptr, 0);
  k_ln1<<<256, 512, 0, stream>>>(oppre, wo_b, norm1_g, norm1_b, ops, opall);
  mgemm<4><<<dim3(4, 2, 1), 256, 0, stream>>>(opall, 1024, 0, otWb, 1024, 0,
      ohpre, 512, 0, 1024, nullptr, nullptr, nullptr, 0);
  k_ln2dot<<<256, 512, 0, stream>>>(ohpre, ot_b, norm2_g, norm2_b, ops, cc, ops_bias, oo);
  k_final<<<64, 128, 0, stream>>>(oo, cc, nWT, nop_b, out_logits);

  (void)in_sizes; (void)n_in; (void)out_size;
}